// Round 6
// baseline (413.357 us; speedup 1.0000x reference)
//
#include <hip/hip_runtime.h>
#include <hip/hip_bf16.h>
#include <hip/hip_fp16.h>
#include <cstdint>
#include <cstddef>

#define N_NODES 50000
#define N_EDGES 800000
#define NBKT    196      // ceil(50000/256) buckets of 256 rows
#define BSH     8        // rows-per-bucket shift
#define BCHUNK  2048     // edges per bin_k block
#define CAP     6144     // max edges per bucket (mean 4082)

typedef __attribute__((ext_vector_type(8))) short short8;
typedef __attribute__((ext_vector_type(4))) float floatx4;
typedef __attribute__((ext_vector_type(2))) float floatx2;
typedef __attribute__((ext_vector_type(4))) unsigned int uintx4;
typedef __attribute__((ext_vector_type(2))) unsigned int uintx2;
typedef __attribute__((ext_vector_type(8))) _Float16 half8v;

__device__ inline float bf2f(unsigned short u) {
    union { unsigned int i; float f; } v; v.i = ((unsigned int)u) << 16; return v.f;
}
__device__ inline unsigned short f2bf(float f) {
    union { float f; unsigned int i; } v; v.f = f;
    unsigned int u = v.i;
    return (unsigned short)((u + 0x7FFFu + ((u >> 16) & 1u)) >> 16);
}
// packed RNE f32x2 -> bf16x2 (v_cvt_pk_bf16_f32 on gfx950)
__device__ inline unsigned int f2bf_pk(float a, float b) {
    __hip_bfloat162 h2 = __float22bfloat162_rn(make_float2(a, b));
    return *reinterpret_cast<unsigned int*>(&h2);
}
// f16 helpers (edge path is f16: packed ALU + mfma_f32_16x16x32_f16)
__device__ inline unsigned short f2fh(float f) {
    _Float16 h = (_Float16)f;
    return __builtin_bit_cast(unsigned short, h);
}
// packed f32x2 -> f16x2 via v_cvt_pkrtz_f16_f32 (1 instr)
// NOTE: builtin returns __fp16 ext_vector_type(2) on this clang — bit_cast it.
__device__ inline unsigned int f2fh_pk(float a, float b) {
    typedef __attribute__((ext_vector_type(2))) __fp16 h2v;
    h2v r = __builtin_amdgcn_cvt_pkrtz(a, b);
    return __builtin_bit_cast(unsigned int, r);
}
__device__ inline __half2 u2h(unsigned int u) { return __builtin_bit_cast(__half2, u); }
__device__ inline unsigned int h2u(__half2 h) { return __builtin_bit_cast(unsigned int, h); }
// f16 SiLU on a packed pair.
__device__ inline __half2 silu_h2(__half2 x) {
    const __half2 nlog2e = __float2half2_rn(-1.4426950408889634f);
    const __half2 one    = __float2half2_rn(1.0f);
    __half2 e = h2exp2(__hmul2(x, nlog2e));
    return __hmul2(x, h2rcp(__hadd2(e, one)));
}
// silu via v_rcp_f32 (1 ulp) instead of IEEE divide
__device__ inline float silu_f(float x) {
    float e = __expf(-x);
    return x * __builtin_amdgcn_rcpf(1.0f + e);
}

__device__ inline int block_excl_scan_256(int v, int* buf) {
    int tid = threadIdx.x;
    buf[tid] = v;
    __syncthreads();
    #pragma unroll
    for (int off = 1; off < 256; off <<= 1) {
        int t = (tid >= off) ? buf[tid - off] : 0;
        __syncthreads();
        buf[tid] += t;
        __syncthreads();
    }
    return buf[tid] - v;
}

// ---------------------------------------------------------------------------
// Pack kernel: fp32->bf16/f16 weight rearrangement into MFMA fragment order.
// R15: h0 conversion removed — embed_fused converts f32->bf16 inline.
// B-fragment order: Bp[(kb*NOUT + n)*8 + i] = B[(kb*8+i)*NOUT + n]
// ---------------------------------------------------------------------------
__device__ inline void pack_std(const float* __restrict__ src,
                                unsigned short* __restrict__ dst,
                                int NOUT, long j) {
    int i = (int)(j & 7);
    long rest = j >> 3;
    int n = (int)(rest % NOUT);
    int kb = (int)(rest / NOUT);
    dst[j] = f2bf(src[(long)(kb * 8 + i) * NOUT + n]);
}
__device__ inline void pack_std_h(const float* __restrict__ src,
                                  unsigned short* __restrict__ dst,
                                  int NOUT, long j) {
    int i = (int)(j & 7);
    long rest = j >> 3;
    int n = (int)(rest % NOUT);
    int kb = (int)(rest / NOUT);
    dst[j] = f2fh(src[(long)(kb * 8 + i) * NOUT + n]);
}

#define SW_IN 8192L
#define SW_OUT 8192L
#define SW1   16384L
#define SE2   4096L
#define SN1   24576L
#define SN2   16384L
#define SB    128L
#define PERL  (SW1 + SE2 + SN1 + SN2 + SB)
#define PACK_TOTAL (SW_IN + SW_OUT + 4 * PERL)

__global__ __launch_bounds__(256) void pack_kernel(
    const float* __restrict__ W_in,
    const float* __restrict__ W_out, const float* __restrict__ eW1,
    const float* __restrict__ eb1, const float* __restrict__ eW2,
    const float* __restrict__ nW1, const float* __restrict__ nW2,
    unsigned short* __restrict__ Winp,
    unsigned short* __restrict__ Woutp, unsigned short* __restrict__ W1p,
    unsigned short* __restrict__ eW2p, unsigned short* __restrict__ nW1p,
    unsigned short* __restrict__ nW2p, float* __restrict__ biasP)
{
    long idx = (long)blockIdx.x * 256 + threadIdx.x;
    if (idx >= PACK_TOTAL) return;
    long j = idx;
    if (j < SW_IN) { pack_std(W_in, Winp, 128, j); return; }
    j -= SW_IN;
    if (j < SW_OUT) { pack_std(W_out, Woutp, 64, j); return; }
    j -= SW_OUT;
    int l = (int)(j / PERL);
    long r = j % PERL;
    if (r < SW1) {
        int i = (int)(r & 7);
        int n = (int)((r >> 3) & 127);
        int kb = (int)(r >> 10);
        int k = kb * 8 + i;
        const float* w = eW1 + (long)l * 256 * 64;
        float v = (n < 64) ? w[(long)k * 64 + n] : w[(long)(128 + k) * 64 + (n - 64)];
        W1p[(long)l * SW1 + r] = f2bf(v);
        return;
    }
    r -= SW1;
    if (r < SE2) { pack_std_h(eW2 + (long)l * 4096, eW2p + (long)l * SE2, 64, r); return; }
    r -= SE2;
    if (r < SN1) { pack_std(nW1 + (long)l * 24576, nW1p + (long)l * SN1, 128, r); return; }
    r -= SN1;
    if (r < SN2) { pack_std(nW2 + (long)l * 16384, nW2p + (long)l * SN2, 128, r); return; }
    r -= SN2;
    biasP[(long)l * 128 + r] = (r < 64) ? eb1[(long)l * 64 + r] : 0.0f;
}

// ---------------------------------------------------------------------------
// Edge-sort pipeline
// ---------------------------------------------------------------------------
__global__ __launch_bounds__(256) void hist_k(const int* __restrict__ erow,
                                              int* __restrict__ countB, int E) {
    __shared__ int c[NBKT];
    for (int i = threadIdx.x; i < NBKT; i += 256) c[i] = 0;
    __syncthreads();
    int j = blockIdx.x * BCHUNK + threadIdx.x;
    #pragma unroll
    for (int i = 0; i < BCHUNK / 256; i++, j += 256)
        if (j < E) atomicAdd(&c[erow[j] >> BSH], 1);
    __syncthreads();
    for (int i = threadIdx.x; i < NBKT; i += 256)
        if (c[i]) atomicAdd(&countB[i], c[i]);
}

__global__ __launch_bounds__(256) void bucket_scan_k(const int* __restrict__ countB,
                                                     int* __restrict__ bucketBase,
                                                     int* __restrict__ bucketCursor) {
    __shared__ int buf[256];
    int tid = threadIdx.x;
    int v = (tid < NBKT) ? countB[tid] : 0;
    int excl = block_excl_scan_256(v, buf);
    if (tid < NBKT) {
        bucketBase[tid] = excl;
        bucketCursor[tid] = excl;
    }
    if (tid == NBKT - 1) bucketBase[NBKT] = excl + v;   // = E
}

__global__ __launch_bounds__(256) void bin_k(
    const int* __restrict__ erow, const int* __restrict__ ecol,
    int* __restrict__ bucketCursor, int2* __restrict__ binned, int E)
{
    __shared__ int2 staged[BCHUNK];
    __shared__ int cnt[NBKT];
    __shared__ int binStart[NBKT];
    __shared__ int gbase[NBKT];
    __shared__ int scanbuf[256];
    const int tid = threadIdx.x;
    const int base = blockIdx.x * BCHUNK;
    const int nloc = min(BCHUNK, E - base);

    for (int i = tid; i < NBKT; i += 256) cnt[i] = 0;
    __syncthreads();

    int2 ed[BCHUNK / 256];
    int  bo[BCHUNK / 256];
    #pragma unroll
    for (int i = 0; i < BCHUNK / 256; i++) {
        int jl = i * 256 + tid;
        if (jl < nloc) {
            int j = base + jl;
            int r = erow[j], c = ecol[j];
            ed[i] = make_int2(r, c);
            int b = r >> BSH;
            int off = atomicAdd(&cnt[b], 1);
            bo[i] = (b << 12) | off;
        } else bo[i] = -1;
    }
    __syncthreads();

    int v = (tid < NBKT) ? cnt[tid] : 0;
    int excl = block_excl_scan_256(v, scanbuf);
    if (tid < NBKT) binStart[tid] = excl;
    if (tid < NBKT && v > 0) gbase[tid] = atomicAdd(&bucketCursor[tid], v);
    __syncthreads();

    #pragma unroll
    for (int i = 0; i < BCHUNK / 256; i++) {
        if (bo[i] >= 0)
            staged[binStart[bo[i] >> 12] + (bo[i] & 0xFFF)] = ed[i];
    }
    __syncthreads();

    for (int j = tid; j < nloc; j += 256) {
        int2 e = staged[j];
        int b = e.x >> BSH;
        binned[gbase[b] + (j - binStart[b])] = e;
    }
}

__global__ __launch_bounds__(256) void sort_k(
    const int2* __restrict__ binned, const int* __restrict__ bucketBase,
    int2* __restrict__ eidx)
{
    __shared__ int2 st[CAP];
    __shared__ int cnt[256];
    __shared__ int cur[256];
    __shared__ int scanbuf[256];
    const int b = blockIdx.x;
    const int tid = threadIdx.x;
    const int s0 = bucketBase[b];
    int n = bucketBase[b + 1] - s0;
    if (n > CAP) n = CAP;

    cnt[tid] = 0;
    __syncthreads();
    for (int j = tid; j < n; j += 256) {
        int2 e = binned[s0 + j];
        st[j] = e;
        atomicAdd(&cnt[e.x & 255], 1);
    }
    __syncthreads();
    int excl = block_excl_scan_256(cnt[tid], scanbuf);
    cur[tid] = excl;
    __syncthreads();
    for (int j = tid; j < n; j += 256) {
        int2 e = st[j];
        int pos = atomicAdd(&cur[e.x & 255], 1);
        eidx[s0 + pos] = e;
    }
}

// ---------------------------------------------------------------------------
// Fused edge + block-segmented aggregate over sorted edges.
// R15: M2 stored in LDS as f16 [el][66] (halved LDS + stores); reduction uses
// 8 groups x 32 feature-pair threads, one u32 load covers 2 features -> total
// reduction wave-cycles halve. Precision: agg is rounded to bf16 downstream,
// so f16 (10-bit) intermediate rounding is below the existing noise floor.
// ---------------------------------------------------------------------------
__global__ __launch_bounds__(256) void edge_fused_k(
    const int2* __restrict__ eidx,
    const unsigned short* __restrict__ P,    // [N,128] f16: 0..63 top(+b1), 64..127 bot
    const unsigned short* __restrict__ Bp,   // eW2 frag order, f16
    const float* __restrict__ b2, float* __restrict__ agg, int E)
{
    __shared__ unsigned short M2h[64 * 66];  // f16, [el][n] stride 66
    __shared__ int ridS[64];
    __shared__ short segStartS[66];
    __shared__ int nsegS;
    const int tid = threadIdx.x;
    const int wave = tid >> 6;
    const int lane = tid & 63;
    const int lrow = lane & 15;
    const int quad = lane >> 4;
    const int e0 = blockIdx.x * 64;
    const int el = wave * 16 + lrow;
    const int e = e0 + el;

    // bias preloaded into the MFMA accumulators
    floatx4 acc[4];
    #pragma unroll
    for (int nt = 0; nt < 4; nt++) {
        float bv = b2[nt * 16 + lrow];
        acc[nt] = (floatx4){bv, bv, bv, bv};
    }

    half8v af0 = {};
    half8v af1 = {};
    if (e < E) {
        int2 rc = eidx[e];
        int rr = rc.x, cc = rc.y;
        if (quad == 0) ridS[el] = rr;
        const uintx4* pt = (const uintx4*)(P + (size_t)rr * 128 + quad * 8);
        const uintx4* pb = (const uintx4*)(P + (size_t)cc * 128 + 64 + quad * 8);
        uintx4 t0 = pt[0], t1 = pt[4];
        uintx4 b0 = pb[0], b1 = pb[4];
        uintx4 O0, O1;
        #pragma unroll
        for (int i = 0; i < 4; i++) {
            O0[i] = h2u(silu_h2(__hadd2(u2h(t0[i]), u2h(b0[i]))));
            O1[i] = h2u(silu_h2(__hadd2(u2h(t1[i]), u2h(b1[i]))));
        }
        af0 = __builtin_bit_cast(half8v, O0);
        af1 = __builtin_bit_cast(half8v, O1);
    } else if (quad == 0) {
        ridS[el] = -1;
    }

    #pragma unroll
    for (int nt = 0; nt < 4; nt++) {
        half8v bf0 = *(const half8v*)(Bp + (size_t)((0 * 4 + quad) * 64 + nt * 16 + lrow) * 8);
        acc[nt] = __builtin_amdgcn_mfma_f32_16x16x32_f16(af0, bf0, acc[nt], 0, 0, 0);
        half8v bf1 = *(const half8v*)(Bp + (size_t)((1 * 4 + quad) * 64 + nt * 16 + lrow) * 8);
        acc[nt] = __builtin_amdgcn_mfma_f32_16x16x32_f16(af1, bf1, acc[nt], 0, 0, 0);
    }

    #pragma unroll
    for (int nt = 0; nt < 4; nt++) {
        int n = nt * 16 + lrow;
        #pragma unroll
        for (int r = 0; r < 4; r++) {
            int el2 = wave * 16 + quad * 4 + r;
            M2h[el2 * 66 + n] = f2fh(silu_f(acc[nt][r]));
        }
    }
    __syncthreads();

    if (tid < 64) {
        bool st = (ridS[tid] >= 0) && (tid == 0 || ridS[tid] != ridS[tid - 1]);
        unsigned long long m = __ballot(st);
        if (st) {
            int pos = __popcll(m & ((1ull << tid) - 1));
            segStartS[pos] = (short)tid;
        }
        if (tid == 0) {
            int ns = __popcll(m);
            nsegS = ns;
            int nvalid = E - e0;
            if (nvalid > 64) nvalid = 64;
            segStartS[ns] = (short)nvalid;
        }
    }
    __syncthreads();

    {
        int f2 = tid & 31;       // feature pair: features 2*f2, 2*f2+1
        int g = tid >> 5;        // 8 segment groups
        int ns = nsegS;
        for (int j = g; j < ns; j += 8) {
            int a = segStartS[j], b = segStartS[j + 1];
            float sx = 0.0f, sy = 0.0f;
            for (int el2 = a; el2 < b; el2++) {
                unsigned int v = *(const unsigned int*)(&M2h[el2 * 66 + 2 * f2]);
                __half2 h = u2h(v);
                sx += __low2float(h);
                sy += __high2float(h);
            }
            int rv = ridS[a];
            if (j == 0 || j == ns - 1) {
                atomicAdd(&agg[(size_t)rv * 64 + 2 * f2], sx);
                atomicAdd(&agg[(size_t)rv * 64 + 2 * f2 + 1], sy);
            } else {
                floatx2 s2 = {sx, sy};
                *(floatx2*)(&agg[(size_t)rv * 64 + 2 * f2]) = s2;
            }
        }
    }
}

// ---------------------------------------------------------------------------
// Fused node-side chain (R14 structure: residual from LDS bf16, no hFT).
// ---------------------------------------------------------------------------
#define SROW 264
template<int FINAL>
__global__ __launch_bounds__(512) void node_fused_k(
    const unsigned short* __restrict__ hbf, const float* __restrict__ agg,
    const unsigned short* __restrict__ W1, const float* __restrict__ b1,
    const unsigned short* __restrict__ W2, const float* __restrict__ b2,
    const unsigned short* __restrict__ B3, const float* __restrict__ bias3,
    unsigned short* __restrict__ hB, unsigned short* __restrict__ Pout,
    float* __restrict__ outF, float* __restrict__ aggZ, int M)
{
    __shared__ unsigned short S[64 * SROW];
    const int tid = threadIdx.x;
    const int m0 = blockIdx.x * 64;
    const int wave = tid >> 6;
    const int lane = tid & 63;
    const int lrow = lane & 15;
    const int quad = lane >> 4;
    const int g = wave >> 1;          // row group 0..3
    const int h = wave & 1;           // N half
    const int elb = g * 16 + quad * 4;

    // agg A-fragments straight into registers (kt=4,5 of the K=192 A-op)
    short8 afa0, afa1;
    {
        const float* ap = agg + (size_t)(m0 + g * 16 + lrow) * 64;
        floatx4 q0 = *(const floatx4*)(ap + quad * 8);
        floatx4 q1 = *(const floatx4*)(ap + quad * 8 + 4);
        floatx4 q2 = *(const floatx4*)(ap + 32 + quad * 8);
        floatx4 q3 = *(const floatx4*)(ap + 32 + quad * 8 + 4);
        unsigned int c0[4] = { f2bf_pk(q0[0], q0[1]), f2bf_pk(q0[2], q0[3]),
                               f2bf_pk(q1[0], q1[1]), f2bf_pk(q1[2], q1[3]) };
        unsigned int c1[4] = { f2bf_pk(q2[0], q2[1]), f2bf_pk(q2[2], q2[3]),
                               f2bf_pk(q3[0], q3[1]), f2bf_pk(q3[2], q3[3]) };
        afa0 = *(const short8*)c0;
        afa1 = *(const short8*)c1;
    }

    // staging: h (128 bf16) only -> S cols 0..127
    for (int t = tid; t < 64 * 16; t += 512) {
        int rr = t >> 4, c = t & 15;
        int row = m0 + rr;
        uintx4 val = {0, 0, 0, 0};
        if (row < M) val = *(const uintx4*)(hbf + (size_t)row * 128 + c * 8);
        *(uintx4*)(&S[rr * SROW + c * 8]) = val;
    }
    __syncthreads();   // B1

    // zero this block's agg rows for the next layer (replaces hipMemsetAsync)
    if (!FINAL) {
        floatx4 z = {0, 0, 0, 0};
        for (int t = tid; t < 64 * 16; t += 512) {
            int rr = t >> 4, c = t & 15;
            int row = m0 + rr;
            if (row < M) *(floatx4*)(aggZ + (size_t)row * 64 + c * 4) = z;
        }
    }

    const unsigned short* arow = &S[(g * 16 + lrow) * SROW];

    // ---- phase A MFMA: K=192 (kt 0..3 from LDS, kt 4..5 from registers) ----
    floatx4 acc[4];
    #pragma unroll
    for (int i = 0; i < 4; i++) acc[i] = (floatx4){0, 0, 0, 0};
    #pragma unroll
    for (int kt = 0; kt < 4; kt++) {
        short8 afrag = *(const short8*)(arow + kt * 32 + quad * 8);
        int kb = kt * 4 + quad;
        #pragma unroll
        for (int j = 0; j < 4; j++) {
            int n = (4 * h + j) * 16 + lrow;
            short8 bfrag = *(const short8*)(W1 + (size_t)(kb * 128 + n) * 8);
            acc[j] = __builtin_amdgcn_mfma_f32_16x16x32_bf16(afrag, bfrag, acc[j], 0, 0, 0);
        }
    }
    #pragma unroll
    for (int j = 0; j < 4; j++) {
        int n = (4 * h + j) * 16 + lrow;
        short8 b4 = *(const short8*)(W1 + (size_t)((16 + quad) * 128 + n) * 8);
        acc[j] = __builtin_amdgcn_mfma_f32_16x16x32_bf16(afa0, b4, acc[j], 0, 0, 0);
        short8 b5 = *(const short8*)(W1 + (size_t)((20 + quad) * 128 + n) * 8);
        acc[j] = __builtin_amdgcn_mfma_f32_16x16x32_bf16(afa1, b5, acc[j], 0, 0, 0);
    }

    // epilogue A: t -> S cols 128..255
    #pragma unroll
    for (int j = 0; j < 4; j++) {
        int n = (4 * h + j) * 16 + lrow;
        float bv = b1[n];
        unsigned int p01 = f2bf_pk(silu_f(acc[j][0] + bv), silu_f(acc[j][1] + bv));
        unsigned int p23 = f2bf_pk(silu_f(acc[j][2] + bv), silu_f(acc[j][3] + bv));
        S[(elb + 0) * SROW + 128 + n] = (unsigned short)(p01 & 0xFFFF);
        S[(elb + 1) * SROW + 128 + n] = (unsigned short)(p01 >> 16);
        S[(elb + 2) * SROW + 128 + n] = (unsigned short)(p23 & 0xFFFF);
        S[(elb + 3) * SROW + 128 + n] = (unsigned short)(p23 >> 16);
    }
    __syncthreads();   // B2: t complete

    // ---- phase B MFMA: K=128 over t (cols 128..255) ----
    floatx4 acc2[4];
    #pragma unroll
    for (int i = 0; i < 4; i++) acc2[i] = (floatx4){0, 0, 0, 0};
    #pragma unroll
    for (int kt = 0; kt < 4; kt++) {
        short8 afrag = *(const short8*)(arow + 128 + kt * 32 + quad * 8);
        int kb = kt * 4 + quad;
        #pragma unroll
        for (int j = 0; j < 4; j++) {
            int n = (4 * h + j) * 16 + lrow;
            short8 bfrag = *(const short8*)(W2 + (size_t)(kb * 128 + n) * 8);
            acc2[j] = __builtin_amdgcn_mfma_f32_16x16x32_bf16(afrag, bfrag, acc2[j], 0, 0, 0);
        }
    }

    // epilogue B: h_new = acc2 + b2 + res(LDS bf16, owner cells) -> S cols 0..127
    #pragma unroll
    for (int j = 0; j < 4; j++) {
        int n = (4 * h + j) * 16 + lrow;
        float bv = b2[n];
        floatx4 v4;
        #pragma unroll
        for (int r = 0; r < 4; r++) {
            float res = bf2f(S[(elb + r) * SROW + n]);
            v4[r] = acc2[j][r] + bv + res;
        }
        unsigned int p01 = f2bf_pk(v4[0], v4[1]);
        unsigned int p23 = f2bf_pk(v4[2], v4[3]);
        S[(elb + 0) * SROW + n] = (unsigned short)(p01 & 0xFFFF);
        S[(elb + 1) * SROW + n] = (unsigned short)(p01 >> 16);
        S[(elb + 2) * SROW + n] = (unsigned short)(p23 & 0xFFFF);
        S[(elb + 3) * SROW + n] = (unsigned short)(p23 >> 16);
    }
    __syncthreads();   // B3: h_new complete (all t reads done)

    // ---- phase C MFMA: K=128 -> P (128, f16) or out (64, f32) ----
    constexpr int NT3 = FINAL ? 2 : 4;
    constexpr int NO3 = FINAL ? 64 : 128;
    floatx4 acc3[NT3];
    #pragma unroll
    for (int i = 0; i < NT3; i++) acc3[i] = (floatx4){0, 0, 0, 0};
    #pragma unroll
    for (int kt = 0; kt < 4; kt++) {
        short8 afrag = *(const short8*)(arow + kt * 32 + quad * 8);
        int kb = kt * 4 + quad;
        #pragma unroll
        for (int j = 0; j < NT3; j++) {
            int n = (NT3 * h + j) * 16 + lrow;
            short8 bfrag = *(const short8*)(B3 + (size_t)(kb * NO3 + n) * 8);
            acc3[j] = __builtin_amdgcn_mfma_f32_16x16x32_bf16(afrag, bfrag, acc3[j], 0, 0, 0);
        }
    }
    // epilogue C -> S cols 128..255 (f16 P) or fp32 out region (same cols)
    #pragma unroll
    for (int j = 0; j < NT3; j++) {
        int n = (NT3 * h + j) * 16 + lrow;
        float bv = bias3[n];
        if (FINAL) {
            #pragma unroll
            for (int r = 0; r < 4; r++)
                ((float*)(&S[(elb + r) * SROW + 128]))[n] = acc3[j][r] + bv;
        } else {
            unsigned int p01 = f2fh_pk(acc3[j][0] + bv, acc3[j][1] + bv);
            unsigned int p23 = f2fh_pk(acc3[j][2] + bv, acc3[j][3] + bv);
            S[(elb + 0) * SROW + 128 + n] = (unsigned short)(p01 & 0xFFFF);
            S[(elb + 1) * SROW + 128 + n] = (unsigned short)(p01 >> 16);
            S[(elb + 2) * SROW + 128 + n] = (unsigned short)(p23 & 0xFFFF);
            S[(elb + 3) * SROW + 128 + n] = (unsigned short)(p23 >> 16);
        }
    }
    __syncthreads();   // B4

    // cooperative wide stores
    if (FINAL) {
        for (int t = tid; t < 64 * 16; t += 512) {
            int rr = t >> 4, c = t & 15;
            int row = m0 + rr;
            if (row < M)
                *(floatx4*)(outF + (size_t)row * 64 + c * 4) =
                    *(const floatx4*)((const float*)(&S[rr * SROW + 128]) + c * 4);
        }
    } else {
        for (int t = tid; t < 64 * 32; t += 512) {
            int rr = t >> 5, c = t & 31;
            int row = m0 + rr;
            if (row < M) {
                if (c < 16)
                    *(uintx4*)(hB + (size_t)row * 128 + c * 8) =
                        *(const uintx4*)(&S[rr * SROW + c * 8]);
                else
                    *(uintx4*)(Pout + (size_t)row * 128 + (c - 16) * 8) =
                        *(const uintx4*)(&S[rr * SROW + 128 + (c - 16) * 8]);
            }
        }
    }
}

// ---------------------------------------------------------------------------
// Fused embedding (256 thr, wave-private rows); P output f16.
// R15: reads h0 f32 directly, converts to bf16 during LDS staging.
// ---------------------------------------------------------------------------
#define SROWE 264
__global__ __launch_bounds__(256) void embed_fused_k(
    const float* __restrict__ h0, const unsigned short* __restrict__ Win,
    const float* __restrict__ b_in, const unsigned short* __restrict__ W1,
    const float* __restrict__ biasP,
    unsigned short* __restrict__ hB, unsigned short* __restrict__ Pout, int M)
{
    __shared__ unsigned short S[64 * SROWE];
    const int tid = threadIdx.x;
    const int m0 = blockIdx.x * 64;
    const int wave = tid >> 6;
    const int lane = tid & 63;
    const int lrow = lane & 15;
    const int quad = lane >> 4;
    const int elb = wave * 16 + quad * 4;

    // staging: h0 f32 -> bf16 into S cols 0..63
    for (int t = tid; t < 64 * 16; t += 256) {
        int rr = t >> 4, c = t & 15;
        int row = m0 + rr;
        floatx4 v = {0, 0, 0, 0};
        if (row < M) v = *(const floatx4*)(h0 + (size_t)row * 64 + c * 4);
        uintx2 u = { f2bf_pk(v[0], v[1]), f2bf_pk(v[2], v[3]) };
        *(uintx2*)(&S[rr * SROWE + c * 4]) = u;
    }
    __syncthreads();   // barrier 1

    const unsigned short* arow = &S[(wave * 16 + lrow) * SROWE];

    floatx4 acc[8];
    #pragma unroll
    for (int i = 0; i < 8; i++) acc[i] = (floatx4){0, 0, 0, 0};
    #pragma unroll
    for (int kt = 0; kt < 2; kt++) {
        short8 afrag = *(const short8*)(arow + kt * 32 + quad * 8);
        int kb = kt * 4 + quad;
        #pragma unroll
        for (int nt = 0; nt < 8; nt++) {
            short8 bfrag = *(const short8*)(Win + (size_t)(kb * 128 + nt * 16 + lrow) * 8);
            acc[nt] = __builtin_amdgcn_mfma_f32_16x16x32_bf16(afrag, bfrag, acc[nt], 0, 0, 0);
        }
    }

    // epilogue: h1 -> S cols 0..127 (bf16)
    #pragma unroll
    for (int nt = 0; nt < 8; nt++) {
        int n = nt * 16 + lrow;
        float bv = b_in[n];
        floatx4 v4;
        #pragma unroll
        for (int r = 0; r < 4; r++) v4[r] = acc[nt][r] + bv;
        unsigned int p01 = f2bf_pk(v4[0], v4[1]);
        unsigned int p23 = f2bf_pk(v4[2], v4[3]);
        S[(elb + 0) * SROWE + n] = (unsigned short)(p01 & 0xFFFF);
        S[(elb + 1) * SROWE + n] = (unsigned short)(p01 >> 16);
        S[(elb + 2) * SROWE + n] = (unsigned short)(p23 & 0xFFFF);
        S[(elb + 3) * SROWE + n] = (unsigned short)(p23 >> 16);
    }

    floatx4 acc3[8];
    #pragma unroll
    for (int i = 0; i < 8; i++) acc3[i] = (floatx4){0, 0, 0, 0};
    #pragma unroll
    for (int kt = 0; kt < 4; kt++) {
        short8 afrag = *(const short8*)(arow + kt * 32 + quad * 8);
        int kb = kt * 4 + quad;
        #pragma unroll
        for (int nt = 0; nt < 8; nt++) {
            short8 bfrag = *(const short8*)(W1 + (size_t)(kb * 128 + nt * 16 + lrow) * 8);
            acc3[nt] = __builtin_amdgcn_mfma_f32_16x16x32_bf16(afrag, bfrag, acc3[nt], 0, 0, 0);
        }
    }
    #pragma unroll
    for (int nt = 0; nt < 8; nt++) {
        int n = nt * 16 + lrow;
        float bv = biasP[n];
        unsigned int p01 = f2fh_pk(acc3[nt][0] + bv, acc3[nt][1] + bv);
        unsigned int p23 = f2fh_pk(acc3[nt][2] + bv, acc3[nt][3] + bv);
        S[(elb + 0) * SROWE + 128 + n] = (unsigned short)(p01 & 0xFFFF);
        S[(elb + 1) * SROWE + 128 + n] = (unsigned short)(p01 >> 16);
        S[(elb + 2) * SROWE + 128 + n] = (unsigned short)(p23 & 0xFFFF);
        S[(elb + 3) * SROWE + 128 + n] = (unsigned short)(p23 >> 16);
    }
    __syncthreads();   // barrier 2

    for (int t = tid; t < 64 * 32; t += 256) {
        int rr = t / 32, c = t % 32;
        int row = m0 + rr;
        if (row < M) {
            if (c < 16)
                *(uintx4*)(hB + (size_t)row * 128 + c * 8) =
                    *(const uintx4*)(&S[rr * SROWE + c * 8]);
            else
                *(uintx4*)(Pout + (size_t)row * 128 + (c - 16) * 8) =
                    *(const uintx4*)(&S[rr * SROWE + 128 + (c - 16) * 8]);
        }
    }
}

// ---------------------------------------------------------------------------
extern "C" void kernel_launch(void* const* d_in, const int* in_sizes, int n_in,
                              void* d_out, int out_size, void* d_ws, size_t ws_size,
                              hipStream_t stream) {
    const float* h0   = (const float*)d_in[0];
    const int*   edges= (const int*)d_in[1];
    const float* W_in = (const float*)d_in[2];
    const float* b_in = (const float*)d_in[3];
    const float* eW1  = (const float*)d_in[4];
    const float* eb1  = (const float*)d_in[5];
    const float* eW2  = (const float*)d_in[6];
    const float* eb2  = (const float*)d_in[7];
    const float* nW1  = (const float*)d_in[8];
    const float* nb1  = (const float*)d_in[9];
    const float* nW2  = (const float*)d_in[10];
    const float* nb2  = (const float*)d_in[11];
    const float* W_out= (const float*)d_in[12];
    const float* b_out= (const float*)d_in[13];
    float* out = (float*)d_out;

    const int E = in_sizes[1] / 2;      // 800000
    const int* erow = edges;
    const int* ecol = edges + E;

    char* ws = (char*)d_ws;
    unsigned short* hbf  = (unsigned short*)(ws + 0);            // 12,800,000
    // (ws+12800000..38424576 free)
    unsigned short* P    = (unsigned short*)(ws + 38424576);     // 12,800,000 (f16)
    float*          agg  = (float*)(ws + 51224576);              // 12,800,000
    int2*           binned=(int2*)(ws + 51224576);               //  6,400,000 (aliases agg; consumed pre-zero)
    int2*           eidx = (int2*)(ws + 76824576);               //  6,400,000
    float*          biasP= (float*)(ws + 83224576);              //  2,048
    unsigned short* Winp = (unsigned short*)(ws + 83226624);     // 16,384
    unsigned short* Woutp= (unsigned short*)(ws + 83243008);     // 16,384
    unsigned short* W1p  = (unsigned short*)(ws + 83259392);     // 131,072
    unsigned short* eW2p = (unsigned short*)(ws + 83390464);     // 32,768 (f16)
    unsigned short* nW1p = (unsigned short*)(ws + 83423232);     // 196,608
    unsigned short* nW2p = (unsigned short*)(ws + 83619840);     // 131,072
    int*            countB=(int*)(ws + 83750912);                // 784
    int*            bucketBase=(int*)(ws + 83751936);            // 788
    int*            bucketCursor=(int*)(ws + 83752960);          // 784

    const int gemm_grid = (N_NODES + 63) / 64;    // 782
    const int edge_grid = (E + 63) / 64;          // 12500
    const int pack_grid = (int)((PACK_TOTAL + 255) / 256);
    const int bin_grid  = (E + BCHUNK - 1) / BCHUNK;   // 391

    hipMemsetAsync(countB, 0, NBKT * 4, stream);
    pack_kernel<<<pack_grid, 256, 0, stream>>>(W_in, W_out, eW1, eb1, eW2,
                                               nW1, nW2, Winp, Woutp, W1p,
                                               eW2p, nW1p, nW2p, biasP);

    // binning before embed (binned aliases agg, unused until layers)
    hist_k<<<bin_grid, 256, 0, stream>>>(erow, countB, E);
    bucket_scan_k<<<1, 256, 0, stream>>>(countB, bucketBase, bucketCursor);
    bin_k<<<bin_grid, 256, 0, stream>>>(erow, ecol, bucketCursor, binned, E);
    sort_k<<<NBKT, 256, 0, stream>>>(binned, bucketBase, eidx);

    // h1 = h0 @ W_in + b_in; P0 = h1 @ W1'[0]
    embed_fused_k<<<gemm_grid, 256, 0, stream>>>(
        h0, Winp, b_in, W1p, biasP, hbf, P, N_NODES);

    // single agg zero for layer 0 (subsequent layers zeroed by node_fused)
    hipMemsetAsync(agg, 0, (size_t)N_NODES * 64 * 4, stream);

    for (int l = 0; l < 4; l++) {
        edge_fused_k<<<edge_grid, 256, 0, stream>>>(
            eidx, P, eW2p + (size_t)l * SE2, eb2 + (size_t)l * 64, agg, E);
        if (l < 3) {
            node_fused_k<0><<<gemm_grid, 512, 0, stream>>>(
                hbf, agg, nW1p + (size_t)l * SN1, nb1 + (size_t)l * 128,
                nW2p + (size_t)l * SN2, nb2 + (size_t)l * 128,
                W1p + (size_t)(l + 1) * SW1, biasP + (size_t)(l + 1) * 128,
                hbf, P, nullptr, agg, N_NODES);
        } else {
            node_fused_k<1><<<gemm_grid, 512, 0, stream>>>(
                hbf, agg, nW1p + (size_t)l * SN1, nb1 + (size_t)l * 128,
                nW2p + (size_t)l * SN2, nb2 + (size_t)l * 128,
                Woutp, b_out, nullptr, nullptr, out, nullptr, N_NODES);
        }
    }
}

// Round 7
// 411.456 us; speedup vs baseline: 1.0046x; 1.0046x over previous
//
#include <hip/hip_runtime.h>
#include <hip/hip_bf16.h>
#include <hip/hip_fp16.h>
#include <cstdint>
#include <cstddef>

#define N_NODES 50000
#define N_EDGES 800000
#define NBKT    196      // ceil(50000/256) buckets of 256 rows
#define BSH     8        // rows-per-bucket shift
#define BCHUNK  2048     // edges per bin_k block
#define CAP     6144     // max edges per bucket (mean 4082)

typedef __attribute__((ext_vector_type(8))) short short8;
typedef __attribute__((ext_vector_type(4))) float floatx4;
typedef __attribute__((ext_vector_type(2))) float floatx2;
typedef __attribute__((ext_vector_type(4))) unsigned int uintx4;
typedef __attribute__((ext_vector_type(2))) unsigned int uintx2;
typedef __attribute__((ext_vector_type(8))) _Float16 half8v;

__device__ inline float bf2f(unsigned short u) {
    union { unsigned int i; float f; } v; v.i = ((unsigned int)u) << 16; return v.f;
}
__device__ inline unsigned short f2bf(float f) {
    union { float f; unsigned int i; } v; v.f = f;
    unsigned int u = v.i;
    return (unsigned short)((u + 0x7FFFu + ((u >> 16) & 1u)) >> 16);
}
// packed RNE f32x2 -> bf16x2 (v_cvt_pk_bf16_f32 on gfx950)
__device__ inline unsigned int f2bf_pk(float a, float b) {
    __hip_bfloat162 h2 = __float22bfloat162_rn(make_float2(a, b));
    return *reinterpret_cast<unsigned int*>(&h2);
}
// f16 helpers (edge path is f16: packed ALU + mfma_f32_16x16x32_f16)
__device__ inline unsigned short f2fh(float f) {
    _Float16 h = (_Float16)f;
    return __builtin_bit_cast(unsigned short, h);
}
// packed f32x2 -> f16x2 via v_cvt_pkrtz_f16_f32 (1 instr)
// NOTE: builtin returns __fp16 ext_vector_type(2) on this clang — bit_cast it.
__device__ inline unsigned int f2fh_pk(float a, float b) {
    typedef __attribute__((ext_vector_type(2))) __fp16 h2v;
    h2v r = __builtin_amdgcn_cvt_pkrtz(a, b);
    return __builtin_bit_cast(unsigned int, r);
}
__device__ inline __half2 u2h(unsigned int u) { return __builtin_bit_cast(__half2, u); }
__device__ inline unsigned int h2u(__half2 h) { return __builtin_bit_cast(unsigned int, h); }
// f16 SiLU on a packed pair.
__device__ inline __half2 silu_h2(__half2 x) {
    const __half2 nlog2e = __float2half2_rn(-1.4426950408889634f);
    const __half2 one    = __float2half2_rn(1.0f);
    __half2 e = h2exp2(__hmul2(x, nlog2e));
    return __hmul2(x, h2rcp(__hadd2(e, one)));
}
// silu via v_rcp_f32 (1 ulp) instead of IEEE divide
__device__ inline float silu_f(float x) {
    float e = __expf(-x);
    return x * __builtin_amdgcn_rcpf(1.0f + e);
}

__device__ inline int block_excl_scan_256(int v, int* buf) {
    int tid = threadIdx.x;
    buf[tid] = v;
    __syncthreads();
    #pragma unroll
    for (int off = 1; off < 256; off <<= 1) {
        int t = (tid >= off) ? buf[tid - off] : 0;
        __syncthreads();
        buf[tid] += t;
        __syncthreads();
    }
    return buf[tid] - v;
}

// ---------------------------------------------------------------------------
// Pack kernel: fp32->bf16/f16 weight rearrangement into MFMA fragment order.
// B-fragment order: Bp[(kb*NOUT + n)*8 + i] = B[(kb*8+i)*NOUT + n]
// ---------------------------------------------------------------------------
__device__ inline void pack_std(const float* __restrict__ src,
                                unsigned short* __restrict__ dst,
                                int NOUT, long j) {
    int i = (int)(j & 7);
    long rest = j >> 3;
    int n = (int)(rest % NOUT);
    int kb = (int)(rest / NOUT);
    dst[j] = f2bf(src[(long)(kb * 8 + i) * NOUT + n]);
}
__device__ inline void pack_std_h(const float* __restrict__ src,
                                  unsigned short* __restrict__ dst,
                                  int NOUT, long j) {
    int i = (int)(j & 7);
    long rest = j >> 3;
    int n = (int)(rest % NOUT);
    int kb = (int)(rest / NOUT);
    dst[j] = f2fh(src[(long)(kb * 8 + i) * NOUT + n]);
}

#define SW_IN 8192L
#define SW_OUT 8192L
#define SW1   16384L
#define SE2   4096L
#define SN1   24576L
#define SN2   16384L
#define SB    128L
#define PERL  (SW1 + SE2 + SN1 + SN2 + SB)
#define PACK_TOTAL (SW_IN + SW_OUT + 4 * PERL)

__global__ __launch_bounds__(256) void pack_kernel(
    const float* __restrict__ W_in,
    const float* __restrict__ W_out, const float* __restrict__ eW1,
    const float* __restrict__ eb1, const float* __restrict__ eW2,
    const float* __restrict__ nW1, const float* __restrict__ nW2,
    unsigned short* __restrict__ Winp,
    unsigned short* __restrict__ Woutp, unsigned short* __restrict__ W1p,
    unsigned short* __restrict__ eW2p, unsigned short* __restrict__ nW1p,
    unsigned short* __restrict__ nW2p, float* __restrict__ biasP)
{
    long idx = (long)blockIdx.x * 256 + threadIdx.x;
    if (idx >= PACK_TOTAL) return;
    long j = idx;
    if (j < SW_IN) { pack_std(W_in, Winp, 128, j); return; }
    j -= SW_IN;
    if (j < SW_OUT) { pack_std(W_out, Woutp, 64, j); return; }
    j -= SW_OUT;
    int l = (int)(j / PERL);
    long r = j % PERL;
    if (r < SW1) {
        int i = (int)(r & 7);
        int n = (int)((r >> 3) & 127);
        int kb = (int)(r >> 10);
        int k = kb * 8 + i;
        const float* w = eW1 + (long)l * 256 * 64;
        float v = (n < 64) ? w[(long)k * 64 + n] : w[(long)(128 + k) * 64 + (n - 64)];
        W1p[(long)l * SW1 + r] = f2bf(v);
        return;
    }
    r -= SW1;
    if (r < SE2) { pack_std_h(eW2 + (long)l * 4096, eW2p + (long)l * SE2, 64, r); return; }
    r -= SE2;
    if (r < SN1) { pack_std(nW1 + (long)l * 24576, nW1p + (long)l * SN1, 128, r); return; }
    r -= SN1;
    if (r < SN2) { pack_std(nW2 + (long)l * 16384, nW2p + (long)l * SN2, 128, r); return; }
    r -= SN2;
    biasP[(long)l * 128 + r] = (r < 64) ? eb1[(long)l * 64 + r] : 0.0f;
}

// ---------------------------------------------------------------------------
// Edge-sort pipeline
// ---------------------------------------------------------------------------
__global__ __launch_bounds__(256) void hist_k(const int* __restrict__ erow,
                                              int* __restrict__ countB, int E) {
    __shared__ int c[NBKT];
    for (int i = threadIdx.x; i < NBKT; i += 256) c[i] = 0;
    __syncthreads();
    int j = blockIdx.x * BCHUNK + threadIdx.x;
    #pragma unroll
    for (int i = 0; i < BCHUNK / 256; i++, j += 256)
        if (j < E) atomicAdd(&c[erow[j] >> BSH], 1);
    __syncthreads();
    for (int i = threadIdx.x; i < NBKT; i += 256)
        if (c[i]) atomicAdd(&countB[i], c[i]);
}

__global__ __launch_bounds__(256) void bucket_scan_k(const int* __restrict__ countB,
                                                     int* __restrict__ bucketBase,
                                                     int* __restrict__ bucketCursor) {
    __shared__ int buf[256];
    int tid = threadIdx.x;
    int v = (tid < NBKT) ? countB[tid] : 0;
    int excl = block_excl_scan_256(v, buf);
    if (tid < NBKT) {
        bucketBase[tid] = excl;
        bucketCursor[tid] = excl;
    }
    if (tid == NBKT - 1) bucketBase[NBKT] = excl + v;   // = E
}

__global__ __launch_bounds__(256) void bin_k(
    const int* __restrict__ erow, const int* __restrict__ ecol,
    int* __restrict__ bucketCursor, int2* __restrict__ binned, int E)
{
    __shared__ int2 staged[BCHUNK];
    __shared__ int cnt[NBKT];
    __shared__ int binStart[NBKT];
    __shared__ int gbase[NBKT];
    __shared__ int scanbuf[256];
    const int tid = threadIdx.x;
    const int base = blockIdx.x * BCHUNK;
    const int nloc = min(BCHUNK, E - base);

    for (int i = tid; i < NBKT; i += 256) cnt[i] = 0;
    __syncthreads();

    int2 ed[BCHUNK / 256];
    int  bo[BCHUNK / 256];
    #pragma unroll
    for (int i = 0; i < BCHUNK / 256; i++) {
        int jl = i * 256 + tid;
        if (jl < nloc) {
            int j = base + jl;
            int r = erow[j], c = ecol[j];
            ed[i] = make_int2(r, c);
            int b = r >> BSH;
            int off = atomicAdd(&cnt[b], 1);
            bo[i] = (b << 12) | off;
        } else bo[i] = -1;
    }
    __syncthreads();

    int v = (tid < NBKT) ? cnt[tid] : 0;
    int excl = block_excl_scan_256(v, scanbuf);
    if (tid < NBKT) binStart[tid] = excl;
    if (tid < NBKT && v > 0) gbase[tid] = atomicAdd(&bucketCursor[tid], v);
    __syncthreads();

    #pragma unroll
    for (int i = 0; i < BCHUNK / 256; i++) {
        if (bo[i] >= 0)
            staged[binStart[bo[i] >> 12] + (bo[i] & 0xFFF)] = ed[i];
    }
    __syncthreads();

    for (int j = tid; j < nloc; j += 256) {
        int2 e = staged[j];
        int b = e.x >> BSH;
        binned[gbase[b] + (j - binStart[b])] = e;
    }
}

__global__ __launch_bounds__(256) void sort_k(
    const int2* __restrict__ binned, const int* __restrict__ bucketBase,
    int2* __restrict__ eidx)
{
    __shared__ int2 st[CAP];
    __shared__ int cnt[256];
    __shared__ int cur[256];
    __shared__ int scanbuf[256];
    const int b = blockIdx.x;
    const int tid = threadIdx.x;
    const int s0 = bucketBase[b];
    int n = bucketBase[b + 1] - s0;
    if (n > CAP) n = CAP;

    cnt[tid] = 0;
    __syncthreads();
    for (int j = tid; j < n; j += 256) {
        int2 e = binned[s0 + j];
        st[j] = e;
        atomicAdd(&cnt[e.x & 255], 1);
    }
    __syncthreads();
    int excl = block_excl_scan_256(cnt[tid], scanbuf);
    cur[tid] = excl;
    __syncthreads();
    for (int j = tid; j < n; j += 256) {
        int2 e = st[j];
        int pos = atomicAdd(&cur[e.x & 255], 1);
        eidx[s0 + pos] = e;
    }
}

// ---------------------------------------------------------------------------
// Fused edge + block-segmented aggregate over sorted edges.
// R16: REVERT to the R5-verified reduction (f32 M2s [el][68], segStartS,
// 4x64-group walk — 0 bank conflicts, coalesced stores/atomics) after R6's
// f16-M2 relayout regressed (1.6M conflicts, +6MB WRITE). Forward lever:
// bijective XCD-aware block swizzle (edges sorted by row => consecutive
// blocks gather overlapping P rows; chunking blocks per XCD makes the
// gather L2-local, cutting gather latency).
// ---------------------------------------------------------------------------
__global__ __launch_bounds__(256) void edge_fused_k(
    const int2* __restrict__ eidx,
    const unsigned short* __restrict__ P,    // [N,128] f16: 0..63 top(+b1), 64..127 bot
    const unsigned short* __restrict__ Bp,   // eW2 frag order, f16
    const float* __restrict__ b2, float* __restrict__ agg, int E, int nwg)
{
    __shared__ float M2s[64 * 68];
    __shared__ int ridS[64];
    __shared__ short segStartS[66];
    __shared__ int nsegS;
    const int tid = threadIdx.x;
    const int wave = tid >> 6;
    const int lane = tid & 63;
    const int lrow = lane & 15;
    const int quad = lane >> 4;

    // bijective XCD swizzle (m204): 8 XCDs, nwg % 8 may be != 0
    int bid;
    {
        int q = nwg >> 3, r = nwg & 7;
        int xcd = blockIdx.x & 7, idx = blockIdx.x >> 3;
        bid = (xcd < r ? xcd * (q + 1) : r * (q + 1) + (xcd - r) * q) + idx;
    }
    const int e0 = bid * 64;
    const int el = wave * 16 + lrow;
    const int e = e0 + el;

    // bias preloaded into the MFMA accumulators
    floatx4 acc[4];
    #pragma unroll
    for (int nt = 0; nt < 4; nt++) {
        float bv = b2[nt * 16 + lrow];
        acc[nt] = (floatx4){bv, bv, bv, bv};
    }

    half8v af0 = {};
    half8v af1 = {};
    if (e < E) {
        int2 rc = eidx[e];
        int rr = rc.x, cc = rc.y;
        if (quad == 0) ridS[el] = rr;
        const uintx4* pt = (const uintx4*)(P + (size_t)rr * 128 + quad * 8);
        const uintx4* pb = (const uintx4*)(P + (size_t)cc * 128 + 64 + quad * 8);
        uintx4 t0 = pt[0], t1 = pt[4];
        uintx4 b0 = pb[0], b1 = pb[4];
        uintx4 O0, O1;
        #pragma unroll
        for (int i = 0; i < 4; i++) {
            O0[i] = h2u(silu_h2(__hadd2(u2h(t0[i]), u2h(b0[i]))));
            O1[i] = h2u(silu_h2(__hadd2(u2h(t1[i]), u2h(b1[i]))));
        }
        af0 = __builtin_bit_cast(half8v, O0);
        af1 = __builtin_bit_cast(half8v, O1);
    } else if (quad == 0) {
        ridS[el] = -1;
    }

    #pragma unroll
    for (int nt = 0; nt < 4; nt++) {
        half8v bf0 = *(const half8v*)(Bp + (size_t)((0 * 4 + quad) * 64 + nt * 16 + lrow) * 8);
        acc[nt] = __builtin_amdgcn_mfma_f32_16x16x32_f16(af0, bf0, acc[nt], 0, 0, 0);
        half8v bf1 = *(const half8v*)(Bp + (size_t)((1 * 4 + quad) * 64 + nt * 16 + lrow) * 8);
        acc[nt] = __builtin_amdgcn_mfma_f32_16x16x32_f16(af1, bf1, acc[nt], 0, 0, 0);
    }

    #pragma unroll
    for (int nt = 0; nt < 4; nt++) {
        int n = nt * 16 + lrow;
        #pragma unroll
        for (int r = 0; r < 4; r++) {
            int el2 = wave * 16 + quad * 4 + r;
            M2s[el2 * 68 + n] = silu_f(acc[nt][r]);
        }
    }
    __syncthreads();

    if (tid < 64) {
        bool st = (ridS[tid] >= 0) && (tid == 0 || ridS[tid] != ridS[tid - 1]);
        unsigned long long m = __ballot(st);
        if (st) {
            int pos = __popcll(m & ((1ull << tid) - 1));
            segStartS[pos] = (short)tid;
        }
        if (tid == 0) {
            int ns = __popcll(m);
            nsegS = ns;
            int nvalid = E - e0;
            if (nvalid > 64) nvalid = 64;
            segStartS[ns] = (short)nvalid;
        }
    }
    __syncthreads();

    {
        int f = tid & 63;
        int g = tid >> 6;
        int ns = nsegS;
        for (int j = g; j < ns; j += 4) {
            int a = segStartS[j], b = segStartS[j + 1];
            float s = 0.0f;
            for (int el2 = a; el2 < b; el2++) s += M2s[el2 * 68 + f];
            int rv = ridS[a];
            if (j == 0 || j == ns - 1)
                atomicAdd(&agg[(size_t)rv * 64 + f], s);
            else
                agg[(size_t)rv * 64 + f] = s;
        }
    }
}

// ---------------------------------------------------------------------------
// Fused node-side chain (R14 structure: residual from LDS bf16, no hFT).
// ---------------------------------------------------------------------------
#define SROW 264
template<int FINAL>
__global__ __launch_bounds__(512) void node_fused_k(
    const unsigned short* __restrict__ hbf, const float* __restrict__ agg,
    const unsigned short* __restrict__ W1, const float* __restrict__ b1,
    const unsigned short* __restrict__ W2, const float* __restrict__ b2,
    const unsigned short* __restrict__ B3, const float* __restrict__ bias3,
    unsigned short* __restrict__ hB, unsigned short* __restrict__ Pout,
    float* __restrict__ outF, float* __restrict__ aggZ, int M)
{
    __shared__ unsigned short S[64 * SROW];
    const int tid = threadIdx.x;
    const int m0 = blockIdx.x * 64;
    const int wave = tid >> 6;
    const int lane = tid & 63;
    const int lrow = lane & 15;
    const int quad = lane >> 4;
    const int g = wave >> 1;          // row group 0..3
    const int h = wave & 1;           // N half
    const int elb = g * 16 + quad * 4;

    // agg A-fragments straight into registers (kt=4,5 of the K=192 A-op)
    short8 afa0, afa1;
    {
        const float* ap = agg + (size_t)(m0 + g * 16 + lrow) * 64;
        floatx4 q0 = *(const floatx4*)(ap + quad * 8);
        floatx4 q1 = *(const floatx4*)(ap + quad * 8 + 4);
        floatx4 q2 = *(const floatx4*)(ap + 32 + quad * 8);
        floatx4 q3 = *(const floatx4*)(ap + 32 + quad * 8 + 4);
        unsigned int c0[4] = { f2bf_pk(q0[0], q0[1]), f2bf_pk(q0[2], q0[3]),
                               f2bf_pk(q1[0], q1[1]), f2bf_pk(q1[2], q1[3]) };
        unsigned int c1[4] = { f2bf_pk(q2[0], q2[1]), f2bf_pk(q2[2], q2[3]),
                               f2bf_pk(q3[0], q3[1]), f2bf_pk(q3[2], q3[3]) };
        afa0 = *(const short8*)c0;
        afa1 = *(const short8*)c1;
    }

    // staging: h (128 bf16) only -> S cols 0..127
    for (int t = tid; t < 64 * 16; t += 512) {
        int rr = t >> 4, c = t & 15;
        int row = m0 + rr;
        uintx4 val = {0, 0, 0, 0};
        if (row < M) val = *(const uintx4*)(hbf + (size_t)row * 128 + c * 8);
        *(uintx4*)(&S[rr * SROW + c * 8]) = val;
    }
    __syncthreads();   // B1

    // zero this block's agg rows for the next layer (replaces hipMemsetAsync)
    if (!FINAL) {
        floatx4 z = {0, 0, 0, 0};
        for (int t = tid; t < 64 * 16; t += 512) {
            int rr = t >> 4, c = t & 15;
            int row = m0 + rr;
            if (row < M) *(floatx4*)(aggZ + (size_t)row * 64 + c * 4) = z;
        }
    }

    const unsigned short* arow = &S[(g * 16 + lrow) * SROW];

    // ---- phase A MFMA: K=192 (kt 0..3 from LDS, kt 4..5 from registers) ----
    floatx4 acc[4];
    #pragma unroll
    for (int i = 0; i < 4; i++) acc[i] = (floatx4){0, 0, 0, 0};
    #pragma unroll
    for (int kt = 0; kt < 4; kt++) {
        short8 afrag = *(const short8*)(arow + kt * 32 + quad * 8);
        int kb = kt * 4 + quad;
        #pragma unroll
        for (int j = 0; j < 4; j++) {
            int n = (4 * h + j) * 16 + lrow;
            short8 bfrag = *(const short8*)(W1 + (size_t)(kb * 128 + n) * 8);
            acc[j] = __builtin_amdgcn_mfma_f32_16x16x32_bf16(afrag, bfrag, acc[j], 0, 0, 0);
        }
    }
    #pragma unroll
    for (int j = 0; j < 4; j++) {
        int n = (4 * h + j) * 16 + lrow;
        short8 b4 = *(const short8*)(W1 + (size_t)((16 + quad) * 128 + n) * 8);
        acc[j] = __builtin_amdgcn_mfma_f32_16x16x32_bf16(afa0, b4, acc[j], 0, 0, 0);
        short8 b5 = *(const short8*)(W1 + (size_t)((20 + quad) * 128 + n) * 8);
        acc[j] = __builtin_amdgcn_mfma_f32_16x16x32_bf16(afa1, b5, acc[j], 0, 0, 0);
    }

    // epilogue A: t -> S cols 128..255
    #pragma unroll
    for (int j = 0; j < 4; j++) {
        int n = (4 * h + j) * 16 + lrow;
        float bv = b1[n];
        unsigned int p01 = f2bf_pk(silu_f(acc[j][0] + bv), silu_f(acc[j][1] + bv));
        unsigned int p23 = f2bf_pk(silu_f(acc[j][2] + bv), silu_f(acc[j][3] + bv));
        S[(elb + 0) * SROW + 128 + n] = (unsigned short)(p01 & 0xFFFF);
        S[(elb + 1) * SROW + 128 + n] = (unsigned short)(p01 >> 16);
        S[(elb + 2) * SROW + 128 + n] = (unsigned short)(p23 & 0xFFFF);
        S[(elb + 3) * SROW + 128 + n] = (unsigned short)(p23 >> 16);
    }
    __syncthreads();   // B2: t complete

    // ---- phase B MFMA: K=128 over t (cols 128..255) ----
    floatx4 acc2[4];
    #pragma unroll
    for (int i = 0; i < 4; i++) acc2[i] = (floatx4){0, 0, 0, 0};
    #pragma unroll
    for (int kt = 0; kt < 4; kt++) {
        short8 afrag = *(const short8*)(arow + 128 + kt * 32 + quad * 8);
        int kb = kt * 4 + quad;
        #pragma unroll
        for (int j = 0; j < 4; j++) {
            int n = (4 * h + j) * 16 + lrow;
            short8 bfrag = *(const short8*)(W2 + (size_t)(kb * 128 + n) * 8);
            acc2[j] = __builtin_amdgcn_mfma_f32_16x16x32_bf16(afrag, bfrag, acc2[j], 0, 0, 0);
        }
    }

    // epilogue B: h_new = acc2 + b2 + res(LDS bf16, owner cells) -> S cols 0..127
    #pragma unroll
    for (int j = 0; j < 4; j++) {
        int n = (4 * h + j) * 16 + lrow;
        float bv = b2[n];
        floatx4 v4;
        #pragma unroll
        for (int r = 0; r < 4; r++) {
            float res = bf2f(S[(elb + r) * SROW + n]);
            v4[r] = acc2[j][r] + bv + res;
        }
        unsigned int p01 = f2bf_pk(v4[0], v4[1]);
        unsigned int p23 = f2bf_pk(v4[2], v4[3]);
        S[(elb + 0) * SROW + n] = (unsigned short)(p01 & 0xFFFF);
        S[(elb + 1) * SROW + n] = (unsigned short)(p01 >> 16);
        S[(elb + 2) * SROW + n] = (unsigned short)(p23 & 0xFFFF);
        S[(elb + 3) * SROW + n] = (unsigned short)(p23 >> 16);
    }
    __syncthreads();   // B3: h_new complete (all t reads done)

    // ---- phase C MFMA: K=128 -> P (128, f16) or out (64, f32) ----
    constexpr int NT3 = FINAL ? 2 : 4;
    constexpr int NO3 = FINAL ? 64 : 128;
    floatx4 acc3[NT3];
    #pragma unroll
    for (int i = 0; i < NT3; i++) acc3[i] = (floatx4){0, 0, 0, 0};
    #pragma unroll
    for (int kt = 0; kt < 4; kt++) {
        short8 afrag = *(const short8*)(arow + kt * 32 + quad * 8);
        int kb = kt * 4 + quad;
        #pragma unroll
        for (int j = 0; j < NT3; j++) {
            int n = (NT3 * h + j) * 16 + lrow;
            short8 bfrag = *(const short8*)(B3 + (size_t)(kb * NO3 + n) * 8);
            acc3[j] = __builtin_amdgcn_mfma_f32_16x16x32_bf16(afrag, bfrag, acc3[j], 0, 0, 0);
        }
    }
    // epilogue C -> S cols 128..255 (f16 P) or fp32 out region (same cols)
    #pragma unroll
    for (int j = 0; j < NT3; j++) {
        int n = (NT3 * h + j) * 16 + lrow;
        float bv = bias3[n];
        if (FINAL) {
            #pragma unroll
            for (int r = 0; r < 4; r++)
                ((float*)(&S[(elb + r) * SROW + 128]))[n] = acc3[j][r] + bv;
        } else {
            unsigned int p01 = f2fh_pk(acc3[j][0] + bv, acc3[j][1] + bv);
            unsigned int p23 = f2fh_pk(acc3[j][2] + bv, acc3[j][3] + bv);
            S[(elb + 0) * SROW + 128 + n] = (unsigned short)(p01 & 0xFFFF);
            S[(elb + 1) * SROW + 128 + n] = (unsigned short)(p01 >> 16);
            S[(elb + 2) * SROW + 128 + n] = (unsigned short)(p23 & 0xFFFF);
            S[(elb + 3) * SROW + 128 + n] = (unsigned short)(p23 >> 16);
        }
    }
    __syncthreads();   // B4

    // cooperative wide stores
    if (FINAL) {
        for (int t = tid; t < 64 * 16; t += 512) {
            int rr = t >> 4, c = t & 15;
            int row = m0 + rr;
            if (row < M)
                *(floatx4*)(outF + (size_t)row * 64 + c * 4) =
                    *(const floatx4*)((const float*)(&S[rr * SROW + 128]) + c * 4);
        }
    } else {
        for (int t = tid; t < 64 * 32; t += 512) {
            int rr = t >> 5, c = t & 31;
            int row = m0 + rr;
            if (row < M) {
                if (c < 16)
                    *(uintx4*)(hB + (size_t)row * 128 + c * 8) =
                        *(const uintx4*)(&S[rr * SROW + c * 8]);
                else
                    *(uintx4*)(Pout + (size_t)row * 128 + (c - 16) * 8) =
                        *(const uintx4*)(&S[rr * SROW + 128 + (c - 16) * 8]);
            }
        }
    }
}

// ---------------------------------------------------------------------------
// Fused embedding (256 thr, wave-private rows); P output f16.
// Reads h0 f32 directly, converts to bf16 during LDS staging.
// ---------------------------------------------------------------------------
#define SROWE 264
__global__ __launch_bounds__(256) void embed_fused_k(
    const float* __restrict__ h0, const unsigned short* __restrict__ Win,
    const float* __restrict__ b_in, const unsigned short* __restrict__ W1,
    const float* __restrict__ biasP,
    unsigned short* __restrict__ hB, unsigned short* __restrict__ Pout, int M)
{
    __shared__ unsigned short S[64 * SROWE];
    const int tid = threadIdx.x;
    const int m0 = blockIdx.x * 64;
    const int wave = tid >> 6;
    const int lane = tid & 63;
    const int lrow = lane & 15;
    const int quad = lane >> 4;
    const int elb = wave * 16 + quad * 4;

    // staging: h0 f32 -> bf16 into S cols 0..63
    for (int t = tid; t < 64 * 16; t += 256) {
        int rr = t >> 4, c = t & 15;
        int row = m0 + rr;
        floatx4 v = {0, 0, 0, 0};
        if (row < M) v = *(const floatx4*)(h0 + (size_t)row * 64 + c * 4);
        uintx2 u = { f2bf_pk(v[0], v[1]), f2bf_pk(v[2], v[3]) };
        *(uintx2*)(&S[rr * SROWE + c * 4]) = u;
    }
    __syncthreads();   // barrier 1

    const unsigned short* arow = &S[(wave * 16 + lrow) * SROWE];

    floatx4 acc[8];
    #pragma unroll
    for (int i = 0; i < 8; i++) acc[i] = (floatx4){0, 0, 0, 0};
    #pragma unroll
    for (int kt = 0; kt < 2; kt++) {
        short8 afrag = *(const short8*)(arow + kt * 32 + quad * 8);
        int kb = kt * 4 + quad;
        #pragma unroll
        for (int nt = 0; nt < 8; nt++) {
            short8 bfrag = *(const short8*)(Win + (size_t)(kb * 128 + nt * 16 + lrow) * 8);
            acc[nt] = __builtin_amdgcn_mfma_f32_16x16x32_bf16(afrag, bfrag, acc[nt], 0, 0, 0);
        }
    }

    // epilogue: h1 -> S cols 0..127 (bf16)
    #pragma unroll
    for (int nt = 0; nt < 8; nt++) {
        int n = nt * 16 + lrow;
        float bv = b_in[n];
        floatx4 v4;
        #pragma unroll
        for (int r = 0; r < 4; r++) v4[r] = acc[nt][r] + bv;
        unsigned int p01 = f2bf_pk(v4[0], v4[1]);
        unsigned int p23 = f2bf_pk(v4[2], v4[3]);
        S[(elb + 0) * SROWE + n] = (unsigned short)(p01 & 0xFFFF);
        S[(elb + 1) * SROWE + n] = (unsigned short)(p01 >> 16);
        S[(elb + 2) * SROWE + n] = (unsigned short)(p23 & 0xFFFF);
        S[(elb + 3) * SROWE + n] = (unsigned short)(p23 >> 16);
    }

    floatx4 acc3[8];
    #pragma unroll
    for (int i = 0; i < 8; i++) acc3[i] = (floatx4){0, 0, 0, 0};
    #pragma unroll
    for (int kt = 0; kt < 4; kt++) {
        short8 afrag = *(const short8*)(arow + kt * 32 + quad * 8);
        int kb = kt * 4 + quad;
        #pragma unroll
        for (int nt = 0; nt < 8; nt++) {
            short8 bfrag = *(const short8*)(W1 + (size_t)(kb * 128 + nt * 16 + lrow) * 8);
            acc3[nt] = __builtin_amdgcn_mfma_f32_16x16x32_bf16(afrag, bfrag, acc3[nt], 0, 0, 0);
        }
    }
    #pragma unroll
    for (int nt = 0; nt < 8; nt++) {
        int n = nt * 16 + lrow;
        float bv = biasP[n];
        unsigned int p01 = f2fh_pk(acc3[nt][0] + bv, acc3[nt][1] + bv);
        unsigned int p23 = f2fh_pk(acc3[nt][2] + bv, acc3[nt][3] + bv);
        S[(elb + 0) * SROWE + 128 + n] = (unsigned short)(p01 & 0xFFFF);
        S[(elb + 1) * SROWE + 128 + n] = (unsigned short)(p01 >> 16);
        S[(elb + 2) * SROWE + 128 + n] = (unsigned short)(p23 & 0xFFFF);
        S[(elb + 3) * SROWE + 128 + n] = (unsigned short)(p23 >> 16);
    }
    __syncthreads();   // barrier 2

    for (int t = tid; t < 64 * 32; t += 256) {
        int rr = t / 32, c = t % 32;
        int row = m0 + rr;
        if (row < M) {
            if (c < 16)
                *(uintx4*)(hB + (size_t)row * 128 + c * 8) =
                    *(const uintx4*)(&S[rr * SROWE + c * 8]);
            else
                *(uintx4*)(Pout + (size_t)row * 128 + (c - 16) * 8) =
                    *(const uintx4*)(&S[rr * SROWE + 128 + (c - 16) * 8]);
        }
    }
}

// ---------------------------------------------------------------------------
extern "C" void kernel_launch(void* const* d_in, const int* in_sizes, int n_in,
                              void* d_out, int out_size, void* d_ws, size_t ws_size,
                              hipStream_t stream) {
    const float* h0   = (const float*)d_in[0];
    const int*   edges= (const int*)d_in[1];
    const float* W_in = (const float*)d_in[2];
    const float* b_in = (const float*)d_in[3];
    const float* eW1  = (const float*)d_in[4];
    const float* eb1  = (const float*)d_in[5];
    const float* eW2  = (const float*)d_in[6];
    const float* eb2  = (const float*)d_in[7];
    const float* nW1  = (const float*)d_in[8];
    const float* nb1  = (const float*)d_in[9];
    const float* nW2  = (const float*)d_in[10];
    const float* nb2  = (const float*)d_in[11];
    const float* W_out= (const float*)d_in[12];
    const float* b_out= (const float*)d_in[13];
    float* out = (float*)d_out;

    const int E = in_sizes[1] / 2;      // 800000
    const int* erow = edges;
    const int* ecol = edges + E;

    char* ws = (char*)d_ws;
    unsigned short* hbf  = (unsigned short*)(ws + 0);            // 12,800,000
    // (ws+12800000..38424576 free)
    unsigned short* P    = (unsigned short*)(ws + 38424576);     // 12,800,000 (f16)
    float*          agg  = (float*)(ws + 51224576);              // 12,800,000
    int2*           binned=(int2*)(ws + 51224576);               //  6,400,000 (aliases agg; consumed pre-zero)
    int2*           eidx = (int2*)(ws + 76824576);               //  6,400,000
    float*          biasP= (float*)(ws + 83224576);              //  2,048
    unsigned short* Winp = (unsigned short*)(ws + 83226624);     // 16,384
    unsigned short* Woutp= (unsigned short*)(ws + 83243008);     // 16,384
    unsigned short* W1p  = (unsigned short*)(ws + 83259392);     // 131,072
    unsigned short* eW2p = (unsigned short*)(ws + 83390464);     // 32,768 (f16)
    unsigned short* nW1p = (unsigned short*)(ws + 83423232);     // 196,608
    unsigned short* nW2p = (unsigned short*)(ws + 83619840);     // 131,072
    int*            countB=(int*)(ws + 83750912);                // 784
    int*            bucketBase=(int*)(ws + 83751936);            // 788
    int*            bucketCursor=(int*)(ws + 83752960);          // 784

    const int gemm_grid = (N_NODES + 63) / 64;    // 782
    const int edge_grid = (E + 63) / 64;          // 12500
    const int pack_grid = (int)((PACK_TOTAL + 255) / 256);
    const int bin_grid  = (E + BCHUNK - 1) / BCHUNK;   // 391

    hipMemsetAsync(countB, 0, NBKT * 4, stream);
    pack_kernel<<<pack_grid, 256, 0, stream>>>(W_in, W_out, eW1, eb1, eW2,
                                               nW1, nW2, Winp, Woutp, W1p,
                                               eW2p, nW1p, nW2p, biasP);

    // binning before embed (binned aliases agg, unused until layers)
    hist_k<<<bin_grid, 256, 0, stream>>>(erow, countB, E);
    bucket_scan_k<<<1, 256, 0, stream>>>(countB, bucketBase, bucketCursor);
    bin_k<<<bin_grid, 256, 0, stream>>>(erow, ecol, bucketCursor, binned, E);
    sort_k<<<NBKT, 256, 0, stream>>>(binned, bucketBase, eidx);

    // h1 = h0 @ W_in + b_in; P0 = h1 @ W1'[0]
    embed_fused_k<<<gemm_grid, 256, 0, stream>>>(
        h0, Winp, b_in, W1p, biasP, hbf, P, N_NODES);

    // single agg zero for layer 0 (subsequent layers zeroed by node_fused)
    hipMemsetAsync(agg, 0, (size_t)N_NODES * 64 * 4, stream);

    for (int l = 0; l < 4; l++) {
        edge_fused_k<<<edge_grid, 256, 0, stream>>>(
            eidx, P, eW2p + (size_t)l * SE2, eb2 + (size_t)l * 64, agg, E, edge_grid);
        if (l < 3) {
            node_fused_k<0><<<gemm_grid, 512, 0, stream>>>(
                hbf, agg, nW1p + (size_t)l * SN1, nb1 + (size_t)l * 128,
                nW2p + (size_t)l * SN2, nb2 + (size_t)l * 128,
                W1p + (size_t)(l + 1) * SW1, biasP + (size_t)(l + 1) * 128,
                hbf, P, nullptr, agg, N_NODES);
        } else {
            node_fused_k<1><<<gemm_grid, 512, 0, stream>>>(
                hbf, agg, nW1p + (size_t)l * SN1, nb1 + (size_t)l * 128,
                nW2p + (size_t)l * SN2, nb2 + (size_t)l * 128,
                Woutp, b_out, nullptr, nullptr, out, nullptr, N_NODES);
        }
    }
}

// Round 8
// 401.147 us; speedup vs baseline: 1.0304x; 1.0257x over previous
//
#include <hip/hip_runtime.h>
#include <hip/hip_bf16.h>
#include <hip/hip_fp16.h>
#include <cstdint>
#include <cstddef>

#define N_NODES 50000
#define N_EDGES 800000
#define NBKT    196      // ceil(50000/256) buckets of 256 rows
#define BSH     8        // rows-per-bucket shift
#define BCHUNK  2048     // edges per bin_k block
#define CAP     6144     // max edges per bucket (mean 4082)

typedef __attribute__((ext_vector_type(8))) short short8;
typedef __attribute__((ext_vector_type(4))) float floatx4;
typedef __attribute__((ext_vector_type(2))) float floatx2;
typedef __attribute__((ext_vector_type(4))) unsigned int uintx4;
typedef __attribute__((ext_vector_type(2))) unsigned int uintx2;
typedef __attribute__((ext_vector_type(8))) _Float16 half8v;

__device__ inline float bf2f(unsigned short u) {
    union { unsigned int i; float f; } v; v.i = ((unsigned int)u) << 16; return v.f;
}
__device__ inline unsigned short f2bf(float f) {
    union { float f; unsigned int i; } v; v.f = f;
    unsigned int u = v.i;
    return (unsigned short)((u + 0x7FFFu + ((u >> 16) & 1u)) >> 16);
}
// packed RNE f32x2 -> bf16x2 (v_cvt_pk_bf16_f32 on gfx950)
__device__ inline unsigned int f2bf_pk(float a, float b) {
    __hip_bfloat162 h2 = __float22bfloat162_rn(make_float2(a, b));
    return *reinterpret_cast<unsigned int*>(&h2);
}
// f16 helpers (edge path is f16: packed ALU + mfma_f32_16x16x32_f16)
__device__ inline unsigned short f2fh(float f) {
    _Float16 h = (_Float16)f;
    return __builtin_bit_cast(unsigned short, h);
}
// packed f32x2 -> f16x2 via v_cvt_pkrtz_f16_f32 (1 instr)
// NOTE: builtin returns __fp16 ext_vector_type(2) on this clang — bit_cast it.
__device__ inline unsigned int f2fh_pk(float a, float b) {
    typedef __attribute__((ext_vector_type(2))) __fp16 h2v;
    h2v r = __builtin_amdgcn_cvt_pkrtz(a, b);
    return __builtin_bit_cast(unsigned int, r);
}
__device__ inline __half2 u2h(unsigned int u) { return __builtin_bit_cast(__half2, u); }
__device__ inline unsigned int h2u(__half2 h) { return __builtin_bit_cast(unsigned int, h); }
// f16 SiLU on a packed pair.
__device__ inline __half2 silu_h2(__half2 x) {
    const __half2 nlog2e = __float2half2_rn(-1.4426950408889634f);
    const __half2 one    = __float2half2_rn(1.0f);
    __half2 e = h2exp2(__hmul2(x, nlog2e));
    return __hmul2(x, h2rcp(__hadd2(e, one)));
}
// silu via v_rcp_f32 (1 ulp) instead of IEEE divide
__device__ inline float silu_f(float x) {
    float e = __expf(-x);
    return x * __builtin_amdgcn_rcpf(1.0f + e);
}

__device__ inline int block_excl_scan_256(int v, int* buf) {
    int tid = threadIdx.x;
    buf[tid] = v;
    __syncthreads();
    #pragma unroll
    for (int off = 1; off < 256; off <<= 1) {
        int t = (tid >= off) ? buf[tid - off] : 0;
        __syncthreads();
        buf[tid] += t;
        __syncthreads();
    }
    return buf[tid] - v;
}

// ---------------------------------------------------------------------------
// Pack kernel: fp32->bf16/f16 weight rearrangement into MFMA fragment order.
// R17: also zeroes countB (replaces a hipMemsetAsync dispatch; safe because
// hist_k launches after pack in the same stream).
// B-fragment order: Bp[(kb*NOUT + n)*8 + i] = B[(kb*8+i)*NOUT + n]
// ---------------------------------------------------------------------------
__device__ inline void pack_std(const float* __restrict__ src,
                                unsigned short* __restrict__ dst,
                                int NOUT, long j) {
    int i = (int)(j & 7);
    long rest = j >> 3;
    int n = (int)(rest % NOUT);
    int kb = (int)(rest / NOUT);
    dst[j] = f2bf(src[(long)(kb * 8 + i) * NOUT + n]);
}
__device__ inline void pack_std_h(const float* __restrict__ src,
                                  unsigned short* __restrict__ dst,
                                  int NOUT, long j) {
    int i = (int)(j & 7);
    long rest = j >> 3;
    int n = (int)(rest % NOUT);
    int kb = (int)(rest / NOUT);
    dst[j] = f2fh(src[(long)(kb * 8 + i) * NOUT + n]);
}

#define SW_IN 8192L
#define SW_OUT 8192L
#define SW1   16384L
#define SE2   4096L
#define SN1   24576L
#define SN2   16384L
#define SB    128L
#define PERL  (SW1 + SE2 + SN1 + SN2 + SB)
#define PACK_TOTAL (SW_IN + SW_OUT + 4 * PERL)
#define PACK_GRID_TOTAL (PACK_TOTAL + NBKT)

__global__ __launch_bounds__(256) void pack_kernel(
    const float* __restrict__ W_in,
    const float* __restrict__ W_out, const float* __restrict__ eW1,
    const float* __restrict__ eb1, const float* __restrict__ eW2,
    const float* __restrict__ nW1, const float* __restrict__ nW2,
    unsigned short* __restrict__ Winp,
    unsigned short* __restrict__ Woutp, unsigned short* __restrict__ W1p,
    unsigned short* __restrict__ eW2p, unsigned short* __restrict__ nW1p,
    unsigned short* __restrict__ nW2p, float* __restrict__ biasP,
    int* __restrict__ countB)
{
    long idx = (long)blockIdx.x * 256 + threadIdx.x;
    if (idx >= PACK_TOTAL) {
        long t = idx - PACK_TOTAL;
        if (t < NBKT) countB[t] = 0;
        return;
    }
    long j = idx;
    if (j < SW_IN) { pack_std(W_in, Winp, 128, j); return; }
    j -= SW_IN;
    if (j < SW_OUT) { pack_std(W_out, Woutp, 64, j); return; }
    j -= SW_OUT;
    int l = (int)(j / PERL);
    long r = j % PERL;
    if (r < SW1) {
        int i = (int)(r & 7);
        int n = (int)((r >> 3) & 127);
        int kb = (int)(r >> 10);
        int k = kb * 8 + i;
        const float* w = eW1 + (long)l * 256 * 64;
        float v = (n < 64) ? w[(long)k * 64 + n] : w[(long)(128 + k) * 64 + (n - 64)];
        W1p[(long)l * SW1 + r] = f2bf(v);
        return;
    }
    r -= SW1;
    if (r < SE2) { pack_std_h(eW2 + (long)l * 4096, eW2p + (long)l * SE2, 64, r); return; }
    r -= SE2;
    if (r < SN1) { pack_std(nW1 + (long)l * 24576, nW1p + (long)l * SN1, 128, r); return; }
    r -= SN1;
    if (r < SN2) { pack_std(nW2 + (long)l * 16384, nW2p + (long)l * SN2, 128, r); return; }
    r -= SN2;
    biasP[(long)l * 128 + r] = (r < 64) ? eb1[(long)l * 64 + r] : 0.0f;
}

// ---------------------------------------------------------------------------
// Edge-sort pipeline
// ---------------------------------------------------------------------------
__global__ __launch_bounds__(256) void hist_k(const int* __restrict__ erow,
                                              int* __restrict__ countB, int E) {
    __shared__ int c[NBKT];
    for (int i = threadIdx.x; i < NBKT; i += 256) c[i] = 0;
    __syncthreads();
    int j = blockIdx.x * BCHUNK + threadIdx.x;
    #pragma unroll
    for (int i = 0; i < BCHUNK / 256; i++, j += 256)
        if (j < E) atomicAdd(&c[erow[j] >> BSH], 1);
    __syncthreads();
    for (int i = threadIdx.x; i < NBKT; i += 256)
        if (c[i]) atomicAdd(&countB[i], c[i]);
}

__global__ __launch_bounds__(256) void bucket_scan_k(const int* __restrict__ countB,
                                                     int* __restrict__ bucketBase,
                                                     int* __restrict__ bucketCursor) {
    __shared__ int buf[256];
    int tid = threadIdx.x;
    int v = (tid < NBKT) ? countB[tid] : 0;
    int excl = block_excl_scan_256(v, buf);
    if (tid < NBKT) {
        bucketBase[tid] = excl;
        bucketCursor[tid] = excl;
    }
    if (tid == NBKT - 1) bucketBase[NBKT] = excl + v;   // = E
}

__global__ __launch_bounds__(256) void bin_k(
    const int* __restrict__ erow, const int* __restrict__ ecol,
    int* __restrict__ bucketCursor, int2* __restrict__ binned, int E)
{
    __shared__ int2 staged[BCHUNK];
    __shared__ int cnt[NBKT];
    __shared__ int binStart[NBKT];
    __shared__ int gbase[NBKT];
    __shared__ int scanbuf[256];
    const int tid = threadIdx.x;
    const int base = blockIdx.x * BCHUNK;
    const int nloc = min(BCHUNK, E - base);

    for (int i = tid; i < NBKT; i += 256) cnt[i] = 0;
    __syncthreads();

    int2 ed[BCHUNK / 256];
    int  bo[BCHUNK / 256];
    #pragma unroll
    for (int i = 0; i < BCHUNK / 256; i++) {
        int jl = i * 256 + tid;
        if (jl < nloc) {
            int j = base + jl;
            int r = erow[j], c = ecol[j];
            ed[i] = make_int2(r, c);
            int b = r >> BSH;
            int off = atomicAdd(&cnt[b], 1);
            bo[i] = (b << 12) | off;
        } else bo[i] = -1;
    }
    __syncthreads();

    int v = (tid < NBKT) ? cnt[tid] : 0;
    int excl = block_excl_scan_256(v, scanbuf);
    if (tid < NBKT) binStart[tid] = excl;
    if (tid < NBKT && v > 0) gbase[tid] = atomicAdd(&bucketCursor[tid], v);
    __syncthreads();

    #pragma unroll
    for (int i = 0; i < BCHUNK / 256; i++) {
        if (bo[i] >= 0)
            staged[binStart[bo[i] >> 12] + (bo[i] & 0xFFF)] = ed[i];
    }
    __syncthreads();

    for (int j = tid; j < nloc; j += 256) {
        int2 e = staged[j];
        int b = e.x >> BSH;
        binned[gbase[b] + (j - binStart[b])] = e;
    }
}

__global__ __launch_bounds__(256) void sort_k(
    const int2* __restrict__ binned, const int* __restrict__ bucketBase,
    int2* __restrict__ eidx)
{
    __shared__ int2 st[CAP];
    __shared__ int cnt[256];
    __shared__ int cur[256];
    __shared__ int scanbuf[256];
    const int b = blockIdx.x;
    const int tid = threadIdx.x;
    const int s0 = bucketBase[b];
    int n = bucketBase[b + 1] - s0;
    if (n > CAP) n = CAP;

    cnt[tid] = 0;
    __syncthreads();
    for (int j = tid; j < n; j += 256) {
        int2 e = binned[s0 + j];
        st[j] = e;
        atomicAdd(&cnt[e.x & 255], 1);
    }
    __syncthreads();
    int excl = block_excl_scan_256(cnt[tid], scanbuf);
    cur[tid] = excl;
    __syncthreads();
    for (int j = tid; j < n; j += 256) {
        int2 e = st[j];
        int pos = atomicAdd(&cur[e.x & 255], 1);
        eidx[s0 + pos] = e;
    }
}

// ---------------------------------------------------------------------------
// Fused edge + block-segmented aggregate over sorted edges.
// R17: exact R5 structure (best measured, 44.0 µs): f32 M2s [el][68],
// segStartS reduction, f16 P/eW2 + f16 MFMA, bias in accumulators.
// XCD swizzle removed (R7 null: -2.5% FETCH, no time win).
// ---------------------------------------------------------------------------
__global__ __launch_bounds__(256) void edge_fused_k(
    const int2* __restrict__ eidx,
    const unsigned short* __restrict__ P,    // [N,128] f16: 0..63 top(+b1), 64..127 bot
    const unsigned short* __restrict__ Bp,   // eW2 frag order, f16
    const float* __restrict__ b2, float* __restrict__ agg, int E)
{
    __shared__ float M2s[64 * 68];
    __shared__ int ridS[64];
    __shared__ short segStartS[66];
    __shared__ int nsegS;
    const int tid = threadIdx.x;
    const int wave = tid >> 6;
    const int lane = tid & 63;
    const int lrow = lane & 15;
    const int quad = lane >> 4;
    const int e0 = blockIdx.x * 64;
    const int el = wave * 16 + lrow;
    const int e = e0 + el;

    // bias preloaded into the MFMA accumulators
    floatx4 acc[4];
    #pragma unroll
    for (int nt = 0; nt < 4; nt++) {
        float bv = b2[nt * 16 + lrow];
        acc[nt] = (floatx4){bv, bv, bv, bv};
    }

    half8v af0 = {};
    half8v af1 = {};
    if (e < E) {
        int2 rc = eidx[e];
        int rr = rc.x, cc = rc.y;
        if (quad == 0) ridS[el] = rr;
        const uintx4* pt = (const uintx4*)(P + (size_t)rr * 128 + quad * 8);
        const uintx4* pb = (const uintx4*)(P + (size_t)cc * 128 + 64 + quad * 8);
        uintx4 t0 = pt[0], t1 = pt[4];
        uintx4 b0 = pb[0], b1 = pb[4];
        uintx4 O0, O1;
        #pragma unroll
        for (int i = 0; i < 4; i++) {
            O0[i] = h2u(silu_h2(__hadd2(u2h(t0[i]), u2h(b0[i]))));
            O1[i] = h2u(silu_h2(__hadd2(u2h(t1[i]), u2h(b1[i]))));
        }
        af0 = __builtin_bit_cast(half8v, O0);
        af1 = __builtin_bit_cast(half8v, O1);
    } else if (quad == 0) {
        ridS[el] = -1;
    }

    #pragma unroll
    for (int nt = 0; nt < 4; nt++) {
        half8v bf0 = *(const half8v*)(Bp + (size_t)((0 * 4 + quad) * 64 + nt * 16 + lrow) * 8);
        acc[nt] = __builtin_amdgcn_mfma_f32_16x16x32_f16(af0, bf0, acc[nt], 0, 0, 0);
        half8v bf1 = *(const half8v*)(Bp + (size_t)((1 * 4 + quad) * 64 + nt * 16 + lrow) * 8);
        acc[nt] = __builtin_amdgcn_mfma_f32_16x16x32_f16(af1, bf1, acc[nt], 0, 0, 0);
    }

    #pragma unroll
    for (int nt = 0; nt < 4; nt++) {
        int n = nt * 16 + lrow;
        #pragma unroll
        for (int r = 0; r < 4; r++) {
            int el2 = wave * 16 + quad * 4 + r;
            M2s[el2 * 68 + n] = silu_f(acc[nt][r]);
        }
    }
    __syncthreads();

    if (tid < 64) {
        bool st = (ridS[tid] >= 0) && (tid == 0 || ridS[tid] != ridS[tid - 1]);
        unsigned long long m = __ballot(st);
        if (st) {
            int pos = __popcll(m & ((1ull << tid) - 1));
            segStartS[pos] = (short)tid;
        }
        if (tid == 0) {
            int ns = __popcll(m);
            nsegS = ns;
            int nvalid = E - e0;
            if (nvalid > 64) nvalid = 64;
            segStartS[ns] = (short)nvalid;
        }
    }
    __syncthreads();

    {
        int f = tid & 63;
        int g = tid >> 6;
        int ns = nsegS;
        for (int j = g; j < ns; j += 4) {
            int a = segStartS[j], b = segStartS[j + 1];
            float s = 0.0f;
            for (int el2 = a; el2 < b; el2++) s += M2s[el2 * 68 + f];
            int rv = ridS[a];
            if (j == 0 || j == ns - 1)
                atomicAdd(&agg[(size_t)rv * 64 + f], s);
            else
                agg[(size_t)rv * 64 + f] = s;
        }
    }
}

// ---------------------------------------------------------------------------
// Fused node-side chain (R14 structure: residual from LDS bf16, no hFT).
// ---------------------------------------------------------------------------
#define SROW 264
template<int FINAL>
__global__ __launch_bounds__(512) void node_fused_k(
    const unsigned short* __restrict__ hbf, const float* __restrict__ agg,
    const unsigned short* __restrict__ W1, const float* __restrict__ b1,
    const unsigned short* __restrict__ W2, const float* __restrict__ b2,
    const unsigned short* __restrict__ B3, const float* __restrict__ bias3,
    unsigned short* __restrict__ hB, unsigned short* __restrict__ Pout,
    float* __restrict__ outF, float* __restrict__ aggZ, int M)
{
    __shared__ unsigned short S[64 * SROW];
    const int tid = threadIdx.x;
    const int m0 = blockIdx.x * 64;
    const int wave = tid >> 6;
    const int lane = tid & 63;
    const int lrow = lane & 15;
    const int quad = lane >> 4;
    const int g = wave >> 1;          // row group 0..3
    const int h = wave & 1;           // N half
    const int elb = g * 16 + quad * 4;

    // agg A-fragments straight into registers (kt=4,5 of the K=192 A-op)
    short8 afa0, afa1;
    {
        const float* ap = agg + (size_t)(m0 + g * 16 + lrow) * 64;
        floatx4 q0 = *(const floatx4*)(ap + quad * 8);
        floatx4 q1 = *(const floatx4*)(ap + quad * 8 + 4);
        floatx4 q2 = *(const floatx4*)(ap + 32 + quad * 8);
        floatx4 q3 = *(const floatx4*)(ap + 32 + quad * 8 + 4);
        unsigned int c0[4] = { f2bf_pk(q0[0], q0[1]), f2bf_pk(q0[2], q0[3]),
                               f2bf_pk(q1[0], q1[1]), f2bf_pk(q1[2], q1[3]) };
        unsigned int c1[4] = { f2bf_pk(q2[0], q2[1]), f2bf_pk(q2[2], q2[3]),
                               f2bf_pk(q3[0], q3[1]), f2bf_pk(q3[2], q3[3]) };
        afa0 = *(const short8*)c0;
        afa1 = *(const short8*)c1;
    }

    // staging: h (128 bf16) only -> S cols 0..127
    for (int t = tid; t < 64 * 16; t += 512) {
        int rr = t >> 4, c = t & 15;
        int row = m0 + rr;
        uintx4 val = {0, 0, 0, 0};
        if (row < M) val = *(const uintx4*)(hbf + (size_t)row * 128 + c * 8);
        *(uintx4*)(&S[rr * SROW + c * 8]) = val;
    }
    __syncthreads();   // B1

    // zero this block's agg rows for the next layer
    if (!FINAL) {
        floatx4 z = {0, 0, 0, 0};
        for (int t = tid; t < 64 * 16; t += 512) {
            int rr = t >> 4, c = t & 15;
            int row = m0 + rr;
            if (row < M) *(floatx4*)(aggZ + (size_t)row * 64 + c * 4) = z;
        }
    }

    const unsigned short* arow = &S[(g * 16 + lrow) * SROW];

    // ---- phase A MFMA: K=192 (kt 0..3 from LDS, kt 4..5 from registers) ----
    floatx4 acc[4];
    #pragma unroll
    for (int i = 0; i < 4; i++) acc[i] = (floatx4){0, 0, 0, 0};
    #pragma unroll
    for (int kt = 0; kt < 4; kt++) {
        short8 afrag = *(const short8*)(arow + kt * 32 + quad * 8);
        int kb = kt * 4 + quad;
        #pragma unroll
        for (int j = 0; j < 4; j++) {
            int n = (4 * h + j) * 16 + lrow;
            short8 bfrag = *(const short8*)(W1 + (size_t)(kb * 128 + n) * 8);
            acc[j] = __builtin_amdgcn_mfma_f32_16x16x32_bf16(afrag, bfrag, acc[j], 0, 0, 0);
        }
    }
    #pragma unroll
    for (int j = 0; j < 4; j++) {
        int n = (4 * h + j) * 16 + lrow;
        short8 b4 = *(const short8*)(W1 + (size_t)((16 + quad) * 128 + n) * 8);
        acc[j] = __builtin_amdgcn_mfma_f32_16x16x32_bf16(afa0, b4, acc[j], 0, 0, 0);
        short8 b5 = *(const short8*)(W1 + (size_t)((20 + quad) * 128 + n) * 8);
        acc[j] = __builtin_amdgcn_mfma_f32_16x16x32_bf16(afa1, b5, acc[j], 0, 0, 0);
    }

    // epilogue A: t -> S cols 128..255
    #pragma unroll
    for (int j = 0; j < 4; j++) {
        int n = (4 * h + j) * 16 + lrow;
        float bv = b1[n];
        unsigned int p01 = f2bf_pk(silu_f(acc[j][0] + bv), silu_f(acc[j][1] + bv));
        unsigned int p23 = f2bf_pk(silu_f(acc[j][2] + bv), silu_f(acc[j][3] + bv));
        S[(elb + 0) * SROW + 128 + n] = (unsigned short)(p01 & 0xFFFF);
        S[(elb + 1) * SROW + 128 + n] = (unsigned short)(p01 >> 16);
        S[(elb + 2) * SROW + 128 + n] = (unsigned short)(p23 & 0xFFFF);
        S[(elb + 3) * SROW + 128 + n] = (unsigned short)(p23 >> 16);
    }
    __syncthreads();   // B2: t complete

    // ---- phase B MFMA: K=128 over t (cols 128..255) ----
    floatx4 acc2[4];
    #pragma unroll
    for (int i = 0; i < 4; i++) acc2[i] = (floatx4){0, 0, 0, 0};
    #pragma unroll
    for (int kt = 0; kt < 4; kt++) {
        short8 afrag = *(const short8*)(arow + 128 + kt * 32 + quad * 8);
        int kb = kt * 4 + quad;
        #pragma unroll
        for (int j = 0; j < 4; j++) {
            int n = (4 * h + j) * 16 + lrow;
            short8 bfrag = *(const short8*)(W2 + (size_t)(kb * 128 + n) * 8);
            acc2[j] = __builtin_amdgcn_mfma_f32_16x16x32_bf16(afrag, bfrag, acc2[j], 0, 0, 0);
        }
    }

    // epilogue B: h_new = acc2 + b2 + res(LDS bf16, owner cells) -> S cols 0..127
    #pragma unroll
    for (int j = 0; j < 4; j++) {
        int n = (4 * h + j) * 16 + lrow;
        float bv = b2[n];
        floatx4 v4;
        #pragma unroll
        for (int r = 0; r < 4; r++) {
            float res = bf2f(S[(elb + r) * SROW + n]);
            v4[r] = acc2[j][r] + bv + res;
        }
        unsigned int p01 = f2bf_pk(v4[0], v4[1]);
        unsigned int p23 = f2bf_pk(v4[2], v4[3]);
        S[(elb + 0) * SROW + n] = (unsigned short)(p01 & 0xFFFF);
        S[(elb + 1) * SROW + n] = (unsigned short)(p01 >> 16);
        S[(elb + 2) * SROW + n] = (unsigned short)(p23 & 0xFFFF);
        S[(elb + 3) * SROW + n] = (unsigned short)(p23 >> 16);
    }
    __syncthreads();   // B3: h_new complete (all t reads done)

    // ---- phase C MFMA: K=128 -> P (128, f16) or out (64, f32) ----
    constexpr int NT3 = FINAL ? 2 : 4;
    constexpr int NO3 = FINAL ? 64 : 128;
    floatx4 acc3[NT3];
    #pragma unroll
    for (int i = 0; i < NT3; i++) acc3[i] = (floatx4){0, 0, 0, 0};
    #pragma unroll
    for (int kt = 0; kt < 4; kt++) {
        short8 afrag = *(const short8*)(arow + kt * 32 + quad * 8);
        int kb = kt * 4 + quad;
        #pragma unroll
        for (int j = 0; j < NT3; j++) {
            int n = (NT3 * h + j) * 16 + lrow;
            short8 bfrag = *(const short8*)(B3 + (size_t)(kb * NO3 + n) * 8);
            acc3[j] = __builtin_amdgcn_mfma_f32_16x16x32_bf16(afrag, bfrag, acc3[j], 0, 0, 0);
        }
    }
    // epilogue C -> S cols 128..255 (f16 P) or fp32 out region (same cols)
    #pragma unroll
    for (int j = 0; j < NT3; j++) {
        int n = (NT3 * h + j) * 16 + lrow;
        float bv = bias3[n];
        if (FINAL) {
            #pragma unroll
            for (int r = 0; r < 4; r++)
                ((float*)(&S[(elb + r) * SROW + 128]))[n] = acc3[j][r] + bv;
        } else {
            unsigned int p01 = f2fh_pk(acc3[j][0] + bv, acc3[j][1] + bv);
            unsigned int p23 = f2fh_pk(acc3[j][2] + bv, acc3[j][3] + bv);
            S[(elb + 0) * SROW + 128 + n] = (unsigned short)(p01 & 0xFFFF);
            S[(elb + 1) * SROW + 128 + n] = (unsigned short)(p01 >> 16);
            S[(elb + 2) * SROW + 128 + n] = (unsigned short)(p23 & 0xFFFF);
            S[(elb + 3) * SROW + 128 + n] = (unsigned short)(p23 >> 16);
        }
    }
    __syncthreads();   // B4

    // cooperative wide stores
    if (FINAL) {
        for (int t = tid; t < 64 * 16; t += 512) {
            int rr = t >> 4, c = t & 15;
            int row = m0 + rr;
            if (row < M)
                *(floatx4*)(outF + (size_t)row * 64 + c * 4) =
                    *(const floatx4*)((const float*)(&S[rr * SROW + 128]) + c * 4);
        }
    } else {
        for (int t = tid; t < 64 * 32; t += 512) {
            int rr = t >> 5, c = t & 31;
            int row = m0 + rr;
            if (row < M) {
                if (c < 16)
                    *(uintx4*)(hB + (size_t)row * 128 + c * 8) =
                        *(const uintx4*)(&S[rr * SROW + c * 8]);
                else
                    *(uintx4*)(Pout + (size_t)row * 128 + (c - 16) * 8) =
                        *(const uintx4*)(&S[rr * SROW + 128 + (c - 16) * 8]);
            }
        }
    }
}

// ---------------------------------------------------------------------------
// Fused embedding (256 thr, wave-private rows); P output f16.
// R17: also zeroes this block's agg rows (replaces the 12.8MB hipMemsetAsync
// dispatch; embed grid == node grid so coverage is identical).
// ---------------------------------------------------------------------------
#define SROWE 264
__global__ __launch_bounds__(256) void embed_fused_k(
    const float* __restrict__ h0, const unsigned short* __restrict__ Win,
    const float* __restrict__ b_in, const unsigned short* __restrict__ W1,
    const float* __restrict__ biasP,
    unsigned short* __restrict__ hB, unsigned short* __restrict__ Pout,
    float* __restrict__ aggZ, int M)
{
    __shared__ unsigned short S[64 * SROWE];
    const int tid = threadIdx.x;
    const int m0 = blockIdx.x * 64;
    const int wave = tid >> 6;
    const int lane = tid & 63;
    const int lrow = lane & 15;
    const int quad = lane >> 4;
    const int elb = wave * 16 + quad * 4;

    // staging: h0 f32 -> bf16 into S cols 0..63
    for (int t = tid; t < 64 * 16; t += 256) {
        int rr = t >> 4, c = t & 15;
        int row = m0 + rr;
        floatx4 v = {0, 0, 0, 0};
        if (row < M) v = *(const floatx4*)(h0 + (size_t)row * 64 + c * 4);
        uintx2 u = { f2bf_pk(v[0], v[1]), f2bf_pk(v[2], v[3]) };
        *(uintx2*)(&S[rr * SROWE + c * 4]) = u;
    }
    __syncthreads();   // barrier 1

    // zero this block's agg rows for layer 0 (fire-and-forget)
    {
        floatx4 z = {0, 0, 0, 0};
        for (int t = tid; t < 64 * 16; t += 256) {
            int rr = t >> 4, c = t & 15;
            int row = m0 + rr;
            if (row < M) *(floatx4*)(aggZ + (size_t)row * 64 + c * 4) = z;
        }
    }

    const unsigned short* arow = &S[(wave * 16 + lrow) * SROWE];

    floatx4 acc[8];
    #pragma unroll
    for (int i = 0; i < 8; i++) acc[i] = (floatx4){0, 0, 0, 0};
    #pragma unroll
    for (int kt = 0; kt < 2; kt++) {
        short8 afrag = *(const short8*)(arow + kt * 32 + quad * 8);
        int kb = kt * 4 + quad;
        #pragma unroll
        for (int nt = 0; nt < 8; nt++) {
            short8 bfrag = *(const short8*)(Win + (size_t)(kb * 128 + nt * 16 + lrow) * 8);
            acc[nt] = __builtin_amdgcn_mfma_f32_16x16x32_bf16(afrag, bfrag, acc[nt], 0, 0, 0);
        }
    }

    // epilogue: h1 -> S cols 0..127 (bf16)
    #pragma unroll
    for (int nt = 0; nt < 8; nt++) {
        int n = nt * 16 + lrow;
        float bv = b_in[n];
        floatx4 v4;
        #pragma unroll
        for (int r = 0; r < 4; r++) v4[r] = acc[nt][r] + bv;
        unsigned int p01 = f2bf_pk(v4[0], v4[1]);
        unsigned int p23 = f2bf_pk(v4[2], v4[3]);
        S[(elb + 0) * SROWE + n] = (unsigned short)(p01 & 0xFFFF);
        S[(elb + 1) * SROWE + n] = (unsigned short)(p01 >> 16);
        S[(elb + 2) * SROWE + n] = (unsigned short)(p23 & 0xFFFF);
        S[(elb + 3) * SROWE + n] = (unsigned short)(p23 >> 16);
    }

    floatx4 acc3[8];
    #pragma unroll
    for (int i = 0; i < 8; i++) acc3[i] = (floatx4){0, 0, 0, 0};
    #pragma unroll
    for (int kt = 0; kt < 4; kt++) {
        short8 afrag = *(const short8*)(arow + kt * 32 + quad * 8);
        int kb = kt * 4 + quad;
        #pragma unroll
        for (int nt = 0; nt < 8; nt++) {
            short8 bfrag = *(const short8*)(W1 + (size_t)(kb * 128 + nt * 16 + lrow) * 8);
            acc3[nt] = __builtin_amdgcn_mfma_f32_16x16x32_bf16(afrag, bfrag, acc3[nt], 0, 0, 0);
        }
    }
    #pragma unroll
    for (int nt = 0; nt < 8; nt++) {
        int n = nt * 16 + lrow;
        float bv = biasP[n];
        unsigned int p01 = f2fh_pk(acc3[nt][0] + bv, acc3[nt][1] + bv);
        unsigned int p23 = f2fh_pk(acc3[nt][2] + bv, acc3[nt][3] + bv);
        S[(elb + 0) * SROWE + 128 + n] = (unsigned short)(p01 & 0xFFFF);
        S[(elb + 1) * SROWE + 128 + n] = (unsigned short)(p01 >> 16);
        S[(elb + 2) * SROWE + 128 + n] = (unsigned short)(p23 & 0xFFFF);
        S[(elb + 3) * SROWE + 128 + n] = (unsigned short)(p23 >> 16);
    }
    __syncthreads();   // barrier 2

    for (int t = tid; t < 64 * 32; t += 256) {
        int rr = t / 32, c = t % 32;
        int row = m0 + rr;
        if (row < M) {
            if (c < 16)
                *(uintx4*)(hB + (size_t)row * 128 + c * 8) =
                    *(const uintx4*)(&S[rr * SROWE + c * 8]);
            else
                *(uintx4*)(Pout + (size_t)row * 128 + (c - 16) * 8) =
                    *(const uintx4*)(&S[rr * SROWE + 128 + (c - 16) * 8]);
        }
    }
}

// ---------------------------------------------------------------------------
extern "C" void kernel_launch(void* const* d_in, const int* in_sizes, int n_in,
                              void* d_out, int out_size, void* d_ws, size_t ws_size,
                              hipStream_t stream) {
    const float* h0   = (const float*)d_in[0];
    const int*   edges= (const int*)d_in[1];
    const float* W_in = (const float*)d_in[2];
    const float* b_in = (const float*)d_in[3];
    const float* eW1  = (const float*)d_in[4];
    const float* eb1  = (const float*)d_in[5];
    const float* eW2  = (const float*)d_in[6];
    const float* eb2  = (const float*)d_in[7];
    const float* nW1  = (const float*)d_in[8];
    const float* nb1  = (const float*)d_in[9];
    const float* nW2  = (const float*)d_in[10];
    const float* nb2  = (const float*)d_in[11];
    const float* W_out= (const float*)d_in[12];
    const float* b_out= (const float*)d_in[13];
    float* out = (float*)d_out;

    const int E = in_sizes[1] / 2;      // 800000
    const int* erow = edges;
    const int* ecol = edges + E;

    char* ws = (char*)d_ws;
    unsigned short* hbf  = (unsigned short*)(ws + 0);            // 12,800,000
    // (ws+12800000..38424576 free)
    unsigned short* P    = (unsigned short*)(ws + 38424576);     // 12,800,000 (f16)
    float*          agg  = (float*)(ws + 51224576);              // 12,800,000
    int2*           binned=(int2*)(ws + 51224576);               //  6,400,000 (aliases agg; consumed pre-zero)
    int2*           eidx = (int2*)(ws + 76824576);               //  6,400,000
    float*          biasP= (float*)(ws + 83224576);              //  2,048
    unsigned short* Winp = (unsigned short*)(ws + 83226624);     // 16,384
    unsigned short* Woutp= (unsigned short*)(ws + 83243008);     // 16,384
    unsigned short* W1p  = (unsigned short*)(ws + 83259392);     // 131,072
    unsigned short* eW2p = (unsigned short*)(ws + 83390464);     // 32,768 (f16)
    unsigned short* nW1p = (unsigned short*)(ws + 83423232);     // 196,608
    unsigned short* nW2p = (unsigned short*)(ws + 83619840);     // 131,072
    int*            countB=(int*)(ws + 83750912);                // 784
    int*            bucketBase=(int*)(ws + 83751936);            // 788
    int*            bucketCursor=(int*)(ws + 83752960);          // 784

    const int gemm_grid = (N_NODES + 63) / 64;    // 782
    const int edge_grid = (E + 63) / 64;          // 12500
    const int pack_grid = (int)((PACK_GRID_TOTAL + 255) / 256);
    const int bin_grid  = (E + BCHUNK - 1) / BCHUNK;   // 391

    // pack also zeroes countB (hist runs after, same stream)
    pack_kernel<<<pack_grid, 256, 0, stream>>>(W_in, W_out, eW1, eb1, eW2,
                                               nW1, nW2, Winp, Woutp, W1p,
                                               eW2p, nW1p, nW2p, biasP, countB);

    // binning (binned aliases agg; consumed by sort before embed's agg zero? 
    // no — sort_k reads binned BEFORE embed runs: order below is serial)
    hist_k<<<bin_grid, 256, 0, stream>>>(erow, countB, E);
    bucket_scan_k<<<1, 256, 0, stream>>>(countB, bucketBase, bucketCursor);
    bin_k<<<bin_grid, 256, 0, stream>>>(erow, ecol, bucketCursor, binned, E);
    sort_k<<<NBKT, 256, 0, stream>>>(binned, bucketBase, eidx);

    // h1 = h0 @ W_in + b_in; P0 = h1 @ W1'[0]; zeroes agg (after sort consumed
    // binned, which aliases agg)
    embed_fused_k<<<gemm_grid, 256, 0, stream>>>(
        h0, Winp, b_in, W1p, biasP, hbf, P, agg, N_NODES);

    for (int l = 0; l < 4; l++) {
        edge_fused_k<<<edge_grid, 256, 0, stream>>>(
            eidx, P, eW2p + (size_t)l * SE2, eb2 + (size_t)l * 64, agg, E);
        if (l < 3) {
            node_fused_k<0><<<gemm_grid, 512, 0, stream>>>(
                hbf, agg, nW1p + (size_t)l * SN1, nb1 + (size_t)l * 128,
                nW2p + (size_t)l * SN2, nb2 + (size_t)l * 128,
                W1p + (size_t)(l + 1) * SW1, biasP + (size_t)(l + 1) * 128,
                hbf, P, nullptr, agg, N_NODES);
        } else {
            node_fused_k<1><<<gemm_grid, 512, 0, stream>>>(
                hbf, agg, nW1p + (size_t)l * SN1, nb1 + (size_t)l * 128,
                nW2p + (size_t)l * SN2, nb2 + (size_t)l * 128,
                Woutp, b_out, nullptr, nullptr, out, nullptr, N_NODES);
        }
    }
}

// Round 9
// 396.942 us; speedup vs baseline: 1.0414x; 1.0106x over previous
//
#include <hip/hip_runtime.h>
#include <hip/hip_bf16.h>
#include <hip/hip_fp16.h>
#include <cstdint>
#include <cstddef>

#define N_NODES 50000
#define N_EDGES 800000
#define NBKT    196      // ceil(50000/256) buckets of 256 rows
#define BSH     8        // rows-per-bucket shift
#define BCHUNK  2048     // edges per bin_k block
#define CAP     6144     // max edges per bucket (mean 4082)

typedef __attribute__((ext_vector_type(8))) short short8;
typedef __attribute__((ext_vector_type(4))) float floatx4;
typedef __attribute__((ext_vector_type(2))) float floatx2;
typedef __attribute__((ext_vector_type(4))) unsigned int uintx4;
typedef __attribute__((ext_vector_type(2))) unsigned int uintx2;
typedef __attribute__((ext_vector_type(8))) _Float16 half8v;

__device__ inline float bf2f(unsigned short u) {
    union { unsigned int i; float f; } v; v.i = ((unsigned int)u) << 16; return v.f;
}
__device__ inline unsigned short f2bf(float f) {
    union { float f; unsigned int i; } v; v.f = f;
    unsigned int u = v.i;
    return (unsigned short)((u + 0x7FFFu + ((u >> 16) & 1u)) >> 16);
}
// packed RNE f32x2 -> bf16x2 (v_cvt_pk_bf16_f32 on gfx950)
__device__ inline unsigned int f2bf_pk(float a, float b) {
    __hip_bfloat162 h2 = __float22bfloat162_rn(make_float2(a, b));
    return *reinterpret_cast<unsigned int*>(&h2);
}
// f16 helpers (edge path is f16: packed ALU + mfma_f32_16x16x32_f16)
__device__ inline unsigned short f2fh(float f) {
    _Float16 h = (_Float16)f;
    return __builtin_bit_cast(unsigned short, h);
}
// packed f32x2 -> f16x2 via v_cvt_pkrtz_f16_f32 (1 instr)
// NOTE: builtin returns __fp16 ext_vector_type(2) on this clang — bit_cast it.
__device__ inline unsigned int f2fh_pk(float a, float b) {
    typedef __attribute__((ext_vector_type(2))) __fp16 h2v;
    h2v r = __builtin_amdgcn_cvt_pkrtz(a, b);
    return __builtin_bit_cast(unsigned int, r);
}
__device__ inline __half2 u2h(unsigned int u) { return __builtin_bit_cast(__half2, u); }
__device__ inline unsigned int h2u(__half2 h) { return __builtin_bit_cast(unsigned int, h); }
// f16 SiLU on a packed pair.
__device__ inline __half2 silu_h2(__half2 x) {
    const __half2 nlog2e = __float2half2_rn(-1.4426950408889634f);
    const __half2 one    = __float2half2_rn(1.0f);
    __half2 e = h2exp2(__hmul2(x, nlog2e));
    return __hmul2(x, h2rcp(__hadd2(e, one)));
}
// silu via v_rcp_f32 (1 ulp) instead of IEEE divide
__device__ inline float silu_f(float x) {
    float e = __expf(-x);
    return x * __builtin_amdgcn_rcpf(1.0f + e);
}

__device__ inline int block_excl_scan_256(int v, int* buf) {
    int tid = threadIdx.x;
    buf[tid] = v;
    __syncthreads();
    #pragma unroll
    for (int off = 1; off < 256; off <<= 1) {
        int t = (tid >= off) ? buf[tid - off] : 0;
        __syncthreads();
        buf[tid] += t;
        __syncthreads();
    }
    return buf[tid] - v;
}

// ---------------------------------------------------------------------------
// Pack kernel: fp32->bf16/f16 weight rearrangement into MFMA fragment order.
// R18: tail zeroes countB AND bucketCursor (both consumed after this dispatch).
// B-fragment order: Bp[(kb*NOUT + n)*8 + i] = B[(kb*8+i)*NOUT + n]
// ---------------------------------------------------------------------------
__device__ inline void pack_std(const float* __restrict__ src,
                                unsigned short* __restrict__ dst,
                                int NOUT, long j) {
    int i = (int)(j & 7);
    long rest = j >> 3;
    int n = (int)(rest % NOUT);
    int kb = (int)(rest / NOUT);
    dst[j] = f2bf(src[(long)(kb * 8 + i) * NOUT + n]);
}
__device__ inline void pack_std_h(const float* __restrict__ src,
                                  unsigned short* __restrict__ dst,
                                  int NOUT, long j) {
    int i = (int)(j & 7);
    long rest = j >> 3;
    int n = (int)(rest % NOUT);
    int kb = (int)(rest / NOUT);
    dst[j] = f2fh(src[(long)(kb * 8 + i) * NOUT + n]);
}

#define SW_IN 8192L
#define SW_OUT 8192L
#define SW1   16384L
#define SE2   4096L
#define SN1   24576L
#define SN2   16384L
#define SB    128L
#define PERL  (SW1 + SE2 + SN1 + SN2 + SB)
#define PACK_TOTAL (SW_IN + SW_OUT + 4 * PERL)
#define PACK_GRID_TOTAL (PACK_TOTAL + 2 * NBKT)

__global__ __launch_bounds__(256) void pack_kernel(
    const float* __restrict__ W_in,
    const float* __restrict__ W_out, const float* __restrict__ eW1,
    const float* __restrict__ eb1, const float* __restrict__ eW2,
    const float* __restrict__ nW1, const float* __restrict__ nW2,
    unsigned short* __restrict__ Winp,
    unsigned short* __restrict__ Woutp, unsigned short* __restrict__ W1p,
    unsigned short* __restrict__ eW2p, unsigned short* __restrict__ nW1p,
    unsigned short* __restrict__ nW2p, float* __restrict__ biasP,
    int* __restrict__ countB, int* __restrict__ bucketCursor)
{
    long idx = (long)blockIdx.x * 256 + threadIdx.x;
    if (idx >= PACK_TOTAL) {
        long t = idx - PACK_TOTAL;
        if (t < NBKT) countB[t] = 0;
        else if (t < 2 * NBKT) bucketCursor[t - NBKT] = 0;
        return;
    }
    long j = idx;
    if (j < SW_IN) { pack_std(W_in, Winp, 128, j); return; }
    j -= SW_IN;
    if (j < SW_OUT) { pack_std(W_out, Woutp, 64, j); return; }
    j -= SW_OUT;
    int l = (int)(j / PERL);
    long r = j % PERL;
    if (r < SW1) {
        int i = (int)(r & 7);
        int n = (int)((r >> 3) & 127);
        int kb = (int)(r >> 10);
        int k = kb * 8 + i;
        const float* w = eW1 + (long)l * 256 * 64;
        float v = (n < 64) ? w[(long)k * 64 + n] : w[(long)(128 + k) * 64 + (n - 64)];
        W1p[(long)l * SW1 + r] = f2bf(v);
        return;
    }
    r -= SW1;
    if (r < SE2) { pack_std_h(eW2 + (long)l * 4096, eW2p + (long)l * SE2, 64, r); return; }
    r -= SE2;
    if (r < SN1) { pack_std(nW1 + (long)l * 24576, nW1p + (long)l * SN1, 128, r); return; }
    r -= SN1;
    if (r < SN2) { pack_std(nW2 + (long)l * 16384, nW2p + (long)l * SN2, 128, r); return; }
    r -= SN2;
    biasP[(long)l * 128 + r] = (r < 64) ? eb1[(long)l * 64 + r] : 0.0f;
}

// ---------------------------------------------------------------------------
// Edge-sort pipeline. R18: bucket_scan_k eliminated — bin and sort compute
// the bucket prefix locally from countB; bucketCursor counts from 0.
// ---------------------------------------------------------------------------
__global__ __launch_bounds__(256) void hist_k(const int* __restrict__ erow,
                                              int* __restrict__ countB, int E) {
    __shared__ int c[NBKT];
    for (int i = threadIdx.x; i < NBKT; i += 256) c[i] = 0;
    __syncthreads();
    int j = blockIdx.x * BCHUNK + threadIdx.x;
    #pragma unroll
    for (int i = 0; i < BCHUNK / 256; i++, j += 256)
        if (j < E) atomicAdd(&c[erow[j] >> BSH], 1);
    __syncthreads();
    for (int i = threadIdx.x; i < NBKT; i += 256)
        if (c[i]) atomicAdd(&countB[i], c[i]);
}

#define SROWE 264
#define BE_SMEM_BYTES (64 * SROWE * 2)   // embed branch need (33792 B) >= bin need

// Merged [bin | embed] dispatch: blocks < binGrid run the binning scatter;
// the rest run the fused embedding GEMM. Independent data paths (bin:
// edges->binned/cursor; embed: h0/weights->hbf,P,agg) — binned no longer
// aliases agg, so embed's agg zero cannot clobber it.
__global__ __launch_bounds__(256) void bin_embed_k(
    const int* __restrict__ erow, const int* __restrict__ ecol,
    const int* __restrict__ countB, int* __restrict__ bucketCursor,
    int2* __restrict__ binned, int E, int binGrid,
    const float* __restrict__ h0, const unsigned short* __restrict__ Win,
    const float* __restrict__ b_in, const unsigned short* __restrict__ W1,
    const float* __restrict__ biasP,
    unsigned short* __restrict__ hB, unsigned short* __restrict__ Pout,
    float* __restrict__ aggZ, int M)
{
    __shared__ char SMEM[BE_SMEM_BYTES];
    const int tid = threadIdx.x;

    if (blockIdx.x < binGrid) {
        // ---------------- bin branch ----------------
        int* cnt      = (int*)SMEM;              // NBKT
        int* binStart = cnt + NBKT;              // NBKT
        int* gbase    = binStart + NBKT;         // NBKT
        int* scanbuf  = gbase + NBKT;            // 256
        int2* staged  = (int2*)(scanbuf + 256);  // BCHUNK (8B aligned: 3376%8==0)

        const int base = blockIdx.x * BCHUNK;
        const int nloc = min(BCHUNK, E - base);

        // local bucket prefix (replaces bucket_scan_k)
        int vcb = (tid < NBKT) ? countB[tid] : 0;
        int exclB = block_excl_scan_256(vcb, scanbuf);

        for (int i = tid; i < NBKT; i += 256) cnt[i] = 0;
        __syncthreads();

        int2 ed[BCHUNK / 256];
        int  bo[BCHUNK / 256];
        #pragma unroll
        for (int i = 0; i < BCHUNK / 256; i++) {
            int jl = i * 256 + tid;
            if (jl < nloc) {
                int j = base + jl;
                int r = erow[j], c = ecol[j];
                ed[i] = make_int2(r, c);
                int b = r >> BSH;
                int off = atomicAdd(&cnt[b], 1);
                bo[i] = (b << 12) | off;
            } else bo[i] = -1;
        }
        __syncthreads();

        int v = (tid < NBKT) ? cnt[tid] : 0;
        int excl = block_excl_scan_256(v, scanbuf);
        if (tid < NBKT) binStart[tid] = excl;
        if (tid < NBKT && v > 0)
            gbase[tid] = exclB + atomicAdd(&bucketCursor[tid], v);
        __syncthreads();

        #pragma unroll
        for (int i = 0; i < BCHUNK / 256; i++) {
            if (bo[i] >= 0)
                staged[binStart[bo[i] >> 12] + (bo[i] & 0xFFF)] = ed[i];
        }
        __syncthreads();

        for (int j = tid; j < nloc; j += 256) {
            int2 e = staged[j];
            int b = e.x >> BSH;
            binned[gbase[b] + (j - binStart[b])] = e;
        }
        return;
    }

    // ---------------- embed branch (R8 body) ----------------
    unsigned short* S = (unsigned short*)SMEM;
    const int m0 = (blockIdx.x - binGrid) * 64;
    const int wave = tid >> 6;
    const int lane = tid & 63;
    const int lrow = lane & 15;
    const int quad = lane >> 4;
    const int elb = wave * 16 + quad * 4;

    // staging: h0 f32 -> bf16 into S cols 0..63
    for (int t = tid; t < 64 * 16; t += 256) {
        int rr = t >> 4, c = t & 15;
        int row = m0 + rr;
        floatx4 v = {0, 0, 0, 0};
        if (row < M) v = *(const floatx4*)(h0 + (size_t)row * 64 + c * 4);
        uintx2 u = { f2bf_pk(v[0], v[1]), f2bf_pk(v[2], v[3]) };
        *(uintx2*)(&S[rr * SROWE + c * 4]) = u;
    }
    __syncthreads();   // barrier 1

    // zero this block's agg rows for layer 0 (fire-and-forget)
    {
        floatx4 z = {0, 0, 0, 0};
        for (int t = tid; t < 64 * 16; t += 256) {
            int rr = t >> 4, c = t & 15;
            int row = m0 + rr;
            if (row < M) *(floatx4*)(aggZ + (size_t)row * 64 + c * 4) = z;
        }
    }

    const unsigned short* arow = &S[(wave * 16 + lrow) * SROWE];

    floatx4 acc[8];
    #pragma unroll
    for (int i = 0; i < 8; i++) acc[i] = (floatx4){0, 0, 0, 0};
    #pragma unroll
    for (int kt = 0; kt < 2; kt++) {
        short8 afrag = *(const short8*)(arow + kt * 32 + quad * 8);
        int kb = kt * 4 + quad;
        #pragma unroll
        for (int nt = 0; nt < 8; nt++) {
            short8 bfrag = *(const short8*)(Win + (size_t)(kb * 128 + nt * 16 + lrow) * 8);
            acc[nt] = __builtin_amdgcn_mfma_f32_16x16x32_bf16(afrag, bfrag, acc[nt], 0, 0, 0);
        }
    }

    // epilogue: h1 -> S cols 0..127 (bf16)
    #pragma unroll
    for (int nt = 0; nt < 8; nt++) {
        int n = nt * 16 + lrow;
        float bv = b_in[n];
        floatx4 v4;
        #pragma unroll
        for (int r = 0; r < 4; r++) v4[r] = acc[nt][r] + bv;
        unsigned int p01 = f2bf_pk(v4[0], v4[1]);
        unsigned int p23 = f2bf_pk(v4[2], v4[3]);
        S[(elb + 0) * SROWE + n] = (unsigned short)(p01 & 0xFFFF);
        S[(elb + 1) * SROWE + n] = (unsigned short)(p01 >> 16);
        S[(elb + 2) * SROWE + n] = (unsigned short)(p23 & 0xFFFF);
        S[(elb + 3) * SROWE + n] = (unsigned short)(p23 >> 16);
    }

    floatx4 acc3[8];
    #pragma unroll
    for (int i = 0; i < 8; i++) acc3[i] = (floatx4){0, 0, 0, 0};
    #pragma unroll
    for (int kt = 0; kt < 4; kt++) {
        short8 afrag = *(const short8*)(arow + kt * 32 + quad * 8);
        int kb = kt * 4 + quad;
        #pragma unroll
        for (int nt = 0; nt < 8; nt++) {
            short8 bfrag = *(const short8*)(W1 + (size_t)(kb * 128 + nt * 16 + lrow) * 8);
            acc3[nt] = __builtin_amdgcn_mfma_f32_16x16x32_bf16(afrag, bfrag, acc3[nt], 0, 0, 0);
        }
    }
    #pragma unroll
    for (int nt = 0; nt < 8; nt++) {
        int n = nt * 16 + lrow;
        float bv = biasP[n];
        unsigned int p01 = f2fh_pk(acc3[nt][0] + bv, acc3[nt][1] + bv);
        unsigned int p23 = f2fh_pk(acc3[nt][2] + bv, acc3[nt][3] + bv);
        S[(elb + 0) * SROWE + 128 + n] = (unsigned short)(p01 & 0xFFFF);
        S[(elb + 1) * SROWE + 128 + n] = (unsigned short)(p01 >> 16);
        S[(elb + 2) * SROWE + 128 + n] = (unsigned short)(p23 & 0xFFFF);
        S[(elb + 3) * SROWE + 128 + n] = (unsigned short)(p23 >> 16);
    }
    __syncthreads();   // barrier 2

    for (int t = tid; t < 64 * 32; t += 256) {
        int rr = t / 32, c = t % 32;
        int row = m0 + rr;
        if (row < M) {
            if (c < 16)
                *(uintx4*)(hB + (size_t)row * 128 + c * 8) =
                    *(const uintx4*)(&S[rr * SROWE + c * 8]);
            else
                *(uintx4*)(Pout + (size_t)row * 128 + (c - 16) * 8) =
                    *(const uintx4*)(&S[rr * SROWE + 128 + (c - 16) * 8]);
        }
    }
}

__global__ __launch_bounds__(256) void sort_k(
    const int2* __restrict__ binned, const int* __restrict__ countB,
    int2* __restrict__ eidx)
{
    __shared__ int2 st[CAP];
    __shared__ int cnt[256];
    __shared__ int cur[256];
    __shared__ int scanbuf[256];
    __shared__ int baseS[2];
    const int b = blockIdx.x;
    const int tid = threadIdx.x;

    // local bucket prefix (replaces bucket_scan_k)
    {
        int v = (tid < NBKT) ? countB[tid] : 0;
        int excl = block_excl_scan_256(v, scanbuf);
        if (tid == b) { baseS[0] = excl; baseS[1] = excl + v; }
    }
    __syncthreads();
    const int s0 = baseS[0];
    int n = baseS[1] - s0;
    if (n > CAP) n = CAP;

    cnt[tid] = 0;
    __syncthreads();
    for (int j = tid; j < n; j += 256) {
        int2 e = binned[s0 + j];
        st[j] = e;
        atomicAdd(&cnt[e.x & 255], 1);
    }
    __syncthreads();
    int excl = block_excl_scan_256(cnt[tid], scanbuf);
    cur[tid] = excl;
    __syncthreads();
    for (int j = tid; j < n; j += 256) {
        int2 e = st[j];
        int pos = atomicAdd(&cur[e.x & 255], 1);
        eidx[s0 + pos] = e;
    }
}

// ---------------------------------------------------------------------------
// Fused edge + block-segmented aggregate over sorted edges (R8 body, best
// measured 44.0 µs: f32 M2s [el][68], segStartS reduction, f16 P/eW2 +
// f16 MFMA, bias in accumulators).
// ---------------------------------------------------------------------------
__global__ __launch_bounds__(256) void edge_fused_k(
    const int2* __restrict__ eidx,
    const unsigned short* __restrict__ P,    // [N,128] f16: 0..63 top(+b1), 64..127 bot
    const unsigned short* __restrict__ Bp,   // eW2 frag order, f16
    const float* __restrict__ b2, float* __restrict__ agg, int E)
{
    __shared__ float M2s[64 * 68];
    __shared__ int ridS[64];
    __shared__ short segStartS[66];
    __shared__ int nsegS;
    const int tid = threadIdx.x;
    const int wave = tid >> 6;
    const int lane = tid & 63;
    const int lrow = lane & 15;
    const int quad = lane >> 4;
    const int e0 = blockIdx.x * 64;
    const int el = wave * 16 + lrow;
    const int e = e0 + el;

    // bias preloaded into the MFMA accumulators
    floatx4 acc[4];
    #pragma unroll
    for (int nt = 0; nt < 4; nt++) {
        float bv = b2[nt * 16 + lrow];
        acc[nt] = (floatx4){bv, bv, bv, bv};
    }

    half8v af0 = {};
    half8v af1 = {};
    if (e < E) {
        int2 rc = eidx[e];
        int rr = rc.x, cc = rc.y;
        if (quad == 0) ridS[el] = rr;
        const uintx4* pt = (const uintx4*)(P + (size_t)rr * 128 + quad * 8);
        const uintx4* pb = (const uintx4*)(P + (size_t)cc * 128 + 64 + quad * 8);
        uintx4 t0 = pt[0], t1 = pt[4];
        uintx4 b0 = pb[0], b1 = pb[4];
        uintx4 O0, O1;
        #pragma unroll
        for (int i = 0; i < 4; i++) {
            O0[i] = h2u(silu_h2(__hadd2(u2h(t0[i]), u2h(b0[i]))));
            O1[i] = h2u(silu_h2(__hadd2(u2h(t1[i]), u2h(b1[i]))));
        }
        af0 = __builtin_bit_cast(half8v, O0);
        af1 = __builtin_bit_cast(half8v, O1);
    } else if (quad == 0) {
        ridS[el] = -1;
    }

    #pragma unroll
    for (int nt = 0; nt < 4; nt++) {
        half8v bf0 = *(const half8v*)(Bp + (size_t)((0 * 4 + quad) * 64 + nt * 16 + lrow) * 8);
        acc[nt] = __builtin_amdgcn_mfma_f32_16x16x32_f16(af0, bf0, acc[nt], 0, 0, 0);
        half8v bf1 = *(const half8v*)(Bp + (size_t)((1 * 4 + quad) * 64 + nt * 16 + lrow) * 8);
        acc[nt] = __builtin_amdgcn_mfma_f32_16x16x32_f16(af1, bf1, acc[nt], 0, 0, 0);
    }

    #pragma unroll
    for (int nt = 0; nt < 4; nt++) {
        int n = nt * 16 + lrow;
        #pragma unroll
        for (int r = 0; r < 4; r++) {
            int el2 = wave * 16 + quad * 4 + r;
            M2s[el2 * 68 + n] = silu_f(acc[nt][r]);
        }
    }
    __syncthreads();

    if (tid < 64) {
        bool st = (ridS[tid] >= 0) && (tid == 0 || ridS[tid] != ridS[tid - 1]);
        unsigned long long m = __ballot(st);
        if (st) {
            int pos = __popcll(m & ((1ull << tid) - 1));
            segStartS[pos] = (short)tid;
        }
        if (tid == 0) {
            int ns = __popcll(m);
            nsegS = ns;
            int nvalid = E - e0;
            if (nvalid > 64) nvalid = 64;
            segStartS[ns] = (short)nvalid;
        }
    }
    __syncthreads();

    {
        int f = tid & 63;
        int g = tid >> 6;
        int ns = nsegS;
        for (int j = g; j < ns; j += 4) {
            int a = segStartS[j], b = segStartS[j + 1];
            float s = 0.0f;
            for (int el2 = a; el2 < b; el2++) s += M2s[el2 * 68 + f];
            int rv = ridS[a];
            if (j == 0 || j == ns - 1)
                atomicAdd(&agg[(size_t)rv * 64 + f], s);
            else
                agg[(size_t)rv * 64 + f] = s;
        }
    }
}

// ---------------------------------------------------------------------------
// Fused node-side chain (R8 body: residual from LDS bf16, no hFT).
// ---------------------------------------------------------------------------
#define SROW 264
template<int FINAL>
__global__ __launch_bounds__(512) void node_fused_k(
    const unsigned short* __restrict__ hbf, const float* __restrict__ agg,
    const unsigned short* __restrict__ W1, const float* __restrict__ b1,
    const unsigned short* __restrict__ W2, const float* __restrict__ b2,
    const unsigned short* __restrict__ B3, const float* __restrict__ bias3,
    unsigned short* __restrict__ hB, unsigned short* __restrict__ Pout,
    float* __restrict__ outF, float* __restrict__ aggZ, int M)
{
    __shared__ unsigned short S[64 * SROW];
    const int tid = threadIdx.x;
    const int m0 = blockIdx.x * 64;
    const int wave = tid >> 6;
    const int lane = tid & 63;
    const int lrow = lane & 15;
    const int quad = lane >> 4;
    const int g = wave >> 1;          // row group 0..3
    const int h = wave & 1;           // N half
    const int elb = g * 16 + quad * 4;

    // agg A-fragments straight into registers (kt=4,5 of the K=192 A-op)
    short8 afa0, afa1;
    {
        const float* ap = agg + (size_t)(m0 + g * 16 + lrow) * 64;
        floatx4 q0 = *(const floatx4*)(ap + quad * 8);
        floatx4 q1 = *(const floatx4*)(ap + quad * 8 + 4);
        floatx4 q2 = *(const floatx4*)(ap + 32 + quad * 8);
        floatx4 q3 = *(const floatx4*)(ap + 32 + quad * 8 + 4);
        unsigned int c0[4] = { f2bf_pk(q0[0], q0[1]), f2bf_pk(q0[2], q0[3]),
                               f2bf_pk(q1[0], q1[1]), f2bf_pk(q1[2], q1[3]) };
        unsigned int c1[4] = { f2bf_pk(q2[0], q2[1]), f2bf_pk(q2[2], q2[3]),
                               f2bf_pk(q3[0], q3[1]), f2bf_pk(q3[2], q3[3]) };
        afa0 = *(const short8*)c0;
        afa1 = *(const short8*)c1;
    }

    // staging: h (128 bf16) only -> S cols 0..127
    for (int t = tid; t < 64 * 16; t += 512) {
        int rr = t >> 4, c = t & 15;
        int row = m0 + rr;
        uintx4 val = {0, 0, 0, 0};
        if (row < M) val = *(const uintx4*)(hbf + (size_t)row * 128 + c * 8);
        *(uintx4*)(&S[rr * SROW + c * 8]) = val;
    }
    __syncthreads();   // B1

    // zero this block's agg rows for the next layer
    if (!FINAL) {
        floatx4 z = {0, 0, 0, 0};
        for (int t = tid; t < 64 * 16; t += 512) {
            int rr = t >> 4, c = t & 15;
            int row = m0 + rr;
            if (row < M) *(floatx4*)(aggZ + (size_t)row * 64 + c * 4) = z;
        }
    }

    const unsigned short* arow = &S[(g * 16 + lrow) * SROW];

    // ---- phase A MFMA: K=192 (kt 0..3 from LDS, kt 4..5 from registers) ----
    floatx4 acc[4];
    #pragma unroll
    for (int i = 0; i < 4; i++) acc[i] = (floatx4){0, 0, 0, 0};
    #pragma unroll
    for (int kt = 0; kt < 4; kt++) {
        short8 afrag = *(const short8*)(arow + kt * 32 + quad * 8);
        int kb = kt * 4 + quad;
        #pragma unroll
        for (int j = 0; j < 4; j++) {
            int n = (4 * h + j) * 16 + lrow;
            short8 bfrag = *(const short8*)(W1 + (size_t)(kb * 128 + n) * 8);
            acc[j] = __builtin_amdgcn_mfma_f32_16x16x32_bf16(afrag, bfrag, acc[j], 0, 0, 0);
        }
    }
    #pragma unroll
    for (int j = 0; j < 4; j++) {
        int n = (4 * h + j) * 16 + lrow;
        short8 b4 = *(const short8*)(W1 + (size_t)((16 + quad) * 128 + n) * 8);
        acc[j] = __builtin_amdgcn_mfma_f32_16x16x32_bf16(afa0, b4, acc[j], 0, 0, 0);
        short8 b5 = *(const short8*)(W1 + (size_t)((20 + quad) * 128 + n) * 8);
        acc[j] = __builtin_amdgcn_mfma_f32_16x16x32_bf16(afa1, b5, acc[j], 0, 0, 0);
    }

    // epilogue A: t -> S cols 128..255
    #pragma unroll
    for (int j = 0; j < 4; j++) {
        int n = (4 * h + j) * 16 + lrow;
        float bv = b1[n];
        unsigned int p01 = f2bf_pk(silu_f(acc[j][0] + bv), silu_f(acc[j][1] + bv));
        unsigned int p23 = f2bf_pk(silu_f(acc[j][2] + bv), silu_f(acc[j][3] + bv));
        S[(elb + 0) * SROW + 128 + n] = (unsigned short)(p01 & 0xFFFF);
        S[(elb + 1) * SROW + 128 + n] = (unsigned short)(p01 >> 16);
        S[(elb + 2) * SROW + 128 + n] = (unsigned short)(p23 & 0xFFFF);
        S[(elb + 3) * SROW + 128 + n] = (unsigned short)(p23 >> 16);
    }
    __syncthreads();   // B2: t complete

    // ---- phase B MFMA: K=128 over t (cols 128..255) ----
    floatx4 acc2[4];
    #pragma unroll
    for (int i = 0; i < 4; i++) acc2[i] = (floatx4){0, 0, 0, 0};
    #pragma unroll
    for (int kt = 0; kt < 4; kt++) {
        short8 afrag = *(const short8*)(arow + 128 + kt * 32 + quad * 8);
        int kb = kt * 4 + quad;
        #pragma unroll
        for (int j = 0; j < 4; j++) {
            int n = (4 * h + j) * 16 + lrow;
            short8 bfrag = *(const short8*)(W2 + (size_t)(kb * 128 + n) * 8);
            acc2[j] = __builtin_amdgcn_mfma_f32_16x16x32_bf16(afrag, bfrag, acc2[j], 0, 0, 0);
        }
    }

    // epilogue B: h_new = acc2 + b2 + res(LDS bf16, owner cells) -> S cols 0..127
    #pragma unroll
    for (int j = 0; j < 4; j++) {
        int n = (4 * h + j) * 16 + lrow;
        float bv = b2[n];
        floatx4 v4;
        #pragma unroll
        for (int r = 0; r < 4; r++) {
            float res = bf2f(S[(elb + r) * SROW + n]);
            v4[r] = acc2[j][r] + bv + res;
        }
        unsigned int p01 = f2bf_pk(v4[0], v4[1]);
        unsigned int p23 = f2bf_pk(v4[2], v4[3]);
        S[(elb + 0) * SROW + n] = (unsigned short)(p01 & 0xFFFF);
        S[(elb + 1) * SROW + n] = (unsigned short)(p01 >> 16);
        S[(elb + 2) * SROW + n] = (unsigned short)(p23 & 0xFFFF);
        S[(elb + 3) * SROW + n] = (unsigned short)(p23 >> 16);
    }
    __syncthreads();   // B3: h_new complete (all t reads done)

    // ---- phase C MFMA: K=128 -> P (128, f16) or out (64, f32) ----
    constexpr int NT3 = FINAL ? 2 : 4;
    constexpr int NO3 = FINAL ? 64 : 128;
    floatx4 acc3[NT3];
    #pragma unroll
    for (int i = 0; i < NT3; i++) acc3[i] = (floatx4){0, 0, 0, 0};
    #pragma unroll
    for (int kt = 0; kt < 4; kt++) {
        short8 afrag = *(const short8*)(arow + kt * 32 + quad * 8);
        int kb = kt * 4 + quad;
        #pragma unroll
        for (int j = 0; j < NT3; j++) {
            int n = (NT3 * h + j) * 16 + lrow;
            short8 bfrag = *(const short8*)(B3 + (size_t)(kb * NO3 + n) * 8);
            acc3[j] = __builtin_amdgcn_mfma_f32_16x16x32_bf16(afrag, bfrag, acc3[j], 0, 0, 0);
        }
    }
    // epilogue C -> S cols 128..255 (f16 P) or fp32 out region (same cols)
    #pragma unroll
    for (int j = 0; j < NT3; j++) {
        int n = (NT3 * h + j) * 16 + lrow;
        float bv = bias3[n];
        if (FINAL) {
            #pragma unroll
            for (int r = 0; r < 4; r++)
                ((float*)(&S[(elb + r) * SROW + 128]))[n] = acc3[j][r] + bv;
        } else {
            unsigned int p01 = f2fh_pk(acc3[j][0] + bv, acc3[j][1] + bv);
            unsigned int p23 = f2fh_pk(acc3[j][2] + bv, acc3[j][3] + bv);
            S[(elb + 0) * SROW + 128 + n] = (unsigned short)(p01 & 0xFFFF);
            S[(elb + 1) * SROW + 128 + n] = (unsigned short)(p01 >> 16);
            S[(elb + 2) * SROW + 128 + n] = (unsigned short)(p23 & 0xFFFF);
            S[(elb + 3) * SROW + 128 + n] = (unsigned short)(p23 >> 16);
        }
    }
    __syncthreads();   // B4

    // cooperative wide stores
    if (FINAL) {
        for (int t = tid; t < 64 * 16; t += 512) {
            int rr = t >> 4, c = t & 15;
            int row = m0 + rr;
            if (row < M)
                *(floatx4*)(outF + (size_t)row * 64 + c * 4) =
                    *(const floatx4*)((const float*)(&S[rr * SROW + 128]) + c * 4);
        }
    } else {
        for (int t = tid; t < 64 * 32; t += 512) {
            int rr = t >> 5, c = t & 31;
            int row = m0 + rr;
            if (row < M) {
                if (c < 16)
                    *(uintx4*)(hB + (size_t)row * 128 + c * 8) =
                        *(const uintx4*)(&S[rr * SROW + c * 8]);
                else
                    *(uintx4*)(Pout + (size_t)row * 128 + (c - 16) * 8) =
                        *(const uintx4*)(&S[rr * SROW + 128 + (c - 16) * 8]);
            }
        }
    }
}

// ---------------------------------------------------------------------------
extern "C" void kernel_launch(void* const* d_in, const int* in_sizes, int n_in,
                              void* d_out, int out_size, void* d_ws, size_t ws_size,
                              hipStream_t stream) {
    const float* h0   = (const float*)d_in[0];
    const int*   edges= (const int*)d_in[1];
    const float* W_in = (const float*)d_in[2];
    const float* b_in = (const float*)d_in[3];
    const float* eW1  = (const float*)d_in[4];
    const float* eb1  = (const float*)d_in[5];
    const float* eW2  = (const float*)d_in[6];
    const float* eb2  = (const float*)d_in[7];
    const float* nW1  = (const float*)d_in[8];
    const float* nb1  = (const float*)d_in[9];
    const float* nW2  = (const float*)d_in[10];
    const float* nb2  = (const float*)d_in[11];
    const float* W_out= (const float*)d_in[12];
    const float* b_out= (const float*)d_in[13];
    float* out = (float*)d_out;

    const int E = in_sizes[1] / 2;      // 800000
    const int* erow = edges;
    const int* ecol = edges + E;

    char* ws = (char*)d_ws;
    unsigned short* hbf  = (unsigned short*)(ws + 0);            // 12,800,000
    int2*           binned=(int2*)(ws + 12800000);               //  6,400,000 (own region — no longer aliases agg)
    unsigned short* P    = (unsigned short*)(ws + 38424576);     // 12,800,000 (f16)
    float*          agg  = (float*)(ws + 51224576);              // 12,800,000
    int2*           eidx = (int2*)(ws + 76824576);               //  6,400,000
    float*          biasP= (float*)(ws + 83224576);              //  2,048
    unsigned short* Winp = (unsigned short*)(ws + 83226624);     // 16,384
    unsigned short* Woutp= (unsigned short*)(ws + 83243008);     // 16,384
    unsigned short* W1p  = (unsigned short*)(ws + 83259392);     // 131,072
    unsigned short* eW2p = (unsigned short*)(ws + 83390464);     // 32,768 (f16)
    unsigned short* nW1p = (unsigned short*)(ws + 83423232);     // 196,608
    unsigned short* nW2p = (unsigned short*)(ws + 83619840);     // 131,072
    int*            countB=(int*)(ws + 83750912);                // 784
    int*            bucketCursor=(int*)(ws + 83752960);          // 784

    const int gemm_grid = (N_NODES + 63) / 64;    // 782
    const int edge_grid = (E + 63) / 64;          // 12500
    const int pack_grid = (int)((PACK_GRID_TOTAL + 255) / 256);
    const int bin_grid  = (E + BCHUNK - 1) / BCHUNK;   // 391

    // pack also zeroes countB + bucketCursor (consumers run in later dispatches)
    pack_kernel<<<pack_grid, 256, 0, stream>>>(W_in, W_out, eW1, eb1, eW2,
                                               nW1, nW2, Winp, Woutp, W1p,
                                               eW2p, nW1p, nW2p, biasP,
                                               countB, bucketCursor);

    hist_k<<<bin_grid, 256, 0, stream>>>(erow, countB, E);

    // merged: binning scatter (blocks 0..390) + fused embedding (rest).
    // Independent data paths; binned no longer aliases agg.
    bin_embed_k<<<bin_grid + gemm_grid, 256, 0, stream>>>(
        erow, ecol, countB, bucketCursor, binned, E, bin_grid,
        h0, Winp, b_in, W1p, biasP, hbf, P, agg, N_NODES);

    sort_k<<<NBKT, 256, 0, stream>>>(binned, countB, eidx);

    for (int l = 0; l < 4; l++) {
        edge_fused_k<<<edge_grid, 256, 0, stream>>>(
            eidx, P, eW2p + (size_t)l * SE2, eb2 + (size_t)l * 64, agg, E);
        if (l < 3) {
            node_fused_k<0><<<gemm_grid, 512, 0, stream>>>(
                hbf, agg, nW1p + (size_t)l * SN1, nb1 + (size_t)l * 128,
                nW2p + (size_t)l * SN2, nb2 + (size_t)l * 128,
                W1p + (size_t)(l + 1) * SW1, biasP + (size_t)(l + 1) * 128,
                hbf, P, nullptr, agg, N_NODES);
        } else {
            node_fused_k<1><<<gemm_grid, 512, 0, stream>>>(
                hbf, agg, nW1p + (size_t)l * SN1, nb1 + (size_t)l * 128,
                nW2p + (size_t)l * SN2, nb2 + (size_t)l * 128,
                Woutp, b_out, nullptr, nullptr, out, nullptr, N_NODES);
        }
    }
}

// Round 10
// 385.069 us; speedup vs baseline: 1.0735x; 1.0308x over previous
//
#include <hip/hip_runtime.h>
#include <hip/hip_bf16.h>
#include <hip/hip_fp16.h>
#include <cstdint>
#include <cstddef>

#define N_NODES 50000
#define N_EDGES 800000
#define NBKT    196      // ceil(50000/256) buckets of 256 rows
#define BSH     8        // rows-per-bucket shift
#define BCHUNK  2048     // edges per bin_k block
#define CAP     6144     // fixed bucket capacity (mean 4082, max ~4400)

typedef __attribute__((ext_vector_type(8))) short short8;
typedef __attribute__((ext_vector_type(4))) float floatx4;
typedef __attribute__((ext_vector_type(2))) float floatx2;
typedef __attribute__((ext_vector_type(4))) unsigned int uintx4;
typedef __attribute__((ext_vector_type(2))) unsigned int uintx2;
typedef __attribute__((ext_vector_type(8))) _Float16 half8v;

__device__ inline float bf2f(unsigned short u) {
    union { unsigned int i; float f; } v; v.i = ((unsigned int)u) << 16; return v.f;
}
__device__ inline unsigned short f2bf(float f) {
    union { float f; unsigned int i; } v; v.f = f;
    unsigned int u = v.i;
    return (unsigned short)((u + 0x7FFFu + ((u >> 16) & 1u)) >> 16);
}
// packed RNE f32x2 -> bf16x2 (v_cvt_pk_bf16_f32 on gfx950)
__device__ inline unsigned int f2bf_pk(float a, float b) {
    __hip_bfloat162 h2 = __float22bfloat162_rn(make_float2(a, b));
    return *reinterpret_cast<unsigned int*>(&h2);
}
// f16 helpers (edge path is f16: packed ALU + mfma_f32_16x16x32_f16)
__device__ inline unsigned short f2fh(float f) {
    _Float16 h = (_Float16)f;
    return __builtin_bit_cast(unsigned short, h);
}
// packed f32x2 -> f16x2 via v_cvt_pkrtz_f16_f32 (1 instr)
// NOTE: builtin returns __fp16 ext_vector_type(2) on this clang — bit_cast it.
__device__ inline unsigned int f2fh_pk(float a, float b) {
    typedef __attribute__((ext_vector_type(2))) __fp16 h2v;
    h2v r = __builtin_amdgcn_cvt_pkrtz(a, b);
    return __builtin_bit_cast(unsigned int, r);
}
__device__ inline __half2 u2h(unsigned int u) { return __builtin_bit_cast(__half2, u); }
__device__ inline unsigned int h2u(__half2 h) { return __builtin_bit_cast(unsigned int, h); }
// f16 SiLU on a packed pair.
__device__ inline __half2 silu_h2(__half2 x) {
    const __half2 nlog2e = __float2half2_rn(-1.4426950408889634f);
    const __half2 one    = __float2half2_rn(1.0f);
    __half2 e = h2exp2(__hmul2(x, nlog2e));
    return __hmul2(x, h2rcp(__hadd2(e, one)));
}
// silu via v_rcp_f32 (1 ulp) instead of IEEE divide
__device__ inline float silu_f(float x) {
    float e = __expf(-x);
    return x * __builtin_amdgcn_rcpf(1.0f + e);
}

__device__ inline int block_excl_scan_256(int v, int* buf) {
    int tid = threadIdx.x;
    buf[tid] = v;
    __syncthreads();
    #pragma unroll
    for (int off = 1; off < 256; off <<= 1) {
        int t = (tid >= off) ? buf[tid - off] : 0;
        __syncthreads();
        buf[tid] += t;
        __syncthreads();
    }
    return buf[tid] - v;
}

// ---------------------------------------------------------------------------
// Pack kernel: fp32->bf16/f16 weight rearrangement into MFMA fragment order.
// R19: tail zeroes bucketCursor only (hist_k + countB eliminated).
// B-fragment order: Bp[(kb*NOUT + n)*8 + i] = B[(kb*8+i)*NOUT + n]
// ---------------------------------------------------------------------------
__device__ inline void pack_std(const float* __restrict__ src,
                                unsigned short* __restrict__ dst,
                                int NOUT, long j) {
    int i = (int)(j & 7);
    long rest = j >> 3;
    int n = (int)(rest % NOUT);
    int kb = (int)(rest / NOUT);
    dst[j] = f2bf(src[(long)(kb * 8 + i) * NOUT + n]);
}
__device__ inline void pack_std_h(const float* __restrict__ src,
                                  unsigned short* __restrict__ dst,
                                  int NOUT, long j) {
    int i = (int)(j & 7);
    long rest = j >> 3;
    int n = (int)(rest % NOUT);
    int kb = (int)(rest / NOUT);
    dst[j] = f2fh(src[(long)(kb * 8 + i) * NOUT + n]);
}

#define SW_IN 8192L
#define SW_OUT 8192L
#define SW1   16384L
#define SE2   4096L
#define SN1   24576L
#define SN2   16384L
#define SB    128L
#define PERL  (SW1 + SE2 + SN1 + SN2 + SB)
#define PACK_TOTAL (SW_IN + SW_OUT + 4 * PERL)
#define PACK_GRID_TOTAL (PACK_TOTAL + NBKT)

__global__ __launch_bounds__(256) void pack_kernel(
    const float* __restrict__ W_in,
    const float* __restrict__ W_out, const float* __restrict__ eW1,
    const float* __restrict__ eb1, const float* __restrict__ eW2,
    const float* __restrict__ nW1, const float* __restrict__ nW2,
    unsigned short* __restrict__ Winp,
    unsigned short* __restrict__ Woutp, unsigned short* __restrict__ W1p,
    unsigned short* __restrict__ eW2p, unsigned short* __restrict__ nW1p,
    unsigned short* __restrict__ nW2p, float* __restrict__ biasP,
    int* __restrict__ bucketCursor)
{
    long idx = (long)blockIdx.x * 256 + threadIdx.x;
    if (idx >= PACK_TOTAL) {
        long t = idx - PACK_TOTAL;
        if (t < NBKT) bucketCursor[t] = 0;
        return;
    }
    long j = idx;
    if (j < SW_IN) { pack_std(W_in, Winp, 128, j); return; }
    j -= SW_IN;
    if (j < SW_OUT) { pack_std(W_out, Woutp, 64, j); return; }
    j -= SW_OUT;
    int l = (int)(j / PERL);
    long r = j % PERL;
    if (r < SW1) {
        int i = (int)(r & 7);
        int n = (int)((r >> 3) & 127);
        int kb = (int)(r >> 10);
        int k = kb * 8 + i;
        const float* w = eW1 + (long)l * 256 * 64;
        float v = (n < 64) ? w[(long)k * 64 + n] : w[(long)(128 + k) * 64 + (n - 64)];
        W1p[(long)l * SW1 + r] = f2bf(v);
        return;
    }
    r -= SW1;
    if (r < SE2) { pack_std_h(eW2 + (long)l * 4096, eW2p + (long)l * SE2, 64, r); return; }
    r -= SE2;
    if (r < SN1) { pack_std(nW1 + (long)l * 24576, nW1p + (long)l * SN1, 128, r); return; }
    r -= SN1;
    if (r < SN2) { pack_std(nW2 + (long)l * 16384, nW2p + (long)l * SN2, 128, r); return; }
    r -= SN2;
    biasP[(long)l * 128 + r] = (r < 64) ? eb1[(long)l * 64 + r] : 0.0f;
}

// ---------------------------------------------------------------------------
// R19: hist_k ELIMINATED. binned is now fixed-capacity bucket regions
// (bucket b occupies binned[b*CAP .. b*CAP+CAP)); bin blocks reserve
// in-bucket slots via bucketCursor atomics (no global prefix needed).
// sort_k recovers counts from the final cursor values.
// ---------------------------------------------------------------------------
#define SROWE 264
#define BE_SMEM_BYTES (64 * SROWE * 2)   // embed branch need (33792 B) >= bin need

// Merged [bin | embed] dispatch: blocks < binGrid run the binning scatter;
// the rest run the fused embedding GEMM. Independent data paths.
__global__ __launch_bounds__(256) void bin_embed_k(
    const int* __restrict__ erow, const int* __restrict__ ecol,
    int* __restrict__ bucketCursor,
    int2* __restrict__ binned, int E, int binGrid,
    const float* __restrict__ h0, const unsigned short* __restrict__ Win,
    const float* __restrict__ b_in, const unsigned short* __restrict__ W1,
    const float* __restrict__ biasP,
    unsigned short* __restrict__ hB, unsigned short* __restrict__ Pout,
    float* __restrict__ aggZ, int M)
{
    __shared__ char SMEM[BE_SMEM_BYTES];
    const int tid = threadIdx.x;

    if (blockIdx.x < binGrid) {
        // ---------------- bin branch ----------------
        int* cnt      = (int*)SMEM;              // NBKT
        int* binStart = cnt + NBKT;              // NBKT
        int* gbase    = binStart + NBKT;         // NBKT (in-bucket base)
        int* scanbuf  = gbase + NBKT;            // 256
        int2* staged  = (int2*)(scanbuf + 256);  // BCHUNK

        const int base = blockIdx.x * BCHUNK;
        const int nloc = min(BCHUNK, E - base);

        for (int i = tid; i < NBKT; i += 256) cnt[i] = 0;
        __syncthreads();

        int2 ed[BCHUNK / 256];
        int  bo[BCHUNK / 256];
        #pragma unroll
        for (int i = 0; i < BCHUNK / 256; i++) {
            int jl = i * 256 + tid;
            if (jl < nloc) {
                int j = base + jl;
                int r = erow[j], c = ecol[j];
                ed[i] = make_int2(r, c);
                int b = r >> BSH;
                int off = atomicAdd(&cnt[b], 1);
                bo[i] = (b << 12) | off;
            } else bo[i] = -1;
        }
        __syncthreads();

        int v = (tid < NBKT) ? cnt[tid] : 0;
        int excl = block_excl_scan_256(v, scanbuf);
        if (tid < NBKT) binStart[tid] = excl;
        if (tid < NBKT && v > 0)
            gbase[tid] = atomicAdd(&bucketCursor[tid], v);
        __syncthreads();

        #pragma unroll
        for (int i = 0; i < BCHUNK / 256; i++) {
            if (bo[i] >= 0)
                staged[binStart[bo[i] >> 12] + (bo[i] & 0xFFF)] = ed[i];
        }
        __syncthreads();

        for (int j = tid; j < nloc; j += 256) {
            int2 e = staged[j];
            int b = e.x >> BSH;
            int off = gbase[b] + (j - binStart[b]);
            if (off < CAP)
                binned[(size_t)b * CAP + off] = e;
        }
        return;
    }

    // ---------------- embed branch ----------------
    unsigned short* S = (unsigned short*)SMEM;
    const int m0 = (blockIdx.x - binGrid) * 64;
    const int wave = tid >> 6;
    const int lane = tid & 63;
    const int lrow = lane & 15;
    const int quad = lane >> 4;
    const int elb = wave * 16 + quad * 4;

    // staging: h0 f32 -> bf16 into S cols 0..63
    for (int t = tid; t < 64 * 16; t += 256) {
        int rr = t >> 4, c = t & 15;
        int row = m0 + rr;
        floatx4 v = {0, 0, 0, 0};
        if (row < M) v = *(const floatx4*)(h0 + (size_t)row * 64 + c * 4);
        uintx2 u = { f2bf_pk(v[0], v[1]), f2bf_pk(v[2], v[3]) };
        *(uintx2*)(&S[rr * SROWE + c * 4]) = u;
    }
    __syncthreads();   // barrier 1

    // zero this block's agg rows for layer 0 (fire-and-forget)
    {
        floatx4 z = {0, 0, 0, 0};
        for (int t = tid; t < 64 * 16; t += 256) {
            int rr = t >> 4, c = t & 15;
            int row = m0 + rr;
            if (row < M) *(floatx4*)(aggZ + (size_t)row * 64 + c * 4) = z;
        }
    }

    const unsigned short* arow = &S[(wave * 16 + lrow) * SROWE];

    floatx4 acc[8];
    #pragma unroll
    for (int i = 0; i < 8; i++) acc[i] = (floatx4){0, 0, 0, 0};
    #pragma unroll
    for (int kt = 0; kt < 2; kt++) {
        short8 afrag = *(const short8*)(arow + kt * 32 + quad * 8);
        int kb = kt * 4 + quad;
        #pragma unroll
        for (int nt = 0; nt < 8; nt++) {
            short8 bfrag = *(const short8*)(Win + (size_t)(kb * 128 + nt * 16 + lrow) * 8);
            acc[nt] = __builtin_amdgcn_mfma_f32_16x16x32_bf16(afrag, bfrag, acc[nt], 0, 0, 0);
        }
    }

    // epilogue: h1 -> S cols 0..127 (bf16)
    #pragma unroll
    for (int nt = 0; nt < 8; nt++) {
        int n = nt * 16 + lrow;
        float bv = b_in[n];
        floatx4 v4;
        #pragma unroll
        for (int r = 0; r < 4; r++) v4[r] = acc[nt][r] + bv;
        unsigned int p01 = f2bf_pk(v4[0], v4[1]);
        unsigned int p23 = f2bf_pk(v4[2], v4[3]);
        S[(elb + 0) * SROWE + n] = (unsigned short)(p01 & 0xFFFF);
        S[(elb + 1) * SROWE + n] = (unsigned short)(p01 >> 16);
        S[(elb + 2) * SROWE + n] = (unsigned short)(p23 & 0xFFFF);
        S[(elb + 3) * SROWE + n] = (unsigned short)(p23 >> 16);
    }

    floatx4 acc3[8];
    #pragma unroll
    for (int i = 0; i < 8; i++) acc3[i] = (floatx4){0, 0, 0, 0};
    #pragma unroll
    for (int kt = 0; kt < 4; kt++) {
        short8 afrag = *(const short8*)(arow + kt * 32 + quad * 8);
        int kb = kt * 4 + quad;
        #pragma unroll
        for (int nt = 0; nt < 8; nt++) {
            short8 bfrag = *(const short8*)(W1 + (size_t)(kb * 128 + nt * 16 + lrow) * 8);
            acc3[nt] = __builtin_amdgcn_mfma_f32_16x16x32_bf16(afrag, bfrag, acc3[nt], 0, 0, 0);
        }
    }
    #pragma unroll
    for (int nt = 0; nt < 8; nt++) {
        int n = nt * 16 + lrow;
        float bv = biasP[n];
        unsigned int p01 = f2fh_pk(acc3[nt][0] + bv, acc3[nt][1] + bv);
        unsigned int p23 = f2fh_pk(acc3[nt][2] + bv, acc3[nt][3] + bv);
        S[(elb + 0) * SROWE + 128 + n] = (unsigned short)(p01 & 0xFFFF);
        S[(elb + 1) * SROWE + 128 + n] = (unsigned short)(p01 >> 16);
        S[(elb + 2) * SROWE + 128 + n] = (unsigned short)(p23 & 0xFFFF);
        S[(elb + 3) * SROWE + 128 + n] = (unsigned short)(p23 >> 16);
    }
    __syncthreads();   // barrier 2

    for (int t = tid; t < 64 * 32; t += 256) {
        int rr = t / 32, c = t % 32;
        int row = m0 + rr;
        if (row < M) {
            if (c < 16)
                *(uintx4*)(hB + (size_t)row * 128 + c * 8) =
                    *(const uintx4*)(&S[rr * SROWE + c * 8]);
            else
                *(uintx4*)(Pout + (size_t)row * 128 + (c - 16) * 8) =
                    *(const uintx4*)(&S[rr * SROWE + 128 + (c - 16) * 8]);
        }
    }
}

__global__ __launch_bounds__(256) void sort_k(
    const int2* __restrict__ binned, const int* __restrict__ bucketCursor,
    int2* __restrict__ eidx)
{
    __shared__ int2 st[CAP];
    __shared__ int cnt[256];
    __shared__ int cur[256];
    __shared__ int scanbuf[256];
    __shared__ int baseS[2];
    const int b = blockIdx.x;
    const int tid = threadIdx.x;

    // counts = final cursor values (clamped at CAP); local prefix for eidx base
    {
        int v = (tid < NBKT) ? min(bucketCursor[tid], CAP) : 0;
        int excl = block_excl_scan_256(v, scanbuf);
        if (tid == b) { baseS[0] = excl; baseS[1] = excl + v; }
    }
    __syncthreads();
    const int s0 = baseS[0];
    const int n = baseS[1] - s0;

    cnt[tid] = 0;
    __syncthreads();
    const int2* bsrc = binned + (size_t)b * CAP;
    for (int j = tid; j < n; j += 256) {
        int2 e = bsrc[j];
        st[j] = e;
        atomicAdd(&cnt[e.x & 255], 1);
    }
    __syncthreads();
    int excl = block_excl_scan_256(cnt[tid], scanbuf);
    cur[tid] = excl;
    __syncthreads();
    for (int j = tid; j < n; j += 256) {
        int2 e = st[j];
        int pos = atomicAdd(&cur[e.x & 255], 1);
        eidx[s0 + pos] = e;
    }
}

// ---------------------------------------------------------------------------
// Fused edge + block-segmented aggregate over sorted edges (R8 body, best
// measured 44.0 µs: f32 M2s [el][68], segStartS reduction, f16 P/eW2 +
// f16 MFMA, bias in accumulators).
// ---------------------------------------------------------------------------
__global__ __launch_bounds__(256) void edge_fused_k(
    const int2* __restrict__ eidx,
    const unsigned short* __restrict__ P,    // [N,128] f16: 0..63 top(+b1), 64..127 bot
    const unsigned short* __restrict__ Bp,   // eW2 frag order, f16
    const float* __restrict__ b2, float* __restrict__ agg, int E)
{
    __shared__ float M2s[64 * 68];
    __shared__ int ridS[64];
    __shared__ short segStartS[66];
    __shared__ int nsegS;
    const int tid = threadIdx.x;
    const int wave = tid >> 6;
    const int lane = tid & 63;
    const int lrow = lane & 15;
    const int quad = lane >> 4;
    const int e0 = blockIdx.x * 64;
    const int el = wave * 16 + lrow;
    const int e = e0 + el;

    // bias preloaded into the MFMA accumulators
    floatx4 acc[4];
    #pragma unroll
    for (int nt = 0; nt < 4; nt++) {
        float bv = b2[nt * 16 + lrow];
        acc[nt] = (floatx4){bv, bv, bv, bv};
    }

    half8v af0 = {};
    half8v af1 = {};
    if (e < E) {
        int2 rc = eidx[e];
        int rr = rc.x, cc = rc.y;
        if (quad == 0) ridS[el] = rr;
        const uintx4* pt = (const uintx4*)(P + (size_t)rr * 128 + quad * 8);
        const uintx4* pb = (const uintx4*)(P + (size_t)cc * 128 + 64 + quad * 8);
        uintx4 t0 = pt[0], t1 = pt[4];
        uintx4 b0 = pb[0], b1 = pb[4];
        uintx4 O0, O1;
        #pragma unroll
        for (int i = 0; i < 4; i++) {
            O0[i] = h2u(silu_h2(__hadd2(u2h(t0[i]), u2h(b0[i]))));
            O1[i] = h2u(silu_h2(__hadd2(u2h(t1[i]), u2h(b1[i]))));
        }
        af0 = __builtin_bit_cast(half8v, O0);
        af1 = __builtin_bit_cast(half8v, O1);
    } else if (quad == 0) {
        ridS[el] = -1;
    }

    #pragma unroll
    for (int nt = 0; nt < 4; nt++) {
        half8v bf0 = *(const half8v*)(Bp + (size_t)((0 * 4 + quad) * 64 + nt * 16 + lrow) * 8);
        acc[nt] = __builtin_amdgcn_mfma_f32_16x16x32_f16(af0, bf0, acc[nt], 0, 0, 0);
        half8v bf1 = *(const half8v*)(Bp + (size_t)((1 * 4 + quad) * 64 + nt * 16 + lrow) * 8);
        acc[nt] = __builtin_amdgcn_mfma_f32_16x16x32_f16(af1, bf1, acc[nt], 0, 0, 0);
    }

    #pragma unroll
    for (int nt = 0; nt < 4; nt++) {
        int n = nt * 16 + lrow;
        #pragma unroll
        for (int r = 0; r < 4; r++) {
            int el2 = wave * 16 + quad * 4 + r;
            M2s[el2 * 68 + n] = silu_f(acc[nt][r]);
        }
    }
    __syncthreads();

    if (tid < 64) {
        bool st = (ridS[tid] >= 0) && (tid == 0 || ridS[tid] != ridS[tid - 1]);
        unsigned long long m = __ballot(st);
        if (st) {
            int pos = __popcll(m & ((1ull << tid) - 1));
            segStartS[pos] = (short)tid;
        }
        if (tid == 0) {
            int ns = __popcll(m);
            nsegS = ns;
            int nvalid = E - e0;
            if (nvalid > 64) nvalid = 64;
            segStartS[ns] = (short)nvalid;
        }
    }
    __syncthreads();

    {
        int f = tid & 63;
        int g = tid >> 6;
        int ns = nsegS;
        for (int j = g; j < ns; j += 4) {
            int a = segStartS[j], b = segStartS[j + 1];
            float s = 0.0f;
            for (int el2 = a; el2 < b; el2++) s += M2s[el2 * 68 + f];
            int rv = ridS[a];
            if (j == 0 || j == ns - 1)
                atomicAdd(&agg[(size_t)rv * 64 + f], s);
            else
                agg[(size_t)rv * 64 + f] = s;
        }
    }
}

// ---------------------------------------------------------------------------
// Fused node-side chain (R8 body: residual from LDS bf16, no hFT).
// ---------------------------------------------------------------------------
#define SROW 264
template<int FINAL>
__global__ __launch_bounds__(512) void node_fused_k(
    const unsigned short* __restrict__ hbf, const float* __restrict__ agg,
    const unsigned short* __restrict__ W1, const float* __restrict__ b1,
    const unsigned short* __restrict__ W2, const float* __restrict__ b2,
    const unsigned short* __restrict__ B3, const float* __restrict__ bias3,
    unsigned short* __restrict__ hB, unsigned short* __restrict__ Pout,
    float* __restrict__ outF, float* __restrict__ aggZ, int M)
{
    __shared__ unsigned short S[64 * SROW];
    const int tid = threadIdx.x;
    const int m0 = blockIdx.x * 64;
    const int wave = tid >> 6;
    const int lane = tid & 63;
    const int lrow = lane & 15;
    const int quad = lane >> 4;
    const int g = wave >> 1;          // row group 0..3
    const int h = wave & 1;           // N half
    const int elb = g * 16 + quad * 4;

    // agg A-fragments straight into registers (kt=4,5 of the K=192 A-op)
    short8 afa0, afa1;
    {
        const float* ap = agg + (size_t)(m0 + g * 16 + lrow) * 64;
        floatx4 q0 = *(const floatx4*)(ap + quad * 8);
        floatx4 q1 = *(const floatx4*)(ap + quad * 8 + 4);
        floatx4 q2 = *(const floatx4*)(ap + 32 + quad * 8);
        floatx4 q3 = *(const floatx4*)(ap + 32 + quad * 8 + 4);
        unsigned int c0[4] = { f2bf_pk(q0[0], q0[1]), f2bf_pk(q0[2], q0[3]),
                               f2bf_pk(q1[0], q1[1]), f2bf_pk(q1[2], q1[3]) };
        unsigned int c1[4] = { f2bf_pk(q2[0], q2[1]), f2bf_pk(q2[2], q2[3]),
                               f2bf_pk(q3[0], q3[1]), f2bf_pk(q3[2], q3[3]) };
        afa0 = *(const short8*)c0;
        afa1 = *(const short8*)c1;
    }

    // staging: h (128 bf16) only -> S cols 0..127
    for (int t = tid; t < 64 * 16; t += 512) {
        int rr = t >> 4, c = t & 15;
        int row = m0 + rr;
        uintx4 val = {0, 0, 0, 0};
        if (row < M) val = *(const uintx4*)(hbf + (size_t)row * 128 + c * 8);
        *(uintx4*)(&S[rr * SROW + c * 8]) = val;
    }
    __syncthreads();   // B1

    // zero this block's agg rows for the next layer
    if (!FINAL) {
        floatx4 z = {0, 0, 0, 0};
        for (int t = tid; t < 64 * 16; t += 512) {
            int rr = t >> 4, c = t & 15;
            int row = m0 + rr;
            if (row < M) *(floatx4*)(aggZ + (size_t)row * 64 + c * 4) = z;
        }
    }

    const unsigned short* arow = &S[(g * 16 + lrow) * SROW];

    // ---- phase A MFMA: K=192 (kt 0..3 from LDS, kt 4..5 from registers) ----
    floatx4 acc[4];
    #pragma unroll
    for (int i = 0; i < 4; i++) acc[i] = (floatx4){0, 0, 0, 0};
    #pragma unroll
    for (int kt = 0; kt < 4; kt++) {
        short8 afrag = *(const short8*)(arow + kt * 32 + quad * 8);
        int kb = kt * 4 + quad;
        #pragma unroll
        for (int j = 0; j < 4; j++) {
            int n = (4 * h + j) * 16 + lrow;
            short8 bfrag = *(const short8*)(W1 + (size_t)(kb * 128 + n) * 8);
            acc[j] = __builtin_amdgcn_mfma_f32_16x16x32_bf16(afrag, bfrag, acc[j], 0, 0, 0);
        }
    }
    #pragma unroll
    for (int j = 0; j < 4; j++) {
        int n = (4 * h + j) * 16 + lrow;
        short8 b4 = *(const short8*)(W1 + (size_t)((16 + quad) * 128 + n) * 8);
        acc[j] = __builtin_amdgcn_mfma_f32_16x16x32_bf16(afa0, b4, acc[j], 0, 0, 0);
        short8 b5 = *(const short8*)(W1 + (size_t)((20 + quad) * 128 + n) * 8);
        acc[j] = __builtin_amdgcn_mfma_f32_16x16x32_bf16(afa1, b5, acc[j], 0, 0, 0);
    }

    // epilogue A: t -> S cols 128..255
    #pragma unroll
    for (int j = 0; j < 4; j++) {
        int n = (4 * h + j) * 16 + lrow;
        float bv = b1[n];
        unsigned int p01 = f2bf_pk(silu_f(acc[j][0] + bv), silu_f(acc[j][1] + bv));
        unsigned int p23 = f2bf_pk(silu_f(acc[j][2] + bv), silu_f(acc[j][3] + bv));
        S[(elb + 0) * SROW + 128 + n] = (unsigned short)(p01 & 0xFFFF);
        S[(elb + 1) * SROW + 128 + n] = (unsigned short)(p01 >> 16);
        S[(elb + 2) * SROW + 128 + n] = (unsigned short)(p23 & 0xFFFF);
        S[(elb + 3) * SROW + 128 + n] = (unsigned short)(p23 >> 16);
    }
    __syncthreads();   // B2: t complete

    // ---- phase B MFMA: K=128 over t (cols 128..255) ----
    floatx4 acc2[4];
    #pragma unroll
    for (int i = 0; i < 4; i++) acc2[i] = (floatx4){0, 0, 0, 0};
    #pragma unroll
    for (int kt = 0; kt < 4; kt++) {
        short8 afrag = *(const short8*)(arow + 128 + kt * 32 + quad * 8);
        int kb = kt * 4 + quad;
        #pragma unroll
        for (int j = 0; j < 4; j++) {
            int n = (4 * h + j) * 16 + lrow;
            short8 bfrag = *(const short8*)(W2 + (size_t)(kb * 128 + n) * 8);
            acc2[j] = __builtin_amdgcn_mfma_f32_16x16x32_bf16(afrag, bfrag, acc2[j], 0, 0, 0);
        }
    }

    // epilogue B: h_new = acc2 + b2 + res(LDS bf16, owner cells) -> S cols 0..127
    #pragma unroll
    for (int j = 0; j < 4; j++) {
        int n = (4 * h + j) * 16 + lrow;
        float bv = b2[n];
        floatx4 v4;
        #pragma unroll
        for (int r = 0; r < 4; r++) {
            float res = bf2f(S[(elb + r) * SROW + n]);
            v4[r] = acc2[j][r] + bv + res;
        }
        unsigned int p01 = f2bf_pk(v4[0], v4[1]);
        unsigned int p23 = f2bf_pk(v4[2], v4[3]);
        S[(elb + 0) * SROW + n] = (unsigned short)(p01 & 0xFFFF);
        S[(elb + 1) * SROW + n] = (unsigned short)(p01 >> 16);
        S[(elb + 2) * SROW + n] = (unsigned short)(p23 & 0xFFFF);
        S[(elb + 3) * SROW + n] = (unsigned short)(p23 >> 16);
    }
    __syncthreads();   // B3: h_new complete (all t reads done)

    // ---- phase C MFMA: K=128 -> P (128, f16) or out (64, f32) ----
    constexpr int NT3 = FINAL ? 2 : 4;
    constexpr int NO3 = FINAL ? 64 : 128;
    floatx4 acc3[NT3];
    #pragma unroll
    for (int i = 0; i < NT3; i++) acc3[i] = (floatx4){0, 0, 0, 0};
    #pragma unroll
    for (int kt = 0; kt < 4; kt++) {
        short8 afrag = *(const short8*)(arow + kt * 32 + quad * 8);
        int kb = kt * 4 + quad;
        #pragma unroll
        for (int j = 0; j < NT3; j++) {
            int n = (NT3 * h + j) * 16 + lrow;
            short8 bfrag = *(const short8*)(B3 + (size_t)(kb * NO3 + n) * 8);
            acc3[j] = __builtin_amdgcn_mfma_f32_16x16x32_bf16(afrag, bfrag, acc3[j], 0, 0, 0);
        }
    }
    // epilogue C -> S cols 128..255 (f16 P) or fp32 out region (same cols)
    #pragma unroll
    for (int j = 0; j < NT3; j++) {
        int n = (NT3 * h + j) * 16 + lrow;
        float bv = bias3[n];
        if (FINAL) {
            #pragma unroll
            for (int r = 0; r < 4; r++)
                ((float*)(&S[(elb + r) * SROW + 128]))[n] = acc3[j][r] + bv;
        } else {
            unsigned int p01 = f2fh_pk(acc3[j][0] + bv, acc3[j][1] + bv);
            unsigned int p23 = f2fh_pk(acc3[j][2] + bv, acc3[j][3] + bv);
            S[(elb + 0) * SROW + 128 + n] = (unsigned short)(p01 & 0xFFFF);
            S[(elb + 1) * SROW + 128 + n] = (unsigned short)(p01 >> 16);
            S[(elb + 2) * SROW + 128 + n] = (unsigned short)(p23 & 0xFFFF);
            S[(elb + 3) * SROW + 128 + n] = (unsigned short)(p23 >> 16);
        }
    }
    __syncthreads();   // B4

    // cooperative wide stores
    if (FINAL) {
        for (int t = tid; t < 64 * 16; t += 512) {
            int rr = t >> 4, c = t & 15;
            int row = m0 + rr;
            if (row < M)
                *(floatx4*)(outF + (size_t)row * 64 + c * 4) =
                    *(const floatx4*)((const float*)(&S[rr * SROW + 128]) + c * 4);
        }
    } else {
        for (int t = tid; t < 64 * 32; t += 512) {
            int rr = t >> 5, c = t & 31;
            int row = m0 + rr;
            if (row < M) {
                if (c < 16)
                    *(uintx4*)(hB + (size_t)row * 128 + c * 8) =
                        *(const uintx4*)(&S[rr * SROW + c * 8]);
                else
                    *(uintx4*)(Pout + (size_t)row * 128 + (c - 16) * 8) =
                        *(const uintx4*)(&S[rr * SROW + 128 + (c - 16) * 8]);
            }
        }
    }
}

// ---------------------------------------------------------------------------
extern "C" void kernel_launch(void* const* d_in, const int* in_sizes, int n_in,
                              void* d_out, int out_size, void* d_ws, size_t ws_size,
                              hipStream_t stream) {
    const float* h0   = (const float*)d_in[0];
    const int*   edges= (const int*)d_in[1];
    const float* W_in = (const float*)d_in[2];
    const float* b_in = (const float*)d_in[3];
    const float* eW1  = (const float*)d_in[4];
    const float* eb1  = (const float*)d_in[5];
    const float* eW2  = (const float*)d_in[6];
    const float* eb2  = (const float*)d_in[7];
    const float* nW1  = (const float*)d_in[8];
    const float* nb1  = (const float*)d_in[9];
    const float* nW2  = (const float*)d_in[10];
    const float* nb2  = (const float*)d_in[11];
    const float* W_out= (const float*)d_in[12];
    const float* b_out= (const float*)d_in[13];
    float* out = (float*)d_out;

    const int E = in_sizes[1] / 2;      // 800000
    const int* erow = edges;
    const int* ecol = edges + E;

    char* ws = (char*)d_ws;
    unsigned short* hbf  = (unsigned short*)(ws + 0);            // 12,800,000
    int2*           binned=(int2*)(ws + 12800000);               //  9,633,792 (196*CAP*8, fixed-capacity buckets)
    unsigned short* P    = (unsigned short*)(ws + 38424576);     // 12,800,000 (f16)
    float*          agg  = (float*)(ws + 51224576);              // 12,800,000
    int2*           eidx = (int2*)(ws + 76824576);               //  6,400,000
    float*          biasP= (float*)(ws + 83224576);              //  2,048
    unsigned short* Winp = (unsigned short*)(ws + 83226624);     // 16,384
    unsigned short* Woutp= (unsigned short*)(ws + 83243008);     // 16,384
    unsigned short* W1p  = (unsigned short*)(ws + 83259392);     // 131,072
    unsigned short* eW2p = (unsigned short*)(ws + 83390464);     // 32,768 (f16)
    unsigned short* nW1p = (unsigned short*)(ws + 83423232);     // 196,608
    unsigned short* nW2p = (unsigned short*)(ws + 83619840);     // 131,072
    int*            bucketCursor=(int*)(ws + 83752960);          // 784

    const int gemm_grid = (N_NODES + 63) / 64;    // 782
    const int edge_grid = (E + 63) / 64;          // 12500
    const int pack_grid = (int)((PACK_GRID_TOTAL + 255) / 256);
    const int bin_grid  = (E + BCHUNK - 1) / BCHUNK;   // 391

    // pack also zeroes bucketCursor (consumed by bin in the next dispatch)
    pack_kernel<<<pack_grid, 256, 0, stream>>>(W_in, W_out, eW1, eb1, eW2,
                                               nW1, nW2, Winp, Woutp, W1p,
                                               eW2p, nW1p, nW2p, biasP,
                                               bucketCursor);

    // merged: binning scatter (blocks 0..390, fixed-capacity buckets) +
    // fused embedding (rest). hist_k eliminated.
    bin_embed_k<<<bin_grid + gemm_grid, 256, 0, stream>>>(
        erow, ecol, bucketCursor, binned, E, bin_grid,
        h0, Winp, b_in, W1p, biasP, hbf, P, agg, N_NODES);

    sort_k<<<NBKT, 256, 0, stream>>>(binned, bucketCursor, eidx);

    for (int l = 0; l < 4; l++) {
        edge_fused_k<<<edge_grid, 256, 0, stream>>>(
            eidx, P, eW2p + (size_t)l * SE2, eb2 + (size_t)l * 64, agg, E);
        if (l < 3) {
            node_fused_k<0><<<gemm_grid, 512, 0, stream>>>(
                hbf, agg, nW1p + (size_t)l * SN1, nb1 + (size_t)l * 128,
                nW2p + (size_t)l * SN2, nb2 + (size_t)l * 128,
                W1p + (size_t)(l + 1) * SW1, biasP + (size_t)(l + 1) * 128,
                hbf, P, nullptr, agg, N_NODES);
        } else {
            node_fused_k<1><<<gemm_grid, 512, 0, stream>>>(
                hbf, agg, nW1p + (size_t)l * SN1, nb1 + (size_t)l * 128,
                nW2p + (size_t)l * SN2, nb2 + (size_t)l * 128,
                Woutp, b_out, nullptr, nullptr, out, nullptr, N_NODES);
        }
    }
}

// Round 12
// 381.597 us; speedup vs baseline: 1.0832x; 1.0091x over previous
//
#include <hip/hip_runtime.h>
#include <hip/hip_bf16.h>
#include <hip/hip_fp16.h>
#include <cstdint>
#include <cstddef>

#define N_NODES 50000
#define N_EDGES 800000
#define NBKT    196      // ceil(50000/256) buckets of 256 rows
#define BSH     8        // rows-per-bucket shift
#define BCHUNK  2048     // edges per bin_k block
#define CAP     6144     // fixed bucket capacity (mean 4082, max ~4400)

typedef __attribute__((ext_vector_type(8))) short short8;
typedef __attribute__((ext_vector_type(4))) float floatx4;
typedef __attribute__((ext_vector_type(2))) float floatx2;
typedef __attribute__((ext_vector_type(4))) unsigned int uintx4;
typedef __attribute__((ext_vector_type(2))) unsigned int uintx2;
typedef __attribute__((ext_vector_type(8))) _Float16 half8v;

__device__ inline float bf2f(unsigned short u) {
    union { unsigned int i; float f; } v; v.i = ((unsigned int)u) << 16; return v.f;
}
__device__ inline unsigned short f2bf(float f) {
    union { float f; unsigned int i; } v; v.f = f;
    unsigned int u = v.i;
    return (unsigned short)((u + 0x7FFFu + ((u >> 16) & 1u)) >> 16);
}
// packed RNE f32x2 -> bf16x2 (v_cvt_pk_bf16_f32 on gfx950)
__device__ inline unsigned int f2bf_pk(float a, float b) {
    __hip_bfloat162 h2 = __float22bfloat162_rn(make_float2(a, b));
    return *reinterpret_cast<unsigned int*>(&h2);
}
// f16 helpers (edge path is f16: packed ALU + mfma_f32_16x16x32_f16)
__device__ inline unsigned short f2fh(float f) {
    _Float16 h = (_Float16)f;
    return __builtin_bit_cast(unsigned short, h);
}
// packed f32x2 -> f16x2 via v_cvt_pkrtz_f16_f32 (1 instr)
// NOTE: builtin returns __fp16 ext_vector_type(2) on this clang — bit_cast it.
__device__ inline unsigned int f2fh_pk(float a, float b) {
    typedef __attribute__((ext_vector_type(2))) __fp16 h2v;
    h2v r = __builtin_amdgcn_cvt_pkrtz(a, b);
    return __builtin_bit_cast(unsigned int, r);
}
__device__ inline __half2 u2h(unsigned int u) { return __builtin_bit_cast(__half2, u); }
__device__ inline unsigned int h2u(__half2 h) { return __builtin_bit_cast(unsigned int, h); }
// f16 SiLU on a packed pair.
__device__ inline __half2 silu_h2(__half2 x) {
    const __half2 nlog2e = __float2half2_rn(-1.4426950408889634f);
    const __half2 one    = __float2half2_rn(1.0f);
    __half2 e = h2exp2(__hmul2(x, nlog2e));
    return __hmul2(x, h2rcp(__hadd2(e, one)));
}
// silu via v_rcp_f32 (1 ulp) instead of IEEE divide
__device__ inline float silu_f(float x) {
    float e = __expf(-x);
    return x * __builtin_amdgcn_rcpf(1.0f + e);
}

__device__ inline int block_excl_scan_256(int v, int* buf) {
    int tid = threadIdx.x;
    buf[tid] = v;
    __syncthreads();
    #pragma unroll
    for (int off = 1; off < 256; off <<= 1) {
        int t = (tid >= off) ? buf[tid - off] : 0;
        __syncthreads();
        buf[tid] += t;
        __syncthreads();
    }
    return buf[tid] - v;
}

// ---------------------------------------------------------------------------
// Pack kernel: fp32->bf16/f16 weight rearrangement into MFMA fragment order.
// Tail zeroes bucketCursor (consumed by bin in the next dispatch).
// B-fragment order: Bp[(kb*NOUT + n)*8 + i] = B[(kb*8+i)*NOUT + n]
// ---------------------------------------------------------------------------
__device__ inline void pack_std(const float* __restrict__ src,
                                unsigned short* __restrict__ dst,
                                int NOUT, long j) {
    int i = (int)(j & 7);
    long rest = j >> 3;
    int n = (int)(rest % NOUT);
    int kb = (int)(rest / NOUT);
    dst[j] = f2bf(src[(long)(kb * 8 + i) * NOUT + n]);
}
__device__ inline void pack_std_h(const float* __restrict__ src,
                                  unsigned short* __restrict__ dst,
                                  int NOUT, long j) {
    int i = (int)(j & 7);
    long rest = j >> 3;
    int n = (int)(rest % NOUT);
    int kb = (int)(rest / NOUT);
    dst[j] = f2fh(src[(long)(kb * 8 + i) * NOUT + n]);
}

#define SW_IN 8192L
#define SW_OUT 8192L
#define SW1   16384L
#define SE2   4096L
#define SN1   24576L
#define SN2   16384L
#define SB    128L
#define PERL  (SW1 + SE2 + SN1 + SN2 + SB)
#define PACK_TOTAL (SW_IN + SW_OUT + 4 * PERL)
#define PACK_GRID_TOTAL (PACK_TOTAL + NBKT)

__global__ __launch_bounds__(256) void pack_kernel(
    const float* __restrict__ W_in,
    const float* __restrict__ W_out, const float* __restrict__ eW1,
    const float* __restrict__ eb1, const float* __restrict__ eW2,
    const float* __restrict__ nW1, const float* __restrict__ nW2,
    unsigned short* __restrict__ Winp,
    unsigned short* __restrict__ Woutp, unsigned short* __restrict__ W1p,
    unsigned short* __restrict__ eW2p, unsigned short* __restrict__ nW1p,
    unsigned short* __restrict__ nW2p, float* __restrict__ biasP,
    int* __restrict__ bucketCursor)
{
    long idx = (long)blockIdx.x * 256 + threadIdx.x;
    if (idx >= PACK_TOTAL) {
        long t = idx - PACK_TOTAL;
        if (t < NBKT) bucketCursor[t] = 0;
        return;
    }
    long j = idx;
    if (j < SW_IN) { pack_std(W_in, Winp, 128, j); return; }
    j -= SW_IN;
    if (j < SW_OUT) { pack_std(W_out, Woutp, 64, j); return; }
    j -= SW_OUT;
    int l = (int)(j / PERL);
    long r = j % PERL;
    if (r < SW1) {
        int i = (int)(r & 7);
        int n = (int)((r >> 3) & 127);
        int kb = (int)(r >> 10);
        int k = kb * 8 + i;
        const float* w = eW1 + (long)l * 256 * 64;
        float v = (n < 64) ? w[(long)k * 64 + n] : w[(long)(128 + k) * 64 + (n - 64)];
        W1p[(long)l * SW1 + r] = f2bf(v);
        return;
    }
    r -= SW1;
    if (r < SE2) { pack_std_h(eW2 + (long)l * 4096, eW2p + (long)l * SE2, 64, r); return; }
    r -= SE2;
    if (r < SN1) { pack_std(nW1 + (long)l * 24576, nW1p + (long)l * SN1, 128, r); return; }
    r -= SN1;
    if (r < SN2) { pack_std(nW2 + (long)l * 16384, nW2p + (long)l * SN2, 128, r); return; }
    r -= SN2;
    biasP[(long)l * 128 + r] = (r < 64) ? eb1[(long)l * 64 + r] : 0.0f;
}

// ---------------------------------------------------------------------------
// binned: fixed-capacity bucket regions (bucket b at binned[b*CAP..)); bin
// blocks reserve in-bucket slots via bucketCursor atomics.
// ---------------------------------------------------------------------------
#define SROWE 264
#define BE_SMEM_BYTES (64 * SROWE * 2)   // embed branch need (33792 B) >= bin need

// Merged [bin | embed] dispatch: blocks < binGrid run the binning scatter;
// the rest run the fused embedding GEMM. Independent data paths.
__global__ __launch_bounds__(256) void bin_embed_k(
    const int* __restrict__ erow, const int* __restrict__ ecol,
    int* __restrict__ bucketCursor,
    int2* __restrict__ binned, int E, int binGrid,
    const float* __restrict__ h0, const unsigned short* __restrict__ Win,
    const float* __restrict__ b_in, const unsigned short* __restrict__ W1,
    const float* __restrict__ biasP,
    unsigned short* __restrict__ hB, unsigned short* __restrict__ Pout,
    float* __restrict__ aggZ, int M)
{
    __shared__ char SMEM[BE_SMEM_BYTES];
    const int tid = threadIdx.x;

    if (blockIdx.x < binGrid) {
        // ---------------- bin branch ----------------
        int* cnt      = (int*)SMEM;              // NBKT
        int* binStart = cnt + NBKT;              // NBKT
        int* gbase    = binStart + NBKT;         // NBKT (in-bucket base)
        int* scanbuf  = gbase + NBKT;            // 256
        int2* staged  = (int2*)(scanbuf + 256);  // BCHUNK

        const int base = blockIdx.x * BCHUNK;
        const int nloc = min(BCHUNK, E - base);

        for (int i = tid; i < NBKT; i += 256) cnt[i] = 0;
        __syncthreads();

        int2 ed[BCHUNK / 256];
        int  bo[BCHUNK / 256];
        #pragma unroll
        for (int i = 0; i < BCHUNK / 256; i++) {
            int jl = i * 256 + tid;
            if (jl < nloc) {
                int j = base + jl;
                int r = erow[j], c = ecol[j];
                ed[i] = make_int2(r, c);
                int b = r >> BSH;
                int off = atomicAdd(&cnt[b], 1);
                bo[i] = (b << 12) | off;
            } else bo[i] = -1;
        }
        __syncthreads();

        int v = (tid < NBKT) ? cnt[tid] : 0;
        int excl = block_excl_scan_256(v, scanbuf);
        if (tid < NBKT) binStart[tid] = excl;
        if (tid < NBKT && v > 0)
            gbase[tid] = atomicAdd(&bucketCursor[tid], v);
        __syncthreads();

        #pragma unroll
        for (int i = 0; i < BCHUNK / 256; i++) {
            if (bo[i] >= 0)
                staged[binStart[bo[i] >> 12] + (bo[i] & 0xFFF)] = ed[i];
        }
        __syncthreads();

        for (int j = tid; j < nloc; j += 256) {
            int2 e = staged[j];
            int b = e.x >> BSH;
            int off = gbase[b] + (j - binStart[b]);
            if (off < CAP)
                binned[(size_t)b * CAP + off] = e;
        }
        return;
    }

    // ---------------- embed branch ----------------
    unsigned short* S = (unsigned short*)SMEM;
    const int m0 = (blockIdx.x - binGrid) * 64;
    const int wave = tid >> 6;
    const int lane = tid & 63;
    const int lrow = lane & 15;
    const int quad = lane >> 4;
    const int elb = wave * 16 + quad * 4;

    // staging: h0 f32 -> bf16 into S cols 0..63
    for (int t = tid; t < 64 * 16; t += 256) {
        int rr = t >> 4, c = t & 15;
        int row = m0 + rr;
        floatx4 v = {0, 0, 0, 0};
        if (row < M) v = *(const floatx4*)(h0 + (size_t)row * 64 + c * 4);
        uintx2 u = { f2bf_pk(v[0], v[1]), f2bf_pk(v[2], v[3]) };
        *(uintx2*)(&S[rr * SROWE + c * 4]) = u;
    }
    __syncthreads();   // barrier 1

    // zero this block's agg rows for layer 0 (full zero — zmask not built yet)
    {
        floatx4 z = {0, 0, 0, 0};
        for (int t = tid; t < 64 * 16; t += 256) {
            int rr = t >> 4, c = t & 15;
            int row = m0 + rr;
            if (row < M) *(floatx4*)(aggZ + (size_t)row * 64 + c * 4) = z;
        }
    }

    const unsigned short* arow = &S[(wave * 16 + lrow) * SROWE];

    floatx4 acc[8];
    #pragma unroll
    for (int i = 0; i < 8; i++) acc[i] = (floatx4){0, 0, 0, 0};
    #pragma unroll
    for (int kt = 0; kt < 2; kt++) {
        short8 afrag = *(const short8*)(arow + kt * 32 + quad * 8);
        int kb = kt * 4 + quad;
        #pragma unroll
        for (int nt = 0; nt < 8; nt++) {
            short8 bfrag = *(const short8*)(Win + (size_t)(kb * 128 + nt * 16 + lrow) * 8);
            acc[nt] = __builtin_amdgcn_mfma_f32_16x16x32_bf16(afrag, bfrag, acc[nt], 0, 0, 0);
        }
    }

    // epilogue: h1 -> S cols 0..127 (bf16)
    #pragma unroll
    for (int nt = 0; nt < 8; nt++) {
        int n = nt * 16 + lrow;
        float bv = b_in[n];
        floatx4 v4;
        #pragma unroll
        for (int r = 0; r < 4; r++) v4[r] = acc[nt][r] + bv;
        unsigned int p01 = f2bf_pk(v4[0], v4[1]);
        unsigned int p23 = f2bf_pk(v4[2], v4[3]);
        S[(elb + 0) * SROWE + n] = (unsigned short)(p01 & 0xFFFF);
        S[(elb + 1) * SROWE + n] = (unsigned short)(p01 >> 16);
        S[(elb + 2) * SROWE + n] = (unsigned short)(p23 & 0xFFFF);
        S[(elb + 3) * SROWE + n] = (unsigned short)(p23 >> 16);
    }

    floatx4 acc3[8];
    #pragma unroll
    for (int i = 0; i < 8; i++) acc3[i] = (floatx4){0, 0, 0, 0};
    #pragma unroll
    for (int kt = 0; kt < 4; kt++) {
        short8 afrag = *(const short8*)(arow + kt * 32 + quad * 8);
        int kb = kt * 4 + quad;
        #pragma unroll
        for (int nt = 0; nt < 8; nt++) {
            short8 bfrag = *(const short8*)(W1 + (size_t)(kb * 128 + nt * 16 + lrow) * 8);
            acc3[nt] = __builtin_amdgcn_mfma_f32_16x16x32_bf16(afrag, bfrag, acc3[nt], 0, 0, 0);
        }
    }
    #pragma unroll
    for (int nt = 0; nt < 8; nt++) {
        int n = nt * 16 + lrow;
        float bv = biasP[n];
        unsigned int p01 = f2fh_pk(acc3[nt][0] + bv, acc3[nt][1] + bv);
        unsigned int p23 = f2fh_pk(acc3[nt][2] + bv, acc3[nt][3] + bv);
        S[(elb + 0) * SROWE + 128 + n] = (unsigned short)(p01 & 0xFFFF);
        S[(elb + 1) * SROWE + 128 + n] = (unsigned short)(p01 >> 16);
        S[(elb + 2) * SROWE + 128 + n] = (unsigned short)(p23 & 0xFFFF);
        S[(elb + 3) * SROWE + 128 + n] = (unsigned short)(p23 >> 16);
    }
    __syncthreads();   // barrier 2

    for (int t = tid; t < 64 * 32; t += 256) {
        int rr = t / 32, c = t % 32;
        int row = m0 + rr;
        if (row < M) {
            if (c < 16)
                *(uintx4*)(hB + (size_t)row * 128 + c * 8) =
                    *(const uintx4*)(&S[rr * SROWE + c * 8]);
            else
                *(uintx4*)(Pout + (size_t)row * 128 + (c - 16) * 8) =
                    *(const uintx4*)(&S[rr * SROWE + 128 + (c - 16) * 8]);
        }
    }
}

// ---------------------------------------------------------------------------
// sort_k — also builds the static needs-zero row mask. Row r needs pre-zeroing
// (atomicAdd target in edge_fused) iff it has no edges, OR its eidx range
// covers an index ≡0 or ≡63 (mod 64). Unflagged rows are fully overwritten by
// a single interior-segment plain store.
// ---------------------------------------------------------------------------
__global__ __launch_bounds__(256) void sort_k(
    const int2* __restrict__ binned, const int* __restrict__ bucketCursor,
    int2* __restrict__ eidx, unsigned long long* __restrict__ zmask)
{
    __shared__ int2 st[CAP];
    __shared__ int cnt[256];
    __shared__ int cur[256];
    __shared__ int scanbuf[256];
    __shared__ int baseS[2];
    const int b = blockIdx.x;
    const int tid = threadIdx.x;

    // counts = final cursor values (clamped at CAP); local prefix for eidx base
    {
        int v = (tid < NBKT) ? min(bucketCursor[tid], CAP) : 0;
        int excl = block_excl_scan_256(v, scanbuf);
        if (tid == b) { baseS[0] = excl; baseS[1] = excl + v; }
    }
    __syncthreads();
    const int s0 = baseS[0];
    const int n = baseS[1] - s0;

    cnt[tid] = 0;
    __syncthreads();
    const int2* bsrc = binned + (size_t)b * CAP;
    for (int j = tid; j < n; j += 256) {
        int2 e = bsrc[j];
        st[j] = e;
        atomicAdd(&cnt[e.x & 255], 1);
    }
    __syncthreads();
    int myCnt = cnt[tid];
    int excl = block_excl_scan_256(myCnt, scanbuf);
    cur[tid] = excl;
    const int myLo = s0 + excl;          // global eidx start of this row
    __syncthreads();
    for (int j = tid; j < n; j += 256) {
        int2 e = st[j];
        int pos = atomicAdd(&cur[e.x & 255], 1);
        eidx[s0 + pos] = e;
    }

    // needs-zero mask: one u64 per 64 rows, via per-wave ballot
    {
        bool nz;
        if (myCnt == 0) nz = true;
        else {
            int lo = myLo, hi = myLo + myCnt;
            int A = lo >> 6, Bk = (hi - 1) >> 6;
            nz = (Bk > A) || ((lo & 63) == 0) || (((hi - 1) & 63) == 63);
        }
        unsigned long long m = __ballot(nz);
        if ((tid & 63) == 0)
            zmask[(((size_t)b << 8) + tid) >> 6] = m;
    }
}

// ---------------------------------------------------------------------------
// Fused edge + block-segmented aggregate over sorted edges (R8 body, best
// measured 44.0 µs: f32 M2s [el][68], segStartS reduction, f16 P/eW2 +
// f16 MFMA, bias in accumulators).
// ---------------------------------------------------------------------------
__global__ __launch_bounds__(256) void edge_fused_k(
    const int2* __restrict__ eidx,
    const unsigned short* __restrict__ P,    // [N,128] f16: 0..63 top(+b1), 64..127 bot
    const unsigned short* __restrict__ Bp,   // eW2 frag order, f16
    const float* __restrict__ b2, float* __restrict__ agg, int E)
{
    __shared__ float M2s[64 * 68];
    __shared__ int ridS[64];
    __shared__ short segStartS[66];
    __shared__ int nsegS;
    const int tid = threadIdx.x;
    const int wave = tid >> 6;
    const int lane = tid & 63;
    const int lrow = lane & 15;
    const int quad = lane >> 4;
    const int e0 = blockIdx.x * 64;
    const int el = wave * 16 + lrow;
    const int e = e0 + el;

    // bias preloaded into the MFMA accumulators
    floatx4 acc[4];
    #pragma unroll
    for (int nt = 0; nt < 4; nt++) {
        float bv = b2[nt * 16 + lrow];
        acc[nt] = (floatx4){bv, bv, bv, bv};
    }

    half8v af0 = {};
    half8v af1 = {};
    if (e < E) {
        int2 rc = eidx[e];
        int rr = rc.x, cc = rc.y;
        if (quad == 0) ridS[el] = rr;
        const uintx4* pt = (const uintx4*)(P + (size_t)rr * 128 + quad * 8);
        const uintx4* pb = (const uintx4*)(P + (size_t)cc * 128 + 64 + quad * 8);
        uintx4 t0 = pt[0], t1 = pt[4];
        uintx4 b0 = pb[0], b1 = pb[4];
        uintx4 O0, O1;
        #pragma unroll
        for (int i = 0; i < 4; i++) {
            O0[i] = h2u(silu_h2(__hadd2(u2h(t0[i]), u2h(b0[i]))));
            O1[i] = h2u(silu_h2(__hadd2(u2h(t1[i]), u2h(b1[i]))));
        }
        af0 = __builtin_bit_cast(half8v, O0);
        af1 = __builtin_bit_cast(half8v, O1);
    } else if (quad == 0) {
        ridS[el] = -1;
    }

    #pragma unroll
    for (int nt = 0; nt < 4; nt++) {
        half8v bf0 = *(const half8v*)(Bp + (size_t)((0 * 4 + quad) * 64 + nt * 16 + lrow) * 8);
        acc[nt] = __builtin_amdgcn_mfma_f32_16x16x32_f16(af0, bf0, acc[nt], 0, 0, 0);
        half8v bf1 = *(const half8v*)(Bp + (size_t)((1 * 4 + quad) * 64 + nt * 16 + lrow) * 8);
        acc[nt] = __builtin_amdgcn_mfma_f32_16x16x32_f16(af1, bf1, acc[nt], 0, 0, 0);
    }

    #pragma unroll
    for (int nt = 0; nt < 4; nt++) {
        int n = nt * 16 + lrow;
        #pragma unroll
        for (int r = 0; r < 4; r++) {
            int el2 = wave * 16 + quad * 4 + r;
            M2s[el2 * 68 + n] = silu_f(acc[nt][r]);
        }
    }
    __syncthreads();

    if (tid < 64) {
        bool st = (ridS[tid] >= 0) && (tid == 0 || ridS[tid] != ridS[tid - 1]);
        unsigned long long m = __ballot(st);
        if (st) {
            int pos = __popcll(m & ((1ull << tid) - 1));
            segStartS[pos] = (short)tid;
        }
        if (tid == 0) {
            int ns = __popcll(m);
            nsegS = ns;
            int nvalid = E - e0;
            if (nvalid > 64) nvalid = 64;
            segStartS[ns] = (short)nvalid;
        }
    }
    __syncthreads();

    {
        int f = tid & 63;
        int g = tid >> 6;
        int ns = nsegS;
        for (int j = g; j < ns; j += 4) {
            int a = segStartS[j], b = segStartS[j + 1];
            float s = 0.0f;
            for (int el2 = a; el2 < b; el2++) s += M2s[el2 * 68 + f];
            int rv = ridS[a];
            if (j == 0 || j == ns - 1)
                atomicAdd(&agg[(size_t)rv * 64 + f], s);
            else
                agg[(size_t)rv * 64 + f] = s;
        }
    }
}

// ---------------------------------------------------------------------------
// Fused node-side chain (R8 body; masked agg zero — only rows flagged in
// zmask (atomicAdd targets / absent rows) are pre-zeroed).
// ---------------------------------------------------------------------------
#define SROW 264
template<int FINAL>
__global__ __launch_bounds__(512) void node_fused_k(
    const unsigned short* __restrict__ hbf, const float* __restrict__ agg,
    const unsigned short* __restrict__ W1, const float* __restrict__ b1,
    const unsigned short* __restrict__ W2, const float* __restrict__ b2,
    const unsigned short* __restrict__ B3, const float* __restrict__ bias3,
    unsigned short* __restrict__ hB, unsigned short* __restrict__ Pout,
    float* __restrict__ outF, float* __restrict__ aggZ,
    const unsigned long long* __restrict__ zmask, int M)
{
    __shared__ unsigned short S[64 * SROW];
    const int tid = threadIdx.x;
    const int m0 = blockIdx.x * 64;
    const int wave = tid >> 6;
    const int lane = tid & 63;
    const int lrow = lane & 15;
    const int quad = lane >> 4;
    const int g = wave >> 1;          // row group 0..3
    const int h = wave & 1;           // N half
    const int elb = g * 16 + quad * 4;

    // agg A-fragments straight into registers (kt=4,5 of the K=192 A-op)
    short8 afa0, afa1;
    {
        const float* ap = agg + (size_t)(m0 + g * 16 + lrow) * 64;
        floatx4 q0 = *(const floatx4*)(ap + quad * 8);
        floatx4 q1 = *(const floatx4*)(ap + quad * 8 + 4);
        floatx4 q2 = *(const floatx4*)(ap + 32 + quad * 8);
        floatx4 q3 = *(const floatx4*)(ap + 32 + quad * 8 + 4);
        unsigned int c0[4] = { f2bf_pk(q0[0], q0[1]), f2bf_pk(q0[2], q0[3]),
                               f2bf_pk(q1[0], q1[1]), f2bf_pk(q1[2], q1[3]) };
        unsigned int c1[4] = { f2bf_pk(q2[0], q2[1]), f2bf_pk(q2[2], q2[3]),
                               f2bf_pk(q3[0], q3[1]), f2bf_pk(q3[2], q3[3]) };
        afa0 = *(const short8*)c0;
        afa1 = *(const short8*)c1;
    }

    // staging: h (128 bf16) only -> S cols 0..127
    for (int t = tid; t < 64 * 16; t += 512) {
        int rr = t >> 4, c = t & 15;
        int row = m0 + rr;
        uintx4 val = {0, 0, 0, 0};
        if (row < M) val = *(const uintx4*)(hbf + (size_t)row * 128 + c * 8);
        *(uintx4*)(&S[rr * SROW + c * 8]) = val;
    }
    __syncthreads();   // B1

    // masked zero of this block's agg rows for the next layer
    if (!FINAL) {
        unsigned long long zm = zmask[m0 >> 6];
        floatx4 z = {0, 0, 0, 0};
        for (int t = tid; t < 64 * 16; t += 512) {
            int rr = t >> 4, c = t & 15;
            int row = m0 + rr;
            if (row < M && ((zm >> rr) & 1ull))
                *(floatx4*)(aggZ + (size_t)row * 64 + c * 4) = z;
        }
    }

    const unsigned short* arow = &S[(g * 16 + lrow) * SROW];

    // ---- phase A MFMA: K=192 (kt 0..3 from LDS, kt 4..5 from registers) ----
    floatx4 acc[4];
    #pragma unroll
    for (int i = 0; i < 4; i++) acc[i] = (floatx4){0, 0, 0, 0};
    #pragma unroll
    for (int kt = 0; kt < 4; kt++) {
        short8 afrag = *(const short8*)(arow + kt * 32 + quad * 8);
        int kb = kt * 4 + quad;
        #pragma unroll
        for (int j = 0; j < 4; j++) {
            int n = (4 * h + j) * 16 + lrow;
            short8 bfrag = *(const short8*)(W1 + (size_t)(kb * 128 + n) * 8);
            acc[j] = __builtin_amdgcn_mfma_f32_16x16x32_bf16(afrag, bfrag, acc[j], 0, 0, 0);
        }
    }
    #pragma unroll
    for (int j = 0; j < 4; j++) {
        int n = (4 * h + j) * 16 + lrow;
        short8 b4 = *(const short8*)(W1 + (size_t)((16 + quad) * 128 + n) * 8);
        acc[j] = __builtin_amdgcn_mfma_f32_16x16x32_bf16(afa0, b4, acc[j], 0, 0, 0);
        short8 b5 = *(const short8*)(W1 + (size_t)((20 + quad) * 128 + n) * 8);
        acc[j] = __builtin_amdgcn_mfma_f32_16x16x32_bf16(afa1, b5, acc[j], 0, 0, 0);
    }

    // epilogue A: t -> S cols 128..255
    #pragma unroll
    for (int j = 0; j < 4; j++) {
        int n = (4 * h + j) * 16 + lrow;
        float bv = b1[n];
        unsigned int p01 = f2bf_pk(silu_f(acc[j][0] + bv), silu_f(acc[j][1] + bv));
        unsigned int p23 = f2bf_pk(silu_f(acc[j][2] + bv), silu_f(acc[j][3] + bv));
        S[(elb + 0) * SROW + 128 + n] = (unsigned short)(p01 & 0xFFFF);
        S[(elb + 1) * SROW + 128 + n] = (unsigned short)(p01 >> 16);
        S[(elb + 2) * SROW + 128 + n] = (unsigned short)(p23 & 0xFFFF);
        S[(elb + 3) * SROW + 128 + n] = (unsigned short)(p23 >> 16);
    }
    __syncthreads();   // B2: t complete

    // ---- phase B MFMA: K=128 over t (cols 128..255) ----
    floatx4 acc2[4];
    #pragma unroll
    for (int i = 0; i < 4; i++) acc2[i] = (floatx4){0, 0, 0, 0};
    #pragma unroll
    for (int kt = 0; kt < 4; kt++) {
        short8 afrag = *(const short8*)(arow + 128 + kt * 32 + quad * 8);
        int kb = kt * 4 + quad;
        #pragma unroll
        for (int j = 0; j < 4; j++) {
            int n = (4 * h + j) * 16 + lrow;
            short8 bfrag = *(const short8*)(W2 + (size_t)(kb * 128 + n) * 8);
            acc2[j] = __builtin_amdgcn_mfma_f32_16x16x32_bf16(afrag, bfrag, acc2[j], 0, 0, 0);
        }
    }

    // epilogue B: h_new = acc2 + b2 + res(LDS bf16, owner cells) -> S cols 0..127
    #pragma unroll
    for (int j = 0; j < 4; j++) {
        int n = (4 * h + j) * 16 + lrow;
        float bv = b2[n];
        floatx4 v4;
        #pragma unroll
        for (int r = 0; r < 4; r++) {
            float res = bf2f(S[(elb + r) * SROW + n]);
            v4[r] = acc2[j][r] + bv + res;
        }
        unsigned int p01 = f2bf_pk(v4[0], v4[1]);
        unsigned int p23 = f2bf_pk(v4[2], v4[3]);
        S[(elb + 0) * SROW + n] = (unsigned short)(p01 & 0xFFFF);
        S[(elb + 1) * SROW + n] = (unsigned short)(p01 >> 16);
        S[(elb + 2) * SROW + n] = (unsigned short)(p23 & 0xFFFF);
        S[(elb + 3) * SROW + n] = (unsigned short)(p23 >> 16);
    }
    __syncthreads();   // B3: h_new complete (all t reads done)

    // ---- phase C MFMA: K=128 -> P (128, f16) or out (64, f32) ----
    constexpr int NT3 = FINAL ? 2 : 4;
    constexpr int NO3 = FINAL ? 64 : 128;
    floatx4 acc3[NT3];
    #pragma unroll
    for (int i = 0; i < NT3; i++) acc3[i] = (floatx4){0, 0, 0, 0};
    #pragma unroll
    for (int kt = 0; kt < 4; kt++) {
        short8 afrag = *(const short8*)(arow + kt * 32 + quad * 8);
        int kb = kt * 4 + quad;
        #pragma unroll
        for (int j = 0; j < NT3; j++) {
            int n = (NT3 * h + j) * 16 + lrow;
            short8 bfrag = *(const short8*)(B3 + (size_t)(kb * NO3 + n) * 8);
            acc3[j] = __builtin_amdgcn_mfma_f32_16x16x32_bf16(afrag, bfrag, acc3[j], 0, 0, 0);
        }
    }
    // epilogue C -> S cols 128..255 (f16 P) or fp32 out region (same cols)
    #pragma unroll
    for (int j = 0; j < NT3; j++) {
        int n = (NT3 * h + j) * 16 + lrow;
        float bv = bias3[n];
        if (FINAL) {
            #pragma unroll
            for (int r = 0; r < 4; r++)
                ((float*)(&S[(elb + r) * SROW + 128]))[n] = acc3[j][r] + bv;
        } else {
            unsigned int p01 = f2fh_pk(acc3[j][0] + bv, acc3[j][1] + bv);
            unsigned int p23 = f2fh_pk(acc3[j][2] + bv, acc3[j][3] + bv);
            S[(elb + 0) * SROW + 128 + n] = (unsigned short)(p01 & 0xFFFF);
            S[(elb + 1) * SROW + 128 + n] = (unsigned short)(p01 >> 16);
            S[(elb + 2) * SROW + 128 + n] = (unsigned short)(p23 & 0xFFFF);
            S[(elb + 3) * SROW + 128 + n] = (unsigned short)(p23 >> 16);
        }
    }
    __syncthreads();   // B4

    // cooperative wide stores
    if (FINAL) {
        for (int t = tid; t < 64 * 16; t += 512) {
            int rr = t >> 4, c = t & 15;
            int row = m0 + rr;
            if (row < M)
                *(floatx4*)(outF + (size_t)row * 64 + c * 4) =
                    *(const floatx4*)((const float*)(&S[rr * SROW + 128]) + c * 4);
        }
    } else {
        for (int t = tid; t < 64 * 32; t += 512) {
            int rr = t >> 5, c = t & 31;
            int row = m0 + rr;
            if (row < M) {
                if (c < 16)
                    *(uintx4*)(hB + (size_t)row * 128 + c * 8) =
                        *(const uintx4*)(&S[rr * SROW + c * 8]);
                else
                    *(uintx4*)(Pout + (size_t)row * 128 + (c - 16) * 8) =
                        *(const uintx4*)(&S[rr * SROW + 128 + (c - 16) * 8]);
            }
        }
    }
}

// ---------------------------------------------------------------------------
extern "C" void kernel_launch(void* const* d_in, const int* in_sizes, int n_in,
                              void* d_out, int out_size, void* d_ws, size_t ws_size,
                              hipStream_t stream) {
    const float* h0   = (const float*)d_in[0];
    const int*   edges= (const int*)d_in[1];
    const float* W_in = (const float*)d_in[2];
    const float* b_in = (const float*)d_in[3];
    const float* eW1  = (const float*)d_in[4];
    const float* eb1  = (const float*)d_in[5];
    const float* eW2  = (const float*)d_in[6];
    const float* eb2  = (const float*)d_in[7];
    const float* nW1  = (const float*)d_in[8];
    const float* nb1  = (const float*)d_in[9];
    const float* nW2  = (const float*)d_in[10];
    const float* nb2  = (const float*)d_in[11];
    const float* W_out= (const float*)d_in[12];
    const float* b_out= (const float*)d_in[13];
    float* out = (float*)d_out;

    const int E = in_sizes[1] / 2;      // 800000
    const int* erow = edges;
    const int* ecol = edges + E;

    char* ws = (char*)d_ws;
    unsigned short* hbf  = (unsigned short*)(ws + 0);            // 12,800,000
    int2*           binned=(int2*)(ws + 12800000);               //  9,633,792 (196*CAP*8)
    unsigned short* P    = (unsigned short*)(ws + 38424576);     // 12,800,000 (f16)
    float*          agg  = (float*)(ws + 51224576);              // 12,800,000
    int2*           eidx = (int2*)(ws + 76824576);               //  6,400,000
    float*          biasP= (float*)(ws + 83224576);              //  2,048
    unsigned short* Winp = (unsigned short*)(ws + 83226624);     // 16,384
    unsigned short* Woutp= (unsigned short*)(ws + 83243008);     // 16,384
    unsigned short* W1p  = (unsigned short*)(ws + 83259392);     // 131,072
    unsigned short* eW2p = (unsigned short*)(ws + 83390464);     // 32,768 (f16)
    unsigned short* nW1p = (unsigned short*)(ws + 83423232);     // 196,608
    unsigned short* nW2p = (unsigned short*)(ws + 83619840);     // 131,072
    int*            bucketCursor=(int*)(ws + 83752960);          // 784
    unsigned long long* zmask = (unsigned long long*)(ws + 83754496); // 6,272 (784 u64)

    const int gemm_grid = (N_NODES + 63) / 64;    // 782
    const int edge_grid = (E + 63) / 64;          // 12500
    const int pack_grid = (int)((PACK_GRID_TOTAL + 255) / 256);
    const int bin_grid  = (E + BCHUNK - 1) / BCHUNK;   // 391

    // pack also zeroes bucketCursor (consumed by bin in the next dispatch)
    pack_kernel<<<pack_grid, 256, 0, stream>>>(W_in, W_out, eW1, eb1, eW2,
                                               nW1, nW2, Winp, Woutp, W1p,
                                               eW2p, nW1p, nW2p, biasP,
                                               bucketCursor);

    // merged: binning scatter (blocks 0..390, fixed-capacity buckets) +
    // fused embedding (rest; embed full-zeroes agg for layer 0)
    bin_embed_k<<<bin_grid + gemm_grid, 256, 0, stream>>>(
        erow, ecol, bucketCursor, binned, E, bin_grid,
        h0, Winp, b_in, W1p, biasP, hbf, P, agg, N_NODES);

    // sort also emits zmask (static needs-zero row mask for layers 1..3)
    sort_k<<<NBKT, 256, 0, stream>>>(binned, bucketCursor, eidx, zmask);

    for (int l = 0; l < 4; l++) {
        edge_fused_k<<<edge_grid, 256, 0, stream>>>(
            eidx, P, eW2p + (size_t)l * SE2, eb2 + (size_t)l * 64, agg, E);
        if (l < 3) {
            node_fused_k<0><<<gemm_grid, 512, 0, stream>>>(
                hbf, agg, nW1p + (size_t)l * SN1, nb1 + (size_t)l * 128,
                nW2p + (size_t)l * SN2, nb2 + (size_t)l * 128,
                W1p + (size_t)(l + 1) * SW1, biasP + (size_t)(l + 1) * 128,
                hbf, P, nullptr, agg, zmask, N_NODES);
        } else {
            node_fused_k<1><<<gemm_grid, 512, 0, stream>>>(
                hbf, agg, nW1p + (size_t)l * SN1, nb1 + (size_t)l * 128,
                nW2p + (size_t)l * SN2, nb2 + (size_t)l * 128,
                Woutp, b_out, nullptr, nullptr, out, nullptr, zmask, N_NODES);
        }
    }
}

// Round 13
// 372.301 us; speedup vs baseline: 1.1103x; 1.0250x over previous
//
#include <hip/hip_runtime.h>
#include <hip/hip_bf16.h>
#include <hip/hip_fp16.h>
#include <cstdint>
#include <cstddef>

#define N_NODES 50000
#define N_EDGES 800000
#define NBKT    196      // ceil(50000/256) buckets of 256 rows
#define BSH     8        // rows-per-bucket shift
#define BCHUNK  2048     // edges per bin_k block
#define CAP     6144     // fixed bucket capacity (mean 4082, max ~4400)

typedef __attribute__((ext_vector_type(8))) short short8;
typedef __attribute__((ext_vector_type(4))) float floatx4;
typedef __attribute__((ext_vector_type(2))) float floatx2;
typedef __attribute__((ext_vector_type(4))) unsigned int uintx4;
typedef __attribute__((ext_vector_type(2))) unsigned int uintx2;
typedef __attribute__((ext_vector_type(8))) _Float16 half8v;

__device__ inline float bf2f(unsigned short u) {
    union { unsigned int i; float f; } v; v.i = ((unsigned int)u) << 16; return v.f;
}
__device__ inline unsigned short f2bf(float f) {
    union { float f; unsigned int i; } v; v.f = f;
    unsigned int u = v.i;
    return (unsigned short)((u + 0x7FFFu + ((u >> 16) & 1u)) >> 16);
}
// packed RNE f32x2 -> bf16x2 (v_cvt_pk_bf16_f32 on gfx950)
__device__ inline unsigned int f2bf_pk(float a, float b) {
    __hip_bfloat162 h2 = __float22bfloat162_rn(make_float2(a, b));
    return *reinterpret_cast<unsigned int*>(&h2);
}
// f16 helpers (edge path is f16: packed ALU + mfma_f32_16x16x32_f16)
__device__ inline unsigned short f2fh(float f) {
    _Float16 h = (_Float16)f;
    return __builtin_bit_cast(unsigned short, h);
}
// packed f32x2 -> f16x2 via v_cvt_pkrtz_f16_f32 (1 instr)
// NOTE: builtin returns __fp16 ext_vector_type(2) on this clang — bit_cast it.
__device__ inline unsigned int f2fh_pk(float a, float b) {
    typedef __attribute__((ext_vector_type(2))) __fp16 h2v;
    h2v r = __builtin_amdgcn_cvt_pkrtz(a, b);
    return __builtin_bit_cast(unsigned int, r);
}
__device__ inline __half2 u2h(unsigned int u) { return __builtin_bit_cast(__half2, u); }
__device__ inline unsigned int h2u(__half2 h) { return __builtin_bit_cast(unsigned int, h); }
// f16 SiLU on a packed pair.
__device__ inline __half2 silu_h2(__half2 x) {
    const __half2 nlog2e = __float2half2_rn(-1.4426950408889634f);
    const __half2 one    = __float2half2_rn(1.0f);
    __half2 e = h2exp2(__hmul2(x, nlog2e));
    return __hmul2(x, h2rcp(__hadd2(e, one)));
}
// silu via v_rcp_f32 (1 ulp) instead of IEEE divide
__device__ inline float silu_f(float x) {
    float e = __expf(-x);
    return x * __builtin_amdgcn_rcpf(1.0f + e);
}

__device__ inline int block_excl_scan_256(int v, int* buf) {
    int tid = threadIdx.x;
    buf[tid] = v;
    __syncthreads();
    #pragma unroll
    for (int off = 1; off < 256; off <<= 1) {
        int t = (tid >= off) ? buf[tid - off] : 0;
        __syncthreads();
        buf[tid] += t;
        __syncthreads();
    }
    return buf[tid] - v;
}

// ---------------------------------------------------------------------------
// Pack kernel: fp32->bf16/f16 weight rearrangement into MFMA fragment order.
// Tail zeroes bucketCursor (consumed by bin in the next dispatch).
// B-fragment order: Bp[(kb*NOUT + n)*8 + i] = B[(kb*8+i)*NOUT + n]
// ---------------------------------------------------------------------------
__device__ inline void pack_std(const float* __restrict__ src,
                                unsigned short* __restrict__ dst,
                                int NOUT, long j) {
    int i = (int)(j & 7);
    long rest = j >> 3;
    int n = (int)(rest % NOUT);
    int kb = (int)(rest / NOUT);
    dst[j] = f2bf(src[(long)(kb * 8 + i) * NOUT + n]);
}
__device__ inline void pack_std_h(const float* __restrict__ src,
                                  unsigned short* __restrict__ dst,
                                  int NOUT, long j) {
    int i = (int)(j & 7);
    long rest = j >> 3;
    int n = (int)(rest % NOUT);
    int kb = (int)(rest / NOUT);
    dst[j] = f2fh(src[(long)(kb * 8 + i) * NOUT + n]);
}

#define SW_IN 8192L
#define SW_OUT 8192L
#define SW1   16384L
#define SE2   4096L
#define SN1   24576L
#define SN2   16384L
#define SB    128L
#define PERL  (SW1 + SE2 + SN1 + SN2 + SB)
#define PACK_TOTAL (SW_IN + SW_OUT + 4 * PERL)
#define PACK_GRID_TOTAL (PACK_TOTAL + NBKT)

__global__ __launch_bounds__(256) void pack_kernel(
    const float* __restrict__ W_in,
    const float* __restrict__ W_out, const float* __restrict__ eW1,
    const float* __restrict__ eb1, const float* __restrict__ eW2,
    const float* __restrict__ nW1, const float* __restrict__ nW2,
    unsigned short* __restrict__ Winp,
    unsigned short* __restrict__ Woutp, unsigned short* __restrict__ W1p,
    unsigned short* __restrict__ eW2p, unsigned short* __restrict__ nW1p,
    unsigned short* __restrict__ nW2p, float* __restrict__ biasP,
    int* __restrict__ bucketCursor)
{
    long idx = (long)blockIdx.x * 256 + threadIdx.x;
    if (idx >= PACK_TOTAL) {
        long t = idx - PACK_TOTAL;
        if (t < NBKT) bucketCursor[t] = 0;
        return;
    }
    long j = idx;
    if (j < SW_IN) { pack_std(W_in, Winp, 128, j); return; }
    j -= SW_IN;
    if (j < SW_OUT) { pack_std(W_out, Woutp, 64, j); return; }
    j -= SW_OUT;
    int l = (int)(j / PERL);
    long r = j % PERL;
    if (r < SW1) {
        int i = (int)(r & 7);
        int n = (int)((r >> 3) & 127);
        int kb = (int)(r >> 10);
        int k = kb * 8 + i;
        const float* w = eW1 + (long)l * 256 * 64;
        float v = (n < 64) ? w[(long)k * 64 + n] : w[(long)(128 + k) * 64 + (n - 64)];
        W1p[(long)l * SW1 + r] = f2bf(v);
        return;
    }
    r -= SW1;
    if (r < SE2) { pack_std_h(eW2 + (long)l * 4096, eW2p + (long)l * SE2, 64, r); return; }
    r -= SE2;
    if (r < SN1) { pack_std(nW1 + (long)l * 24576, nW1p + (long)l * SN1, 128, r); return; }
    r -= SN1;
    if (r < SN2) { pack_std(nW2 + (long)l * 16384, nW2p + (long)l * SN2, 128, r); return; }
    r -= SN2;
    biasP[(long)l * 128 + r] = (r < 64) ? eb1[(long)l * 64 + r] : 0.0f;
}

// ---------------------------------------------------------------------------
// binned: fixed-capacity bucket regions (bucket b at binned[b*CAP..)); bin
// blocks reserve in-bucket slots via bucketCursor atomics.
// ---------------------------------------------------------------------------
#define SROWE 264
#define BE_SMEM_BYTES (64 * SROWE * 2)   // embed branch need (33792 B) >= bin need

// Merged [bin | embed] dispatch: blocks < binGrid run the binning scatter;
// the rest run the fused embedding GEMM. Independent data paths.
__global__ __launch_bounds__(256) void bin_embed_k(
    const int* __restrict__ erow, const int* __restrict__ ecol,
    int* __restrict__ bucketCursor,
    int2* __restrict__ binned, int E, int binGrid,
    const float* __restrict__ h0, const unsigned short* __restrict__ Win,
    const float* __restrict__ b_in, const unsigned short* __restrict__ W1,
    const float* __restrict__ biasP,
    unsigned short* __restrict__ hB, unsigned short* __restrict__ Pout,
    float* __restrict__ aggZ, int M)
{
    __shared__ char SMEM[BE_SMEM_BYTES];
    const int tid = threadIdx.x;

    if (blockIdx.x < binGrid) {
        // ---------------- bin branch ----------------
        int* cnt      = (int*)SMEM;              // NBKT
        int* binStart = cnt + NBKT;              // NBKT
        int* gbase    = binStart + NBKT;         // NBKT (in-bucket base)
        int* scanbuf  = gbase + NBKT;            // 256
        int2* staged  = (int2*)(scanbuf + 256);  // BCHUNK

        const int base = blockIdx.x * BCHUNK;
        const int nloc = min(BCHUNK, E - base);

        for (int i = tid; i < NBKT; i += 256) cnt[i] = 0;
        __syncthreads();

        int2 ed[BCHUNK / 256];
        int  bo[BCHUNK / 256];
        #pragma unroll
        for (int i = 0; i < BCHUNK / 256; i++) {
            int jl = i * 256 + tid;
            if (jl < nloc) {
                int j = base + jl;
                int r = erow[j], c = ecol[j];
                ed[i] = make_int2(r, c);
                int b = r >> BSH;
                int off = atomicAdd(&cnt[b], 1);
                bo[i] = (b << 12) | off;
            } else bo[i] = -1;
        }
        __syncthreads();

        int v = (tid < NBKT) ? cnt[tid] : 0;
        int excl = block_excl_scan_256(v, scanbuf);
        if (tid < NBKT) binStart[tid] = excl;
        if (tid < NBKT && v > 0)
            gbase[tid] = atomicAdd(&bucketCursor[tid], v);
        __syncthreads();

        #pragma unroll
        for (int i = 0; i < BCHUNK / 256; i++) {
            if (bo[i] >= 0)
                staged[binStart[bo[i] >> 12] + (bo[i] & 0xFFF)] = ed[i];
        }
        __syncthreads();

        for (int j = tid; j < nloc; j += 256) {
            int2 e = staged[j];
            int b = e.x >> BSH;
            int off = gbase[b] + (j - binStart[b]);
            if (off < CAP)
                binned[(size_t)b * CAP + off] = e;
        }
        return;
    }

    // ---------------- embed branch ----------------
    unsigned short* S = (unsigned short*)SMEM;
    const int m0 = (blockIdx.x - binGrid) * 64;
    const int wave = tid >> 6;
    const int lane = tid & 63;
    const int lrow = lane & 15;
    const int quad = lane >> 4;
    const int elb = wave * 16 + quad * 4;

    // staging: h0 f32 -> bf16 into S cols 0..63
    for (int t = tid; t < 64 * 16; t += 256) {
        int rr = t >> 4, c = t & 15;
        int row = m0 + rr;
        floatx4 v = {0, 0, 0, 0};
        if (row < M) v = *(const floatx4*)(h0 + (size_t)row * 64 + c * 4);
        uintx2 u = { f2bf_pk(v[0], v[1]), f2bf_pk(v[2], v[3]) };
        *(uintx2*)(&S[rr * SROWE + c * 4]) = u;
    }
    __syncthreads();   // barrier 1

    // zero this block's agg rows for layer 0 (full zero — zmask not built yet)
    {
        floatx4 z = {0, 0, 0, 0};
        for (int t = tid; t < 64 * 16; t += 256) {
            int rr = t >> 4, c = t & 15;
            int row = m0 + rr;
            if (row < M) *(floatx4*)(aggZ + (size_t)row * 64 + c * 4) = z;
        }
    }

    const unsigned short* arow = &S[(wave * 16 + lrow) * SROWE];

    floatx4 acc[8];
    #pragma unroll
    for (int i = 0; i < 8; i++) acc[i] = (floatx4){0, 0, 0, 0};
    #pragma unroll
    for (int kt = 0; kt < 2; kt++) {
        short8 afrag = *(const short8*)(arow + kt * 32 + quad * 8);
        int kb = kt * 4 + quad;
        #pragma unroll
        for (int nt = 0; nt < 8; nt++) {
            short8 bfrag = *(const short8*)(Win + (size_t)(kb * 128 + nt * 16 + lrow) * 8);
            acc[nt] = __builtin_amdgcn_mfma_f32_16x16x32_bf16(afrag, bfrag, acc[nt], 0, 0, 0);
        }
    }

    // epilogue: h1 -> S cols 0..127 (bf16)
    #pragma unroll
    for (int nt = 0; nt < 8; nt++) {
        int n = nt * 16 + lrow;
        float bv = b_in[n];
        floatx4 v4;
        #pragma unroll
        for (int r = 0; r < 4; r++) v4[r] = acc[nt][r] + bv;
        unsigned int p01 = f2bf_pk(v4[0], v4[1]);
        unsigned int p23 = f2bf_pk(v4[2], v4[3]);
        S[(elb + 0) * SROWE + n] = (unsigned short)(p01 & 0xFFFF);
        S[(elb + 1) * SROWE + n] = (unsigned short)(p01 >> 16);
        S[(elb + 2) * SROWE + n] = (unsigned short)(p23 & 0xFFFF);
        S[(elb + 3) * SROWE + n] = (unsigned short)(p23 >> 16);
    }

    floatx4 acc3[8];
    #pragma unroll
    for (int i = 0; i < 8; i++) acc3[i] = (floatx4){0, 0, 0, 0};
    #pragma unroll
    for (int kt = 0; kt < 4; kt++) {
        short8 afrag = *(const short8*)(arow + kt * 32 + quad * 8);
        int kb = kt * 4 + quad;
        #pragma unroll
        for (int nt = 0; nt < 8; nt++) {
            short8 bfrag = *(const short8*)(W1 + (size_t)(kb * 128 + nt * 16 + lrow) * 8);
            acc3[nt] = __builtin_amdgcn_mfma_f32_16x16x32_bf16(afrag, bfrag, acc3[nt], 0, 0, 0);
        }
    }
    #pragma unroll
    for (int nt = 0; nt < 8; nt++) {
        int n = nt * 16 + lrow;
        float bv = biasP[n];
        unsigned int p01 = f2fh_pk(acc3[nt][0] + bv, acc3[nt][1] + bv);
        unsigned int p23 = f2fh_pk(acc3[nt][2] + bv, acc3[nt][3] + bv);
        S[(elb + 0) * SROWE + 128 + n] = (unsigned short)(p01 & 0xFFFF);
        S[(elb + 1) * SROWE + 128 + n] = (unsigned short)(p01 >> 16);
        S[(elb + 2) * SROWE + 128 + n] = (unsigned short)(p23 & 0xFFFF);
        S[(elb + 3) * SROWE + 128 + n] = (unsigned short)(p23 >> 16);
    }
    __syncthreads();   // barrier 2

    for (int t = tid; t < 64 * 32; t += 256) {
        int rr = t / 32, c = t % 32;
        int row = m0 + rr;
        if (row < M) {
            if (c < 16)
                *(uintx4*)(hB + (size_t)row * 128 + c * 8) =
                    *(const uintx4*)(&S[rr * SROWE + c * 8]);
            else
                *(uintx4*)(Pout + (size_t)row * 128 + (c - 16) * 8) =
                    *(const uintx4*)(&S[rr * SROWE + 128 + (c - 16) * 8]);
        }
    }
}

// ---------------------------------------------------------------------------
// sort_k — also builds the static needs-zero row mask. Row r needs pre-zeroing
// (atomicAdd target in edge_fused) iff it has no edges, OR its eidx range
// covers an index ≡0 or ≡63 (mod 64). Unflagged rows are fully overwritten by
// a single interior-segment plain store.
// ---------------------------------------------------------------------------
__global__ __launch_bounds__(256) void sort_k(
    const int2* __restrict__ binned, const int* __restrict__ bucketCursor,
    int2* __restrict__ eidx, unsigned long long* __restrict__ zmask)
{
    __shared__ int2 st[CAP];
    __shared__ int cnt[256];
    __shared__ int cur[256];
    __shared__ int scanbuf[256];
    __shared__ int baseS[2];
    const int b = blockIdx.x;
    const int tid = threadIdx.x;

    // counts = final cursor values (clamped at CAP); local prefix for eidx base
    {
        int v = (tid < NBKT) ? min(bucketCursor[tid], CAP) : 0;
        int excl = block_excl_scan_256(v, scanbuf);
        if (tid == b) { baseS[0] = excl; baseS[1] = excl + v; }
    }
    __syncthreads();
    const int s0 = baseS[0];
    const int n = baseS[1] - s0;

    cnt[tid] = 0;
    __syncthreads();
    const int2* bsrc = binned + (size_t)b * CAP;
    for (int j = tid; j < n; j += 256) {
        int2 e = bsrc[j];
        st[j] = e;
        atomicAdd(&cnt[e.x & 255], 1);
    }
    __syncthreads();
    int myCnt = cnt[tid];
    int excl = block_excl_scan_256(myCnt, scanbuf);
    cur[tid] = excl;
    const int myLo = s0 + excl;          // global eidx start of this row
    __syncthreads();
    for (int j = tid; j < n; j += 256) {
        int2 e = st[j];
        int pos = atomicAdd(&cur[e.x & 255], 1);
        eidx[s0 + pos] = e;
    }

    // needs-zero mask: one u64 per 64 rows, via per-wave ballot
    {
        bool nz;
        if (myCnt == 0) nz = true;
        else {
            int lo = myLo, hi = myLo + myCnt;
            int A = lo >> 6, Bk = (hi - 1) >> 6;
            nz = (Bk > A) || ((lo & 63) == 0) || (((hi - 1) & 63) == 63);
        }
        unsigned long long m = __ballot(nz);
        if ((tid & 63) == 0)
            zmask[(((size_t)b << 8) + tid) >> 6] = m;
    }
}

// ---------------------------------------------------------------------------
// Fused edge + block-segmented aggregate over sorted edges (R8 body, best
// measured 44.0 µs: f32 M2s [el][68], segStartS reduction, f16 P/eW2 +
// f16 MFMA, bias in accumulators).
// ---------------------------------------------------------------------------
__global__ __launch_bounds__(256) void edge_fused_k(
    const int2* __restrict__ eidx,
    const unsigned short* __restrict__ P,    // [N,128] f16: 0..63 top(+b1), 64..127 bot
    const unsigned short* __restrict__ Bp,   // eW2 frag order, f16
    const float* __restrict__ b2, float* __restrict__ agg, int E)
{
    __shared__ float M2s[64 * 68];
    __shared__ int ridS[64];
    __shared__ short segStartS[66];
    __shared__ int nsegS;
    const int tid = threadIdx.x;
    const int wave = tid >> 6;
    const int lane = tid & 63;
    const int lrow = lane & 15;
    const int quad = lane >> 4;
    const int e0 = blockIdx.x * 64;
    const int el = wave * 16 + lrow;
    const int e = e0 + el;

    // bias preloaded into the MFMA accumulators
    floatx4 acc[4];
    #pragma unroll
    for (int nt = 0; nt < 4; nt++) {
        float bv = b2[nt * 16 + lrow];
        acc[nt] = (floatx4){bv, bv, bv, bv};
    }

    half8v af0 = {};
    half8v af1 = {};
    if (e < E) {
        int2 rc = eidx[e];
        int rr = rc.x, cc = rc.y;
        if (quad == 0) ridS[el] = rr;
        const uintx4* pt = (const uintx4*)(P + (size_t)rr * 128 + quad * 8);
        const uintx4* pb = (const uintx4*)(P + (size_t)cc * 128 + 64 + quad * 8);
        uintx4 t0 = pt[0], t1 = pt[4];
        uintx4 b0 = pb[0], b1 = pb[4];
        uintx4 O0, O1;
        #pragma unroll
        for (int i = 0; i < 4; i++) {
            O0[i] = h2u(silu_h2(__hadd2(u2h(t0[i]), u2h(b0[i]))));
            O1[i] = h2u(silu_h2(__hadd2(u2h(t1[i]), u2h(b1[i]))));
        }
        af0 = __builtin_bit_cast(half8v, O0);
        af1 = __builtin_bit_cast(half8v, O1);
    } else if (quad == 0) {
        ridS[el] = -1;
    }

    #pragma unroll
    for (int nt = 0; nt < 4; nt++) {
        half8v bf0 = *(const half8v*)(Bp + (size_t)((0 * 4 + quad) * 64 + nt * 16 + lrow) * 8);
        acc[nt] = __builtin_amdgcn_mfma_f32_16x16x32_f16(af0, bf0, acc[nt], 0, 0, 0);
        half8v bf1 = *(const half8v*)(Bp + (size_t)((1 * 4 + quad) * 64 + nt * 16 + lrow) * 8);
        acc[nt] = __builtin_amdgcn_mfma_f32_16x16x32_f16(af1, bf1, acc[nt], 0, 0, 0);
    }

    #pragma unroll
    for (int nt = 0; nt < 4; nt++) {
        int n = nt * 16 + lrow;
        #pragma unroll
        for (int r = 0; r < 4; r++) {
            int el2 = wave * 16 + quad * 4 + r;
            M2s[el2 * 68 + n] = silu_f(acc[nt][r]);
        }
    }
    __syncthreads();

    if (tid < 64) {
        bool st = (ridS[tid] >= 0) && (tid == 0 || ridS[tid] != ridS[tid - 1]);
        unsigned long long m = __ballot(st);
        if (st) {
            int pos = __popcll(m & ((1ull << tid) - 1));
            segStartS[pos] = (short)tid;
        }
        if (tid == 0) {
            int ns = __popcll(m);
            nsegS = ns;
            int nvalid = E - e0;
            if (nvalid > 64) nvalid = 64;
            segStartS[ns] = (short)nvalid;
        }
    }
    __syncthreads();

    {
        int f = tid & 63;
        int g = tid >> 6;
        int ns = nsegS;
        for (int j = g; j < ns; j += 4) {
            int a = segStartS[j], b = segStartS[j + 1];
            float s = 0.0f;
            for (int el2 = a; el2 < b; el2++) s += M2s[el2 * 68 + f];
            int rv = ridS[a];
            if (j == 0 || j == ns - 1)
                atomicAdd(&agg[(size_t)rv * 64 + f], s);
            else
                agg[(size_t)rv * 64 + f] = s;
        }
    }
}

// ---------------------------------------------------------------------------
// Fused node-side chain — R21: 256 threads / 32 rows per block (was 512/64).
// Same per-wave work (waves 0..3: g=wave>>1 row group, h=wave&1 N half);
// LDS halves to 16.9KB -> 8 blocks/CU (was 4), grid 1563 (was 782) for
// better latency hiding + tail granularity.
// ---------------------------------------------------------------------------
#define SROW 264
template<int FINAL>
__global__ __launch_bounds__(256) void node_fused_k(
    const unsigned short* __restrict__ hbf, const float* __restrict__ agg,
    const unsigned short* __restrict__ W1, const float* __restrict__ b1,
    const unsigned short* __restrict__ W2, const float* __restrict__ b2,
    const unsigned short* __restrict__ B3, const float* __restrict__ bias3,
    unsigned short* __restrict__ hB, unsigned short* __restrict__ Pout,
    float* __restrict__ outF, float* __restrict__ aggZ,
    const unsigned long long* __restrict__ zmask, int M)
{
    __shared__ unsigned short S[32 * SROW];
    const int tid = threadIdx.x;
    const int m0 = blockIdx.x * 32;
    const int wave = tid >> 6;
    const int lane = tid & 63;
    const int lrow = lane & 15;
    const int quad = lane >> 4;
    const int g = wave >> 1;          // row group 0..1
    const int h = wave & 1;           // N half
    const int elb = g * 16 + quad * 4;

    // agg A-fragments straight into registers (kt=4,5 of the K=192 A-op)
    short8 afa0, afa1;
    {
        const float* ap = agg + (size_t)(m0 + g * 16 + lrow) * 64;
        floatx4 q0 = *(const floatx4*)(ap + quad * 8);
        floatx4 q1 = *(const floatx4*)(ap + quad * 8 + 4);
        floatx4 q2 = *(const floatx4*)(ap + 32 + quad * 8);
        floatx4 q3 = *(const floatx4*)(ap + 32 + quad * 8 + 4);
        unsigned int c0[4] = { f2bf_pk(q0[0], q0[1]), f2bf_pk(q0[2], q0[3]),
                               f2bf_pk(q1[0], q1[1]), f2bf_pk(q1[2], q1[3]) };
        unsigned int c1[4] = { f2bf_pk(q2[0], q2[1]), f2bf_pk(q2[2], q2[3]),
                               f2bf_pk(q3[0], q3[1]), f2bf_pk(q3[2], q3[3]) };
        afa0 = *(const short8*)c0;
        afa1 = *(const short8*)c1;
    }

    // staging: h (128 bf16) only -> S cols 0..127
    for (int t = tid; t < 32 * 16; t += 256) {
        int rr = t >> 4, c = t & 15;
        int row = m0 + rr;
        uintx4 val = {0, 0, 0, 0};
        if (row < M) val = *(const uintx4*)(hbf + (size_t)row * 128 + c * 8);
        *(uintx4*)(&S[rr * SROW + c * 8]) = val;
    }
    __syncthreads();   // B1

    // masked zero of this block's agg rows for the next layer
    if (!FINAL) {
        unsigned long long zm = zmask[m0 >> 6];
        int bb = m0 & 63;   // 0 or 32
        floatx4 z = {0, 0, 0, 0};
        for (int t = tid; t < 32 * 16; t += 256) {
            int rr = t >> 4, c = t & 15;
            int row = m0 + rr;
            if (row < M && ((zm >> (bb + rr)) & 1ull))
                *(floatx4*)(aggZ + (size_t)row * 64 + c * 4) = z;
        }
    }

    const unsigned short* arow = &S[(g * 16 + lrow) * SROW];

    // ---- phase A MFMA: K=192 (kt 0..3 from LDS, kt 4..5 from registers) ----
    floatx4 acc[4];
    #pragma unroll
    for (int i = 0; i < 4; i++) acc[i] = (floatx4){0, 0, 0, 0};
    #pragma unroll
    for (int kt = 0; kt < 4; kt++) {
        short8 afrag = *(const short8*)(arow + kt * 32 + quad * 8);
        int kb = kt * 4 + quad;
        #pragma unroll
        for (int j = 0; j < 4; j++) {
            int n = (4 * h + j) * 16 + lrow;
            short8 bfrag = *(const short8*)(W1 + (size_t)(kb * 128 + n) * 8);
            acc[j] = __builtin_amdgcn_mfma_f32_16x16x32_bf16(afrag, bfrag, acc[j], 0, 0, 0);
        }
    }
    #pragma unroll
    for (int j = 0; j < 4; j++) {
        int n = (4 * h + j) * 16 + lrow;
        short8 b4 = *(const short8*)(W1 + (size_t)((16 + quad) * 128 + n) * 8);
        acc[j] = __builtin_amdgcn_mfma_f32_16x16x32_bf16(afa0, b4, acc[j], 0, 0, 0);
        short8 b5 = *(const short8*)(W1 + (size_t)((20 + quad) * 128 + n) * 8);
        acc[j] = __builtin_amdgcn_mfma_f32_16x16x32_bf16(afa1, b5, acc[j], 0, 0, 0);
    }

    // epilogue A: t -> S cols 128..255
    #pragma unroll
    for (int j = 0; j < 4; j++) {
        int n = (4 * h + j) * 16 + lrow;
        float bv = b1[n];
        unsigned int p01 = f2bf_pk(silu_f(acc[j][0] + bv), silu_f(acc[j][1] + bv));
        unsigned int p23 = f2bf_pk(silu_f(acc[j][2] + bv), silu_f(acc[j][3] + bv));
        S[(elb + 0) * SROW + 128 + n] = (unsigned short)(p01 & 0xFFFF);
        S[(elb + 1) * SROW + 128 + n] = (unsigned short)(p01 >> 16);
        S[(elb + 2) * SROW + 128 + n] = (unsigned short)(p23 & 0xFFFF);
        S[(elb + 3) * SROW + 128 + n] = (unsigned short)(p23 >> 16);
    }
    __syncthreads();   // B2: t complete

    // ---- phase B MFMA: K=128 over t (cols 128..255) ----
    floatx4 acc2[4];
    #pragma unroll
    for (int i = 0; i < 4; i++) acc2[i] = (floatx4){0, 0, 0, 0};
    #pragma unroll
    for (int kt = 0; kt < 4; kt++) {
        short8 afrag = *(const short8*)(arow + 128 + kt * 32 + quad * 8);
        int kb = kt * 4 + quad;
        #pragma unroll
        for (int j = 0; j < 4; j++) {
            int n = (4 * h + j) * 16 + lrow;
            short8 bfrag = *(const short8*)(W2 + (size_t)(kb * 128 + n) * 8);
            acc2[j] = __builtin_amdgcn_mfma_f32_16x16x32_bf16(afrag, bfrag, acc2[j], 0, 0, 0);
        }
    }

    // epilogue B: h_new = acc2 + b2 + res(LDS bf16, owner cells) -> S cols 0..127
    #pragma unroll
    for (int j = 0; j < 4; j++) {
        int n = (4 * h + j) * 16 + lrow;
        float bv = b2[n];
        floatx4 v4;
        #pragma unroll
        for (int r = 0; r < 4; r++) {
            float res = bf2f(S[(elb + r) * SROW + n]);
            v4[r] = acc2[j][r] + bv + res;
        }
        unsigned int p01 = f2bf_pk(v4[0], v4[1]);
        unsigned int p23 = f2bf_pk(v4[2], v4[3]);
        S[(elb + 0) * SROW + n] = (unsigned short)(p01 & 0xFFFF);
        S[(elb + 1) * SROW + n] = (unsigned short)(p01 >> 16);
        S[(elb + 2) * SROW + n] = (unsigned short)(p23 & 0xFFFF);
        S[(elb + 3) * SROW + n] = (unsigned short)(p23 >> 16);
    }
    __syncthreads();   // B3: h_new complete (all t reads done)

    // ---- phase C MFMA: K=128 -> P (128, f16) or out (64, f32) ----
    constexpr int NT3 = FINAL ? 2 : 4;
    constexpr int NO3 = FINAL ? 64 : 128;
    floatx4 acc3[NT3];
    #pragma unroll
    for (int i = 0; i < NT3; i++) acc3[i] = (floatx4){0, 0, 0, 0};
    #pragma unroll
    for (int kt = 0; kt < 4; kt++) {
        short8 afrag = *(const short8*)(arow + kt * 32 + quad * 8);
        int kb = kt * 4 + quad;
        #pragma unroll
        for (int j = 0; j < NT3; j++) {
            int n = (NT3 * h + j) * 16 + lrow;
            short8 bfrag = *(const short8*)(B3 + (size_t)(kb * NO3 + n) * 8);
            acc3[j] = __builtin_amdgcn_mfma_f32_16x16x32_bf16(afrag, bfrag, acc3[j], 0, 0, 0);
        }
    }
    // epilogue C -> S cols 128..255 (f16 P) or fp32 out region (same cols)
    #pragma unroll
    for (int j = 0; j < NT3; j++) {
        int n = (NT3 * h + j) * 16 + lrow;
        float bv = bias3[n];
        if (FINAL) {
            #pragma unroll
            for (int r = 0; r < 4; r++)
                ((float*)(&S[(elb + r) * SROW + 128]))[n] = acc3[j][r] + bv;
        } else {
            unsigned int p01 = f2fh_pk(acc3[j][0] + bv, acc3[j][1] + bv);
            unsigned int p23 = f2fh_pk(acc3[j][2] + bv, acc3[j][3] + bv);
            S[(elb + 0) * SROW + 128 + n] = (unsigned short)(p01 & 0xFFFF);
            S[(elb + 1) * SROW + 128 + n] = (unsigned short)(p01 >> 16);
            S[(elb + 2) * SROW + 128 + n] = (unsigned short)(p23 & 0xFFFF);
            S[(elb + 3) * SROW + 128 + n] = (unsigned short)(p23 >> 16);
        }
    }
    __syncthreads();   // B4

    // cooperative wide stores
    if (FINAL) {
        for (int t = tid; t < 32 * 16; t += 256) {
            int rr = t >> 4, c = t & 15;
            int row = m0 + rr;
            if (row < M)
                *(floatx4*)(outF + (size_t)row * 64 + c * 4) =
                    *(const floatx4*)((const float*)(&S[rr * SROW + 128]) + c * 4);
        }
    } else {
        for (int t = tid; t < 32 * 32; t += 256) {
            int rr = t >> 5, c = t & 31;
            int row = m0 + rr;
            if (row < M) {
                if (c < 16)
                    *(uintx4*)(hB + (size_t)row * 128 + c * 8) =
                        *(const uintx4*)(&S[rr * SROW + c * 8]);
                else
                    *(uintx4*)(Pout + (size_t)row * 128 + (c - 16) * 8) =
                        *(const uintx4*)(&S[rr * SROW + 128 + (c - 16) * 8]);
            }
        }
    }
}

// ---------------------------------------------------------------------------
extern "C" void kernel_launch(void* const* d_in, const int* in_sizes, int n_in,
                              void* d_out, int out_size, void* d_ws, size_t ws_size,
                              hipStream_t stream) {
    const float* h0   = (const float*)d_in[0];
    const int*   edges= (const int*)d_in[1];
    const float* W_in = (const float*)d_in[2];
    const float* b_in = (const float*)d_in[3];
    const float* eW1  = (const float*)d_in[4];
    const float* eb1  = (const float*)d_in[5];
    const float* eW2  = (const float*)d_in[6];
    const float* eb2  = (const float*)d_in[7];
    const float* nW1  = (const float*)d_in[8];
    const float* nb1  = (const float*)d_in[9];
    const float* nW2  = (const float*)d_in[10];
    const float* nb2  = (const float*)d_in[11];
    const float* W_out= (const float*)d_in[12];
    const float* b_out= (const float*)d_in[13];
    float* out = (float*)d_out;

    const int E = in_sizes[1] / 2;      // 800000
    const int* erow = edges;
    const int* ecol = edges + E;

    char* ws = (char*)d_ws;
    unsigned short* hbf  = (unsigned short*)(ws + 0);            // 12,800,000
    int2*           binned=(int2*)(ws + 12800000);               //  9,633,792 (196*CAP*8)
    unsigned short* P    = (unsigned short*)(ws + 38424576);     // 12,800,000 (f16)
    float*          agg  = (float*)(ws + 51224576);              // 12,800,000
    int2*           eidx = (int2*)(ws + 76824576);               //  6,400,000
    float*          biasP= (float*)(ws + 83224576);              //  2,048
    unsigned short* Winp = (unsigned short*)(ws + 83226624);     // 16,384
    unsigned short* Woutp= (unsigned short*)(ws + 83243008);     // 16,384
    unsigned short* W1p  = (unsigned short*)(ws + 83259392);     // 131,072
    unsigned short* eW2p = (unsigned short*)(ws + 83390464);     // 32,768 (f16)
    unsigned short* nW1p = (unsigned short*)(ws + 83423232);     // 196,608
    unsigned short* nW2p = (unsigned short*)(ws + 83619840);     // 131,072
    int*            bucketCursor=(int*)(ws + 83752960);          // 784
    unsigned long long* zmask = (unsigned long long*)(ws + 83754496); // 6,272 (784 u64)

    const int gemm_grid = (N_NODES + 63) / 64;    // 782 (embed)
    const int node_grid = (N_NODES + 31) / 32;    // 1563 (node, 32 rows/block)
    const int edge_grid = (E + 63) / 64;          // 12500
    const int pack_grid = (int)((PACK_GRID_TOTAL + 255) / 256);
    const int bin_grid  = (E + BCHUNK - 1) / BCHUNK;   // 391

    // pack also zeroes bucketCursor (consumed by bin in the next dispatch)
    pack_kernel<<<pack_grid, 256, 0, stream>>>(W_in, W_out, eW1, eb1, eW2,
                                               nW1, nW2, Winp, Woutp, W1p,
                                               eW2p, nW1p, nW2p, biasP,
                                               bucketCursor);

    // merged: binning scatter (blocks 0..390, fixed-capacity buckets) +
    // fused embedding (rest; embed full-zeroes agg for layer 0)
    bin_embed_k<<<bin_grid + gemm_grid, 256, 0, stream>>>(
        erow, ecol, bucketCursor, binned, E, bin_grid,
        h0, Winp, b_in, W1p, biasP, hbf, P, agg, N_NODES);

    // sort also emits zmask (static needs-zero row mask for layers 1..3)
    sort_k<<<NBKT, 256, 0, stream>>>(binned, bucketCursor, eidx, zmask);

    for (int l = 0; l < 4; l++) {
        edge_fused_k<<<edge_grid, 256, 0, stream>>>(
            eidx, P, eW2p + (size_t)l * SE2, eb2 + (size_t)l * 64, agg, E);
        if (l < 3) {
            node_fused_k<0><<<node_grid, 256, 0, stream>>>(
                hbf, agg, nW1p + (size_t)l * SN1, nb1 + (size_t)l * 128,
                nW2p + (size_t)l * SN2, nb2 + (size_t)l * 128,
                W1p + (size_t)(l + 1) * SW1, biasP + (size_t)(l + 1) * 128,
                hbf, P, nullptr, agg, zmask, N_NODES);
        } else {
            node_fused_k<1><<<node_grid, 256, 0, stream>>>(
                hbf, agg, nW1p + (size_t)l * SN1, nb1 + (size_t)l * 128,
                nW2p + (size_t)l * SN2, nb2 + (size_t)l * 128,
                Woutp, b_out, nullptr, nullptr, out, nullptr, zmask, N_NODES);
        }
    }
}

// Round 14
// 367.178 us; speedup vs baseline: 1.1258x; 1.0140x over previous
//
#include <hip/hip_runtime.h>
#include <hip/hip_bf16.h>
#include <hip/hip_fp16.h>
#include <cstdint>
#include <cstddef>

#define N_NODES 50000
#define N_EDGES 800000
#define NBKT    196      // ceil(50000/256) buckets of 256 rows
#define BSH     8        // rows-per-bucket shift
#define BCHUNK  2048     // edges per bin block
#define CAP     6144     // fixed bucket capacity (mean 4082, max ~4400)

typedef __attribute__((ext_vector_type(8))) short short8;
typedef __attribute__((ext_vector_type(4))) float floatx4;
typedef __attribute__((ext_vector_type(2))) float floatx2;
typedef __attribute__((ext_vector_type(4))) unsigned int uintx4;
typedef __attribute__((ext_vector_type(2))) unsigned int uintx2;
typedef __attribute__((ext_vector_type(8))) _Float16 half8v;

__device__ inline float bf2f(unsigned short u) {
    union { unsigned int i; float f; } v; v.i = ((unsigned int)u) << 16; return v.f;
}
__device__ inline unsigned short f2bf(float f) {
    union { float f; unsigned int i; } v; v.f = f;
    unsigned int u = v.i;
    return (unsigned short)((u + 0x7FFFu + ((u >> 16) & 1u)) >> 16);
}
// packed RNE f32x2 -> bf16x2 (v_cvt_pk_bf16_f32 on gfx950)
__device__ inline unsigned int f2bf_pk(float a, float b) {
    __hip_bfloat162 h2 = __float22bfloat162_rn(make_float2(a, b));
    return *reinterpret_cast<unsigned int*>(&h2);
}
// f16 helpers (edge path is f16: packed ALU + mfma_f32_16x16x32_f16)
__device__ inline unsigned short f2fh(float f) {
    _Float16 h = (_Float16)f;
    return __builtin_bit_cast(unsigned short, h);
}
// packed f32x2 -> f16x2 via v_cvt_pkrtz_f16_f32 (1 instr)
// NOTE: builtin returns __fp16 ext_vector_type(2) on this clang — bit_cast it.
__device__ inline unsigned int f2fh_pk(float a, float b) {
    typedef __attribute__((ext_vector_type(2))) __fp16 h2v;
    h2v r = __builtin_amdgcn_cvt_pkrtz(a, b);
    return __builtin_bit_cast(unsigned int, r);
}
__device__ inline __half2 u2h(unsigned int u) { return __builtin_bit_cast(__half2, u); }
__device__ inline unsigned int h2u(__half2 h) { return __builtin_bit_cast(unsigned int, h); }
// f16 SiLU on a packed pair.
__device__ inline __half2 silu_h2(__half2 x) {
    const __half2 nlog2e = __float2half2_rn(-1.4426950408889634f);
    const __half2 one    = __float2half2_rn(1.0f);
    __half2 e = h2exp2(__hmul2(x, nlog2e));
    return __hmul2(x, h2rcp(__hadd2(e, one)));
}
// silu via v_rcp_f32 (1 ulp) instead of IEEE divide
__device__ inline float silu_f(float x) {
    float e = __expf(-x);
    return x * __builtin_amdgcn_rcpf(1.0f + e);
}

__device__ inline int block_excl_scan_256(int v, int* buf) {
    int tid = threadIdx.x;
    buf[tid] = v;
    __syncthreads();
    #pragma unroll
    for (int off = 1; off < 256; off <<= 1) {
        int t = (tid >= off) ? buf[tid - off] : 0;
        __syncthreads();
        buf[tid] += t;
        __syncthreads();
    }
    return buf[tid] - v;
}

// ---------------------------------------------------------------------------
// Weight packing helpers.
// B-fragment order: Bp[(kb*NOUT + n)*8 + i] = B[(kb*8+i)*NOUT + n]
// ---------------------------------------------------------------------------
__device__ inline void pack_std(const float* __restrict__ src,
                                unsigned short* __restrict__ dst,
                                int NOUT, long j) {
    int i = (int)(j & 7);
    long rest = j >> 3;
    int n = (int)(rest % NOUT);
    int kb = (int)(rest / NOUT);
    dst[j] = f2bf(src[(long)(kb * 8 + i) * NOUT + n]);
}
__device__ inline void pack_std_h(const float* __restrict__ src,
                                  unsigned short* __restrict__ dst,
                                  int NOUT, long j) {
    int i = (int)(j & 7);
    long rest = j >> 3;
    int n = (int)(rest % NOUT);
    int kb = (int)(rest / NOUT);
    dst[j] = f2fh(src[(long)(kb * 8 + i) * NOUT + n]);
}

#define SW_IN 8192L
#define SW_OUT 8192L
#define SW1   16384L
#define SE2   4096L
#define SN1   24576L
#define SN2   16384L
#define SB    128L
#define PERL  (SW1 + SE2 + SN1 + SN2 + SB)
#define PACK_TOTAL (SW_IN + SW_OUT + 4 * PERL)
#define PACK_BLOCKS ((int)((PACK_TOTAL + 255) / 256))

// ---------------------------------------------------------------------------
// R22: merged [bin | pack] dispatch. Blocks < binGrid run the binning
// scatter; the rest run weight packing. Independent data paths (bin:
// edges -> binned/cursor; pack: weights -> packed buffers). bucketCursor
// pre-zeroed by a 784B memset (pack-tail zeroing would race with bin here).
// ---------------------------------------------------------------------------
#define PB_SMEM_BYTES (NBKT * 3 * 4 + 256 * 4 + BCHUNK * 8)   // bin branch need

__global__ __launch_bounds__(256) void bin_pack_k(
    const int* __restrict__ erow, const int* __restrict__ ecol,
    int* __restrict__ bucketCursor, int2* __restrict__ binned,
    int E, int binGrid,
    const float* __restrict__ W_in, const float* __restrict__ W_out,
    const float* __restrict__ eW1, const float* __restrict__ eb1,
    const float* __restrict__ eW2, const float* __restrict__ nW1,
    const float* __restrict__ nW2,
    unsigned short* __restrict__ Winp, unsigned short* __restrict__ Woutp,
    unsigned short* __restrict__ W1p, unsigned short* __restrict__ eW2p,
    unsigned short* __restrict__ nW1p, unsigned short* __restrict__ nW2p,
    float* __restrict__ biasP)
{
    __shared__ char SMEM[PB_SMEM_BYTES];
    const int tid = threadIdx.x;

    if (blockIdx.x < binGrid) {
        // ---------------- bin branch ----------------
        int* cnt      = (int*)SMEM;              // NBKT
        int* binStart = cnt + NBKT;              // NBKT
        int* gbase    = binStart + NBKT;         // NBKT (in-bucket base)
        int* scanbuf  = gbase + NBKT;            // 256
        int2* staged  = (int2*)(scanbuf + 256);  // BCHUNK

        const int base = blockIdx.x * BCHUNK;
        const int nloc = min(BCHUNK, E - base);

        for (int i = tid; i < NBKT; i += 256) cnt[i] = 0;
        __syncthreads();

        int2 ed[BCHUNK / 256];
        int  bo[BCHUNK / 256];
        #pragma unroll
        for (int i = 0; i < BCHUNK / 256; i++) {
            int jl = i * 256 + tid;
            if (jl < nloc) {
                int j = base + jl;
                int r = erow[j], c = ecol[j];
                ed[i] = make_int2(r, c);
                int b = r >> BSH;
                int off = atomicAdd(&cnt[b], 1);
                bo[i] = (b << 12) | off;
            } else bo[i] = -1;
        }
        __syncthreads();

        int v = (tid < NBKT) ? cnt[tid] : 0;
        int excl = block_excl_scan_256(v, scanbuf);
        if (tid < NBKT) binStart[tid] = excl;
        if (tid < NBKT && v > 0)
            gbase[tid] = atomicAdd(&bucketCursor[tid], v);
        __syncthreads();

        #pragma unroll
        for (int i = 0; i < BCHUNK / 256; i++) {
            if (bo[i] >= 0)
                staged[binStart[bo[i] >> 12] + (bo[i] & 0xFFF)] = ed[i];
        }
        __syncthreads();

        for (int j = tid; j < nloc; j += 256) {
            int2 e = staged[j];
            int b = e.x >> BSH;
            int off = gbase[b] + (j - binStart[b]);
            if (off < CAP)
                binned[(size_t)b * CAP + off] = e;
        }
        return;
    }

    // ---------------- pack branch ----------------
    long idx = (long)(blockIdx.x - binGrid) * 256 + tid;
    if (idx >= PACK_TOTAL) return;
    long j = idx;
    if (j < SW_IN) { pack_std(W_in, Winp, 128, j); return; }
    j -= SW_IN;
    if (j < SW_OUT) { pack_std(W_out, Woutp, 64, j); return; }
    j -= SW_OUT;
    int l = (int)(j / PERL);
    long r = j % PERL;
    if (r < SW1) {
        int i = (int)(r & 7);
        int n = (int)((r >> 3) & 127);
        int kb = (int)(r >> 10);
        int k = kb * 8 + i;
        const float* w = eW1 + (long)l * 256 * 64;
        float v = (n < 64) ? w[(long)k * 64 + n] : w[(long)(128 + k) * 64 + (n - 64)];
        W1p[(long)l * SW1 + r] = f2bf(v);
        return;
    }
    r -= SW1;
    if (r < SE2) { pack_std_h(eW2 + (long)l * 4096, eW2p + (long)l * SE2, 64, r); return; }
    r -= SE2;
    if (r < SN1) { pack_std(nW1 + (long)l * 24576, nW1p + (long)l * SN1, 128, r); return; }
    r -= SN1;
    if (r < SN2) { pack_std(nW2 + (long)l * 16384, nW2p + (long)l * SN2, 128, r); return; }
    r -= SN2;
    biasP[(long)l * 128 + r] = (r < 64) ? eb1[(long)l * 64 + r] : 0.0f;
}

// ---------------------------------------------------------------------------
// R22: merged [sort | embed] dispatch. Blocks < NBKT run the LDS-free sort
// (re-reads its L2-resident bucket in the scatter pass; no 49KB staging so
// the merged kernel keeps embed's 33.8KB LDS footprint); the rest run the
// fused embedding GEMM. sort consumes binned+cursor (from bin), embed
// consumes packed weights (from pack) — both produced by the prior dispatch.
// sort also emits zmask (static needs-zero row mask for node layers 1..3).
// ---------------------------------------------------------------------------
#define SROWE 264
#define SE_SMEM_BYTES (64 * SROWE * 2)   // embed need (33792 B) >= sort need (~3.1KB)

__global__ __launch_bounds__(256) void sort_embed_k(
    const int2* __restrict__ binned, const int* __restrict__ bucketCursor,
    int2* __restrict__ eidx, unsigned long long* __restrict__ zmask,
    const float* __restrict__ h0, const unsigned short* __restrict__ Win,
    const float* __restrict__ b_in, const unsigned short* __restrict__ W1,
    const float* __restrict__ biasP,
    unsigned short* __restrict__ hB, unsigned short* __restrict__ Pout,
    float* __restrict__ aggZ, int M)
{
    __shared__ char SMEM[SE_SMEM_BYTES];
    const int tid = threadIdx.x;

    if (blockIdx.x < NBKT) {
        // ---------------- sort branch (LDS-free staging) ----------------
        int* cnt     = (int*)SMEM;         // 256
        int* cur     = cnt + 256;          // 256
        int* scanbuf = cur + 256;          // 256
        int* baseS   = scanbuf + 256;      // 2
        const int b = blockIdx.x;

        // counts = final cursor values (clamped at CAP); local prefix for eidx base
        {
            int v = (tid < NBKT) ? min(bucketCursor[tid], CAP) : 0;
            int excl = block_excl_scan_256(v, scanbuf);
            if (tid == b) { baseS[0] = excl; baseS[1] = excl + v; }
        }
        __syncthreads();
        const int s0 = baseS[0];
        const int n = baseS[1] - s0;

        cnt[tid] = 0;
        __syncthreads();
        const int2* bsrc = binned + (size_t)b * CAP;
        // pass 1: count rows (row ids only)
        for (int j = tid; j < n; j += 256)
            atomicAdd(&cnt[bsrc[j].x & 255], 1);
        __syncthreads();
        int myCnt = cnt[tid];
        int excl = block_excl_scan_256(myCnt, scanbuf);
        cur[tid] = excl;
        const int myLo = s0 + excl;        // global eidx start of this row
        __syncthreads();
        // pass 2: re-read bucket (L2-resident) and scatter
        for (int j = tid; j < n; j += 256) {
            int2 e = bsrc[j];
            int pos = atomicAdd(&cur[e.x & 255], 1);
            eidx[s0 + pos] = e;
        }

        // needs-zero mask: one u64 per 64 rows, via per-wave ballot
        {
            bool nz;
            if (myCnt == 0) nz = true;
            else {
                int lo = myLo, hi = myLo + myCnt;
                int A = lo >> 6, Bk = (hi - 1) >> 6;
                nz = (Bk > A) || ((lo & 63) == 0) || (((hi - 1) & 63) == 63);
            }
            unsigned long long m = __ballot(nz);
            if ((tid & 63) == 0)
                zmask[(((size_t)b << 8) + tid) >> 6] = m;
        }
        return;
    }

    // ---------------- embed branch ----------------
    unsigned short* S = (unsigned short*)SMEM;
    const int m0 = (blockIdx.x - NBKT) * 64;
    const int wave = tid >> 6;
    const int lane = tid & 63;
    const int lrow = lane & 15;
    const int quad = lane >> 4;
    const int elb = wave * 16 + quad * 4;

    // staging: h0 f32 -> bf16 into S cols 0..63
    for (int t = tid; t < 64 * 16; t += 256) {
        int rr = t >> 4, c = t & 15;
        int row = m0 + rr;
        floatx4 v = {0, 0, 0, 0};
        if (row < M) v = *(const floatx4*)(h0 + (size_t)row * 64 + c * 4);
        uintx2 u = { f2bf_pk(v[0], v[1]), f2bf_pk(v[2], v[3]) };
        *(uintx2*)(&S[rr * SROWE + c * 4]) = u;
    }
    __syncthreads();   // barrier 1

    // zero this block's agg rows for layer 0 (full zero — zmask not ready yet)
    {
        floatx4 z = {0, 0, 0, 0};
        for (int t = tid; t < 64 * 16; t += 256) {
            int rr = t >> 4, c = t & 15;
            int row = m0 + rr;
            if (row < M) *(floatx4*)(aggZ + (size_t)row * 64 + c * 4) = z;
        }
    }

    const unsigned short* arow = &S[(wave * 16 + lrow) * SROWE];

    floatx4 acc[8];
    #pragma unroll
    for (int i = 0; i < 8; i++) acc[i] = (floatx4){0, 0, 0, 0};
    #pragma unroll
    for (int kt = 0; kt < 2; kt++) {
        short8 afrag = *(const short8*)(arow + kt * 32 + quad * 8);
        int kb = kt * 4 + quad;
        #pragma unroll
        for (int nt = 0; nt < 8; nt++) {
            short8 bfrag = *(const short8*)(Win + (size_t)(kb * 128 + nt * 16 + lrow) * 8);
            acc[nt] = __builtin_amdgcn_mfma_f32_16x16x32_bf16(afrag, bfrag, acc[nt], 0, 0, 0);
        }
    }

    // epilogue: h1 -> S cols 0..127 (bf16)
    #pragma unroll
    for (int nt = 0; nt < 8; nt++) {
        int n = nt * 16 + lrow;
        float bv = b_in[n];
        floatx4 v4;
        #pragma unroll
        for (int r = 0; r < 4; r++) v4[r] = acc[nt][r] + bv;
        unsigned int p01 = f2bf_pk(v4[0], v4[1]);
        unsigned int p23 = f2bf_pk(v4[2], v4[3]);
        S[(elb + 0) * SROWE + n] = (unsigned short)(p01 & 0xFFFF);
        S[(elb + 1) * SROWE + n] = (unsigned short)(p01 >> 16);
        S[(elb + 2) * SROWE + n] = (unsigned short)(p23 & 0xFFFF);
        S[(elb + 3) * SROWE + n] = (unsigned short)(p23 >> 16);
    }

    floatx4 acc3[8];
    #pragma unroll
    for (int i = 0; i < 8; i++) acc3[i] = (floatx4){0, 0, 0, 0};
    #pragma unroll
    for (int kt = 0; kt < 4; kt++) {
        short8 afrag = *(const short8*)(arow + kt * 32 + quad * 8);
        int kb = kt * 4 + quad;
        #pragma unroll
        for (int nt = 0; nt < 8; nt++) {
            short8 bfrag = *(const short8*)(W1 + (size_t)(kb * 128 + nt * 16 + lrow) * 8);
            acc3[nt] = __builtin_amdgcn_mfma_f32_16x16x32_bf16(afrag, bfrag, acc3[nt], 0, 0, 0);
        }
    }
    #pragma unroll
    for (int nt = 0; nt < 8; nt++) {
        int n = nt * 16 + lrow;
        float bv = biasP[n];
        unsigned int p01 = f2fh_pk(acc3[nt][0] + bv, acc3[nt][1] + bv);
        unsigned int p23 = f2fh_pk(acc3[nt][2] + bv, acc3[nt][3] + bv);
        S[(elb + 0) * SROWE + 128 + n] = (unsigned short)(p01 & 0xFFFF);
        S[(elb + 1) * SROWE + 128 + n] = (unsigned short)(p01 >> 16);
        S[(elb + 2) * SROWE + 128 + n] = (unsigned short)(p23 & 0xFFFF);
        S[(elb + 3) * SROWE + 128 + n] = (unsigned short)(p23 >> 16);
    }
    __syncthreads();   // barrier 2

    for (int t = tid; t < 64 * 32; t += 256) {
        int rr = t / 32, c = t % 32;
        int row = m0 + rr;
        if (row < M) {
            if (c < 16)
                *(uintx4*)(hB + (size_t)row * 128 + c * 8) =
                    *(const uintx4*)(&S[rr * SROWE + c * 8]);
            else
                *(uintx4*)(Pout + (size_t)row * 128 + (c - 16) * 8) =
                    *(const uintx4*)(&S[rr * SROWE + 128 + (c - 16) * 8]);
        }
    }
}

// ---------------------------------------------------------------------------
// Fused edge + block-segmented aggregate over sorted edges (R8 body, best
// measured 44.0 µs: f32 M2s [el][68], segStartS reduction, f16 P/eW2 +
// f16 MFMA, bias in accumulators).
// ---------------------------------------------------------------------------
__global__ __launch_bounds__(256) void edge_fused_k(
    const int2* __restrict__ eidx,
    const unsigned short* __restrict__ P,    // [N,128] f16: 0..63 top(+b1), 64..127 bot
    const unsigned short* __restrict__ Bp,   // eW2 frag order, f16
    const float* __restrict__ b2, float* __restrict__ agg, int E)
{
    __shared__ float M2s[64 * 68];
    __shared__ int ridS[64];
    __shared__ short segStartS[66];
    __shared__ int nsegS;
    const int tid = threadIdx.x;
    const int wave = tid >> 6;
    const int lane = tid & 63;
    const int lrow = lane & 15;
    const int quad = lane >> 4;
    const int e0 = blockIdx.x * 64;
    const int el = wave * 16 + lrow;
    const int e = e0 + el;

    // bias preloaded into the MFMA accumulators
    floatx4 acc[4];
    #pragma unroll
    for (int nt = 0; nt < 4; nt++) {
        float bv = b2[nt * 16 + lrow];
        acc[nt] = (floatx4){bv, bv, bv, bv};
    }

    half8v af0 = {};
    half8v af1 = {};
    if (e < E) {
        int2 rc = eidx[e];
        int rr = rc.x, cc = rc.y;
        if (quad == 0) ridS[el] = rr;
        const uintx4* pt = (const uintx4*)(P + (size_t)rr * 128 + quad * 8);
        const uintx4* pb = (const uintx4*)(P + (size_t)cc * 128 + 64 + quad * 8);
        uintx4 t0 = pt[0], t1 = pt[4];
        uintx4 b0 = pb[0], b1 = pb[4];
        uintx4 O0, O1;
        #pragma unroll
        for (int i = 0; i < 4; i++) {
            O0[i] = h2u(silu_h2(__hadd2(u2h(t0[i]), u2h(b0[i]))));
            O1[i] = h2u(silu_h2(__hadd2(u2h(t1[i]), u2h(b1[i]))));
        }
        af0 = __builtin_bit_cast(half8v, O0);
        af1 = __builtin_bit_cast(half8v, O1);
    } else if (quad == 0) {
        ridS[el] = -1;
    }

    #pragma unroll
    for (int nt = 0; nt < 4; nt++) {
        half8v bf0 = *(const half8v*)(Bp + (size_t)((0 * 4 + quad) * 64 + nt * 16 + lrow) * 8);
        acc[nt] = __builtin_amdgcn_mfma_f32_16x16x32_f16(af0, bf0, acc[nt], 0, 0, 0);
        half8v bf1 = *(const half8v*)(Bp + (size_t)((1 * 4 + quad) * 64 + nt * 16 + lrow) * 8);
        acc[nt] = __builtin_amdgcn_mfma_f32_16x16x32_f16(af1, bf1, acc[nt], 0, 0, 0);
    }

    #pragma unroll
    for (int nt = 0; nt < 4; nt++) {
        int n = nt * 16 + lrow;
        #pragma unroll
        for (int r = 0; r < 4; r++) {
            int el2 = wave * 16 + quad * 4 + r;
            M2s[el2 * 68 + n] = silu_f(acc[nt][r]);
        }
    }
    __syncthreads();

    if (tid < 64) {
        bool st = (ridS[tid] >= 0) && (tid == 0 || ridS[tid] != ridS[tid - 1]);
        unsigned long long m = __ballot(st);
        if (st) {
            int pos = __popcll(m & ((1ull << tid) - 1));
            segStartS[pos] = (short)tid;
        }
        if (tid == 0) {
            int ns = __popcll(m);
            nsegS = ns;
            int nvalid = E - e0;
            if (nvalid > 64) nvalid = 64;
            segStartS[ns] = (short)nvalid;
        }
    }
    __syncthreads();

    {
        int f = tid & 63;
        int g = tid >> 6;
        int ns = nsegS;
        for (int j = g; j < ns; j += 4) {
            int a = segStartS[j], b = segStartS[j + 1];
            float s = 0.0f;
            for (int el2 = a; el2 < b; el2++) s += M2s[el2 * 68 + f];
            int rv = ridS[a];
            if (j == 0 || j == ns - 1)
                atomicAdd(&agg[(size_t)rv * 64 + f], s);
            else
                agg[(size_t)rv * 64 + f] = s;
        }
    }
}

// ---------------------------------------------------------------------------
// Fused node-side chain — R21 geometry (256 thr / 32 rows, 16.9KB LDS,
// 8 blocks/CU), masked agg zero via zmask.
// ---------------------------------------------------------------------------
#define SROW 264
template<int FINAL>
__global__ __launch_bounds__(256) void node_fused_k(
    const unsigned short* __restrict__ hbf, const float* __restrict__ agg,
    const unsigned short* __restrict__ W1, const float* __restrict__ b1,
    const unsigned short* __restrict__ W2, const float* __restrict__ b2,
    const unsigned short* __restrict__ B3, const float* __restrict__ bias3,
    unsigned short* __restrict__ hB, unsigned short* __restrict__ Pout,
    float* __restrict__ outF, float* __restrict__ aggZ,
    const unsigned long long* __restrict__ zmask, int M)
{
    __shared__ unsigned short S[32 * SROW];
    const int tid = threadIdx.x;
    const int m0 = blockIdx.x * 32;
    const int wave = tid >> 6;
    const int lane = tid & 63;
    const int lrow = lane & 15;
    const int quad = lane >> 4;
    const int g = wave >> 1;          // row group 0..1
    const int h = wave & 1;           // N half
    const int elb = g * 16 + quad * 4;

    // agg A-fragments straight into registers (kt=4,5 of the K=192 A-op)
    short8 afa0, afa1;
    {
        const float* ap = agg + (size_t)(m0 + g * 16 + lrow) * 64;
        floatx4 q0 = *(const floatx4*)(ap + quad * 8);
        floatx4 q1 = *(const floatx4*)(ap + quad * 8 + 4);
        floatx4 q2 = *(const floatx4*)(ap + 32 + quad * 8);
        floatx4 q3 = *(const floatx4*)(ap + 32 + quad * 8 + 4);
        unsigned int c0[4] = { f2bf_pk(q0[0], q0[1]), f2bf_pk(q0[2], q0[3]),
                               f2bf_pk(q1[0], q1[1]), f2bf_pk(q1[2], q1[3]) };
        unsigned int c1[4] = { f2bf_pk(q2[0], q2[1]), f2bf_pk(q2[2], q2[3]),
                               f2bf_pk(q3[0], q3[1]), f2bf_pk(q3[2], q3[3]) };
        afa0 = *(const short8*)c0;
        afa1 = *(const short8*)c1;
    }

    // staging: h (128 bf16) only -> S cols 0..127
    for (int t = tid; t < 32 * 16; t += 256) {
        int rr = t >> 4, c = t & 15;
        int row = m0 + rr;
        uintx4 val = {0, 0, 0, 0};
        if (row < M) val = *(const uintx4*)(hbf + (size_t)row * 128 + c * 8);
        *(uintx4*)(&S[rr * SROW + c * 8]) = val;
    }
    __syncthreads();   // B1

    // masked zero of this block's agg rows for the next layer
    if (!FINAL) {
        unsigned long long zm = zmask[m0 >> 6];
        int bb = m0 & 63;   // 0 or 32
        floatx4 z = {0, 0, 0, 0};
        for (int t = tid; t < 32 * 16; t += 256) {
            int rr = t >> 4, c = t & 15;
            int row = m0 + rr;
            if (row < M && ((zm >> (bb + rr)) & 1ull))
                *(floatx4*)(aggZ + (size_t)row * 64 + c * 4) = z;
        }
    }

    const unsigned short* arow = &S[(g * 16 + lrow) * SROW];

    // ---- phase A MFMA: K=192 (kt 0..3 from LDS, kt 4..5 from registers) ----
    floatx4 acc[4];
    #pragma unroll
    for (int i = 0; i < 4; i++) acc[i] = (floatx4){0, 0, 0, 0};
    #pragma unroll
    for (int kt = 0; kt < 4; kt++) {
        short8 afrag = *(const short8*)(arow + kt * 32 + quad * 8);
        int kb = kt * 4 + quad;
        #pragma unroll
        for (int j = 0; j < 4; j++) {
            int n = (4 * h + j) * 16 + lrow;
            short8 bfrag = *(const short8*)(W1 + (size_t)(kb * 128 + n) * 8);
            acc[j] = __builtin_amdgcn_mfma_f32_16x16x32_bf16(afrag, bfrag, acc[j], 0, 0, 0);
        }
    }
    #pragma unroll
    for (int j = 0; j < 4; j++) {
        int n = (4 * h + j) * 16 + lrow;
        short8 b4 = *(const short8*)(W1 + (size_t)((16 + quad) * 128 + n) * 8);
        acc[j] = __builtin_amdgcn_mfma_f32_16x16x32_bf16(afa0, b4, acc[j], 0, 0, 0);
        short8 b5 = *(const short8*)(W1 + (size_t)((20 + quad) * 128 + n) * 8);
        acc[j] = __builtin_amdgcn_mfma_f32_16x16x32_bf16(afa1, b5, acc[j], 0, 0, 0);
    }

    // epilogue A: t -> S cols 128..255
    #pragma unroll
    for (int j = 0; j < 4; j++) {
        int n = (4 * h + j) * 16 + lrow;
        float bv = b1[n];
        unsigned int p01 = f2bf_pk(silu_f(acc[j][0] + bv), silu_f(acc[j][1] + bv));
        unsigned int p23 = f2bf_pk(silu_f(acc[j][2] + bv), silu_f(acc[j][3] + bv));
        S[(elb + 0) * SROW + 128 + n] = (unsigned short)(p01 & 0xFFFF);
        S[(elb + 1) * SROW + 128 + n] = (unsigned short)(p01 >> 16);
        S[(elb + 2) * SROW + 128 + n] = (unsigned short)(p23 & 0xFFFF);
        S[(elb + 3) * SROW + 128 + n] = (unsigned short)(p23 >> 16);
    }
    __syncthreads();   // B2: t complete

    // ---- phase B MFMA: K=128 over t (cols 128..255) ----
    floatx4 acc2[4];
    #pragma unroll
    for (int i = 0; i < 4; i++) acc2[i] = (floatx4){0, 0, 0, 0};
    #pragma unroll
    for (int kt = 0; kt < 4; kt++) {
        short8 afrag = *(const short8*)(arow + 128 + kt * 32 + quad * 8);
        int kb = kt * 4 + quad;
        #pragma unroll
        for (int j = 0; j < 4; j++) {
            int n = (4 * h + j) * 16 + lrow;
            short8 bfrag = *(const short8*)(W2 + (size_t)(kb * 128 + n) * 8);
            acc2[j] = __builtin_amdgcn_mfma_f32_16x16x32_bf16(afrag, bfrag, acc2[j], 0, 0, 0);
        }
    }

    // epilogue B: h_new = acc2 + b2 + res(LDS bf16, owner cells) -> S cols 0..127
    #pragma unroll
    for (int j = 0; j < 4; j++) {
        int n = (4 * h + j) * 16 + lrow;
        float bv = b2[n];
        floatx4 v4;
        #pragma unroll
        for (int r = 0; r < 4; r++) {
            float res = bf2f(S[(elb + r) * SROW + n]);
            v4[r] = acc2[j][r] + bv + res;
        }
        unsigned int p01 = f2bf_pk(v4[0], v4[1]);
        unsigned int p23 = f2bf_pk(v4[2], v4[3]);
        S[(elb + 0) * SROW + n] = (unsigned short)(p01 & 0xFFFF);
        S[(elb + 1) * SROW + n] = (unsigned short)(p01 >> 16);
        S[(elb + 2) * SROW + n] = (unsigned short)(p23 & 0xFFFF);
        S[(elb + 3) * SROW + n] = (unsigned short)(p23 >> 16);
    }
    __syncthreads();   // B3: h_new complete (all t reads done)

    // ---- phase C MFMA: K=128 -> P (128, f16) or out (64, f32) ----
    constexpr int NT3 = FINAL ? 2 : 4;
    constexpr int NO3 = FINAL ? 64 : 128;
    floatx4 acc3[NT3];
    #pragma unroll
    for (int i = 0; i < NT3; i++) acc3[i] = (floatx4){0, 0, 0, 0};
    #pragma unroll
    for (int kt = 0; kt < 4; kt++) {
        short8 afrag = *(const short8*)(arow + kt * 32 + quad * 8);
        int kb = kt * 4 + quad;
        #pragma unroll
        for (int j = 0; j < NT3; j++) {
            int n = (NT3 * h + j) * 16 + lrow;
            short8 bfrag = *(const short8*)(B3 + (size_t)(kb * NO3 + n) * 8);
            acc3[j] = __builtin_amdgcn_mfma_f32_16x16x32_bf16(afrag, bfrag, acc3[j], 0, 0, 0);
        }
    }
    // epilogue C -> S cols 128..255 (f16 P) or fp32 out region (same cols)
    #pragma unroll
    for (int j = 0; j < NT3; j++) {
        int n = (NT3 * h + j) * 16 + lrow;
        float bv = bias3[n];
        if (FINAL) {
            #pragma unroll
            for (int r = 0; r < 4; r++)
                ((float*)(&S[(elb + r) * SROW + 128]))[n] = acc3[j][r] + bv;
        } else {
            unsigned int p01 = f2fh_pk(acc3[j][0] + bv, acc3[j][1] + bv);
            unsigned int p23 = f2fh_pk(acc3[j][2] + bv, acc3[j][3] + bv);
            S[(elb + 0) * SROW + 128 + n] = (unsigned short)(p01 & 0xFFFF);
            S[(elb + 1) * SROW + 128 + n] = (unsigned short)(p01 >> 16);
            S[(elb + 2) * SROW + 128 + n] = (unsigned short)(p23 & 0xFFFF);
            S[(elb + 3) * SROW + 128 + n] = (unsigned short)(p23 >> 16);
        }
    }
    __syncthreads();   // B4

    // cooperative wide stores
    if (FINAL) {
        for (int t = tid; t < 32 * 16; t += 256) {
            int rr = t >> 4, c = t & 15;
            int row = m0 + rr;
            if (row < M)
                *(floatx4*)(outF + (size_t)row * 64 + c * 4) =
                    *(const floatx4*)((const float*)(&S[rr * SROW + 128]) + c * 4);
        }
    } else {
        for (int t = tid; t < 32 * 32; t += 256) {
            int rr = t >> 5, c = t & 31;
            int row = m0 + rr;
            if (row < M) {
                if (c < 16)
                    *(uintx4*)(hB + (size_t)row * 128 + c * 8) =
                        *(const uintx4*)(&S[rr * SROW + c * 8]);
                else
                    *(uintx4*)(Pout + (size_t)row * 128 + (c - 16) * 8) =
                        *(const uintx4*)(&S[rr * SROW + 128 + (c - 16) * 8]);
            }
        }
    }
}

// ---------------------------------------------------------------------------
extern "C" void kernel_launch(void* const* d_in, const int* in_sizes, int n_in,
                              void* d_out, int out_size, void* d_ws, size_t ws_size,
                              hipStream_t stream) {
    const float* h0   = (const float*)d_in[0];
    const int*   edges= (const int*)d_in[1];
    const float* W_in = (const float*)d_in[2];
    const float* b_in = (const float*)d_in[3];
    const float* eW1  = (const float*)d_in[4];
    const float* eb1  = (const float*)d_in[5];
    const float* eW2  = (const float*)d_in[6];
    const float* eb2  = (const float*)d_in[7];
    const float* nW1  = (const float*)d_in[8];
    const float* nb1  = (const float*)d_in[9];
    const float* nW2  = (const float*)d_in[10];
    const float* nb2  = (const float*)d_in[11];
    const float* W_out= (const float*)d_in[12];
    const float* b_out= (const float*)d_in[13];
    float* out = (float*)d_out;

    const int E = in_sizes[1] / 2;      // 800000
    const int* erow = edges;
    const int* ecol = edges + E;

    char* ws = (char*)d_ws;
    unsigned short* hbf  = (unsigned short*)(ws + 0);            // 12,800,000
    int2*           binned=(int2*)(ws + 12800000);               //  9,633,792 (196*CAP*8)
    unsigned short* P    = (unsigned short*)(ws + 38424576);     // 12,800,000 (f16)
    float*          agg  = (float*)(ws + 51224576);              // 12,800,000
    int2*           eidx = (int2*)(ws + 76824576);               //  6,400,000
    float*          biasP= (float*)(ws + 83224576);              //  2,048
    unsigned short* Winp = (unsigned short*)(ws + 83226624);     // 16,384
    unsigned short* Woutp= (unsigned short*)(ws + 83243008);     // 16,384
    unsigned short* W1p  = (unsigned short*)(ws + 83259392);     // 131,072
    unsigned short* eW2p = (unsigned short*)(ws + 83390464);     // 32,768 (f16)
    unsigned short* nW1p = (unsigned short*)(ws + 83423232);     // 196,608
    unsigned short* nW2p = (unsigned short*)(ws + 83619840);     // 131,072
    int*            bucketCursor=(int*)(ws + 83752960);          // 784
    unsigned long long* zmask = (unsigned long long*)(ws + 83754496); // 6,272 (784 u64)

    const int gemm_grid = (N_NODES + 63) / 64;    // 782 (embed)
    const int node_grid = (N_NODES + 31) / 32;    // 1563 (node, 32 rows/block)
    const int edge_grid = (E + 63) / 64;          // 12500
    const int bin_grid  = (E + BCHUNK - 1) / BCHUNK;   // 391

    // cursor zero (bin uses it in the next dispatch; pack-tail zeroing would race)
    hipMemsetAsync(bucketCursor, 0, NBKT * 4, stream);

    // merged [bin | pack]: independent paths, run concurrently
    bin_pack_k<<<bin_grid + PACK_BLOCKS, 256, 0, stream>>>(
        erow, ecol, bucketCursor, binned, E, bin_grid,
        W_in, W_out, eW1, eb1, eW2, nW1, nW2,
        Winp, Woutp, W1p, eW2p, nW1p, nW2p, biasP);

    // merged [sort | embed]: sort consumes binned/cursor, embed consumes
    // packed weights; both produced by the prior dispatch. sort emits zmask.
    sort_embed_k<<<NBKT + gemm_grid, 256, 0, stream>>>(
        binned, bucketCursor, eidx, zmask,
        h0, Winp, b_in, W1p, biasP, hbf, P, agg, N_NODES);

    for (int l = 0; l < 4; l++) {
        edge_fused_k<<<edge_grid, 256, 0, stream>>>(
            eidx, P, eW2p + (size_t)l * SE2, eb2 + (size_t)l * 64, agg, E);
        if (l < 3) {
            node_fused_k<0><<<node_grid, 256, 0, stream>>>(
                hbf, agg, nW1p + (size_t)l * SN1, nb1 + (size_t)l * 128,
                nW2p + (size_t)l * SN2, nb2 + (size_t)l * 128,
                W1p + (size_t)(l + 1) * SW1, biasP + (size_t)(l + 1) * 128,
                hbf, P, nullptr, agg, zmask, N_NODES);
        } else {
            node_fused_k<1><<<node_grid, 256, 0, stream>>>(
                hbf, agg, nW1p + (size_t)l * SN1, nb1 + (size_t)l * 128,
                nW2p + (size_t)l * SN2, nb2 + (size_t)l * 128,
                Woutp, b_out, nullptr, nullptr, out, nullptr, zmask, N_NODES);
        }
    }
}